// Round 6
// baseline (2193.471 us; speedup 1.0000x reference)
//
#include <hip/hip_runtime.h>
#include <hip/hip_bf16.h>
#include <math.h>

#define DMODEL 256
#define KNB 32
#define NHEAD 8
#define FIN 95
#define FPAIR 162
#define FOUT 1024
#define DHID 512
#define TR 8

typedef __hip_bfloat16 bf16;
__device__ inline float B2F(bf16 x) { return __bfloat162float(x); }
__device__ inline bf16 F2B(float x) { return __float2bfloat16(x); }

__device__ inline float gelu_t(float x) {
    return 0.5f * x * (1.f + tanhf(0.7978845608028654f * (x + 0.044715f * x * x * x)));
}

// block-wide reduce of two values; block = 256 threads (4 waves)
__device__ inline void block_reduce2(float& a, float& b, float* sm) {
    __syncthreads();
    for (int off = 32; off > 0; off >>= 1) {
        a += __shfl_down(a, off);
        b += __shfl_down(b, off);
    }
    int lane = threadIdx.x & 63, w = threadIdx.x >> 6;
    if (lane == 0) { sm[w * 2] = a; sm[w * 2 + 1] = b; }
    __syncthreads();
    if (threadIdx.x == 0) {
        float sa = 0.f, sb = 0.f;
        for (int i = 0; i < 4; i++) { sa += sm[i * 2]; sb += sm[i * 2 + 1]; }
        sm[0] = sa; sm[1] = sb;
    }
    __syncthreads();
    a = sm[0]; b = sm[1];
}

// Kernel A: frames, local_pos, feat, lup = local + feat @ w_in  (lup -> d_out local region, f32)
__global__ __launch_bounds__(256) void kA(const float* __restrict__ local,
                                          const float* __restrict__ pos,
                                          const float* __restrict__ w_in,
                                          float* __restrict__ Rw,
                                          float* __restrict__ lpw,
                                          float* __restrict__ lup) {
    int i = blockIdx.x;
    int tid = threadIdx.x;
    const float* pp = pos + (size_t)i * 15;
    float nx = pp[0], ny = pp[1], nz = pp[2];
    float cax = pp[3], cay = pp[4], caz = pp[5];
    float cx = pp[6], cy = pp[7], cz = pp[8];
    float e1x = cx - cax, e1y = cy - cay, e1z = cz - caz;
    float inv = rsqrtf(e1x * e1x + e1y * e1y + e1z * e1z + 1e-6f);
    e1x *= inv; e1y *= inv; e1z *= inv;
    float ux = nx - cax, uy = ny - cay, uz = nz - caz;
    float d = ux * e1x + uy * e1y + uz * e1z;
    float wx = ux - d * e1x, wy = uy - d * e1y, wz = uz - d * e1z;
    inv = rsqrtf(wx * wx + wy * wy + wz * wz + 1e-6f);
    float e2x = wx * inv, e2y = wy * inv, e2z = wz * inv;
    float e3x = e1y * e2z - e1z * e2y;
    float e3y = e1z * e2x - e1x * e2z;
    float e3z = e1x * e2y - e1y * e2x;
    // flat[r*3+c] = e_c[coord r]
    float R[9] = {e1x, e2x, e3x, e1y, e2y, e3y, e1z, e2z, e3z};

    __shared__ float lp[15];
    __shared__ float feat[FIN];
    __shared__ float dd[5], dinv[5];

    if (tid < 9) Rw[(size_t)i * 9 + tid] = R[tid];
    if (tid < 15) {
        int a = tid / 3, ii = tid % 3;
        float px = pp[a * 3 + 0] - cax, py = pp[a * 3 + 1] - cay, pz = pp[a * 3 + 2] - caz;
        float v = R[0 * 3 + ii] * px + R[1 * 3 + ii] * py + R[2 * 3 + ii] * pz;
        lp[tid] = v;
        lpw[(size_t)i * 15 + tid] = v;
    }
    __syncthreads();
    if (tid < 5) {
        float s = lp[tid * 3] * lp[tid * 3] + lp[tid * 3 + 1] * lp[tid * 3 + 1] + lp[tid * 3 + 2] * lp[tid * 3 + 2];
        dd[tid] = sqrtf(s + 1e-12f);
        dinv[tid] = rsqrtf(s + 1e-6f);
    }
    __syncthreads();
    if (tid < 15) {
        feat[tid] = lp[tid] * dinv[tid / 3];
    } else if (tid < 95) {
        int u = tid - 15, a = u >> 4, b = u & 15;
        float z = (dd[a] - (float)b * (10.f / 15.f)) * (1.f / 0.625f);
        feat[tid] = expf(-z * z);
    }
    __syncthreads();
    float acc = local[(size_t)i * DMODEL + tid];
    for (int f = 0; f < FIN; f++) acc += feat[f] * w_in[f * DMODEL + tid];
    lup[(size_t)i * DMODEL + tid] = acc;
}

// Kernel B: LN1 + 6 projections; q/k/v bf16, point projections stored in LOCAL frame bf16
__global__ __launch_bounds__(256) void kB(const float* __restrict__ lup,
                                          const float* __restrict__ ln1_s,
                                          const float* __restrict__ ln1_o,
                                          const float* __restrict__ wq,
                                          const float* __restrict__ wk,
                                          const float* __restrict__ wv,
                                          const float* __restrict__ wqp,
                                          const float* __restrict__ wkp,
                                          const float* __restrict__ wvp,
                                          bf16* __restrict__ qbh,
                                          bf16* __restrict__ kbh,
                                          bf16* __restrict__ vbh,
                                          bf16* __restrict__ qpl,
                                          bf16* __restrict__ kpl,
                                          bf16* __restrict__ vpl) {
    int r0 = blockIdx.x * TR;
    int tid = threadIdx.x;
    __shared__ float xn[TR][DMODEL];
    __shared__ float red[8];

    for (int r = 0; r < TR; r++) {
        float v = lup[(size_t)(r0 + r) * DMODEL + tid];
        float a = v, b = v * v;
        block_reduce2(a, b, red);
        float mu = a * (1.f / 256.f);
        float var = b * (1.f / 256.f) - mu * mu;
        xn[r][tid] = (v - mu) * rsqrtf(var + 1e-5f) * ln1_s[tid] + ln1_o[tid];
    }
    __syncthreads();
    for (int o = tid; o < 1344; o += 256) {
        const float* W; bf16* O; int col, ncol;
        if (o < 256)       { W = wq;  O = qbh; col = o;        ncol = 256; }
        else if (o < 512)  { W = wk;  O = kbh; col = o - 256;  ncol = 256; }
        else if (o < 768)  { W = wv;  O = vbh; col = o - 512;  ncol = 256; }
        else if (o < 960)  { W = wqp; O = qpl; col = o - 768;  ncol = 192; }
        else if (o < 1152) { W = wkp; O = kpl; col = o - 960;  ncol = 192; }
        else               { W = wvp; O = vpl; col = o - 1152; ncol = 192; }
        float acc[TR] = {0.f, 0.f, 0.f, 0.f, 0.f, 0.f, 0.f, 0.f};
        for (int f = 0; f < 256; f++) {
            float w = W[f * ncol + col];
#pragma unroll
            for (int r = 0; r < TR; r++) acc[r] += xn[r][f] * w;
        }
        for (int r = 0; r < TR; r++) O[(size_t)(r0 + r) * ncol + col] = F2B(acc[r]);
    }
}

// Kernel C: pair features + pair MLP + attention + IPA concat (bf16 out)
__global__ __launch_bounds__(256) void kC(const float* __restrict__ pos,
                                          const int* __restrict__ nbr,
                                          const int* __restrict__ resi,
                                          const int* __restrict__ chain,
                                          const int* __restrict__ batch,
                                          const int* __restrict__ mask,
                                          const float* __restrict__ Rw,
                                          const float* __restrict__ w_pair,
                                          const float* __restrict__ b_pair,
                                          const float* __restrict__ wbm,
                                          const float* __restrict__ gamma,
                                          const bf16* __restrict__ qbh,
                                          const bf16* __restrict__ kbh,
                                          const bf16* __restrict__ vbh,
                                          const bf16* __restrict__ qpl,
                                          const bf16* __restrict__ kpl,
                                          const bf16* __restrict__ vpl,
                                          bf16* __restrict__ ipab,
                                          int N) {
    int i = blockIdx.x;
    int tid = threadIdx.x;
    __shared__ float qS[256], qpS[192];
    __shared__ float pf[KNB][FPAIR];
    __shared__ float pairS[KNB][64];
    __shared__ float lg[KNB * NHEAD];
    __shared__ float optg[192];
    __shared__ float ipaS[FOUT];
    __shared__ float RjS[KNB][9], tjS[KNB][3];
    __shared__ int idxS[KNB], rpS[KNB], scS[KNB], sbS[KNB], pmS[KNB];

    float R[9];
#pragma unroll
    for (int u = 0; u < 9; u++) R[u] = Rw[(size_t)i * 9 + u];
    float t0 = pos[(size_t)i * 15 + 3];
    float t1 = pos[(size_t)i * 15 + 4];
    float t2 = pos[(size_t)i * 15 + 5];

    qS[tid] = B2F(qbh[(size_t)i * 256 + tid]);
    if (tid < KNB) {
        int nb = nbr[(size_t)i * KNB + tid];
        int j = min(max(nb, 0), N - 1);
        idxS[tid] = j;
        int rp = resi[j] - resi[i];
        rp = min(max(rp, -32), 32) + 32;
        rpS[tid] = rp;
        scS[tid] = (chain[j] == chain[i]) ? 1 : 0;
        sbS[tid] = (batch[j] == batch[i]) ? 1 : 0;
        pmS[tid] = (mask[i] != 0 && mask[j] != 0 && nb >= 0 && batch[j] == batch[i]) ? 1 : 0;
    }
    __syncthreads();
    // gather neighbour frames
    for (int u = tid; u < KNB * 9; u += 256) RjS[u / 9][u % 9] = Rw[(size_t)idxS[u / 9] * 9 + (u % 9)];
    if (tid < KNB * 3) tjS[tid / 3][tid % 3] = pos[(size_t)idxS[tid / 3] * 15 + 3 + (tid % 3)];
    // qp -> global frame (f32)
    if (tid < 192) {
        int hp = tid / 3, ii = tid % 3;
        float p0 = B2F(qpl[(size_t)i * 192 + hp * 3 + 0]);
        float p1 = B2F(qpl[(size_t)i * 192 + hp * 3 + 1]);
        float p2 = B2F(qpl[(size_t)i * 192 + hp * 3 + 2]);
        float tc = (ii == 0) ? t0 : (ii == 1 ? t1 : t2);
        qpS[tid] = R[ii * 3 + 0] * p0 + R[ii * 3 + 1] * p1 + R[ii * 3 + 2] * p2 + tc;
    }
    // dirs + rbf(dij): 160 threads = 32 neighbours x 5 atoms
    if (tid < 160) {
        int kk = tid & 31, a = tid >> 5;
        int j = idxS[kk];
        const float* pj = pos + (size_t)j * 15 + a * 3;
        float px = pj[0] - t0, py = pj[1] - t1, pz = pj[2] - t2;
        float r0_ = R[0] * px + R[3] * py + R[6] * pz;
        float r1_ = R[1] * px + R[4] * py + R[7] * pz;
        float r2_ = R[2] * px + R[5] * py + R[8] * pz;
        float s = r0_ * r0_ + r1_ * r1_ + r2_ * r2_;
        float dij = sqrtf(s + 1e-12f);
        float di = 1.f / (dij + 1e-6f);
        pf[kk][a * 3 + 0] = r0_ * di;
        pf[kk][a * 3 + 1] = r1_ * di;
        pf[kk][a * 3 + 2] = r2_ * di;
        for (int b = 0; b < 16; b++) {
            float z = (dij - (float)b * (10.f / 15.f)) * (1.f / 0.625f);
            pf[kk][15 + a * 16 + b] = expf(-z * z);
        }
    }
    // one-hot relpos + same_chain + same_batch
    for (int u = tid; u < KNB * 67; u += 256) {
        int kk = u / 67, m = u % 67;
        float v;
        if (m < 65) v = (m == rpS[kk]) ? 1.f : 0.f;
        else if (m == 65) v = (float)scS[kk];
        else v = (float)sbS[kk];
        pf[kk][95 + m] = v;
    }
    __syncthreads();
    // pair = gelu(pf @ w_pair + b_pair)
    {
        int kg = tid >> 6, d = tid & 63;
        for (int kk = kg; kk < KNB; kk += 4) {
            float s = b_pair[d];
            for (int f = 0; f < FPAIR; f++) s += pf[kk][f] * w_pair[f * 64 + d];
            pairS[kk][d] = gelu_t(s);
        }
    }
    __syncthreads();
    // logits
    {
        int kk = tid >> 3, h = tid & 7;
        int j = idxS[kk];
        float qk = 0.f;
        const bf16* kj = kbh + (size_t)j * 256 + h * 32;
        const float* qh = qS + h * 32;
        for (int d2i = 0; d2i < 32; d2i++) qk += qh[d2i] * B2F(kj[d2i]);
        qk *= 0.17677669529663687f;  // 1/sqrt(32)
        float d2 = 0.f;
        const bf16* kpj = kpl + (size_t)j * 192 + h * 24;
        for (int p = 0; p < 8; p++) {
            float p0 = B2F(kpj[p * 3 + 0]), p1 = B2F(kpj[p * 3 + 1]), p2 = B2F(kpj[p * 3 + 2]);
#pragma unroll
            for (int ii = 0; ii < 3; ii++) {
                float kpv = RjS[kk][ii * 3 + 0] * p0 + RjS[kk][ii * 3 + 1] * p1 +
                            RjS[kk][ii * 3 + 2] * p2 + tjS[kk][ii];
                float df = qpS[h * 24 + p * 3 + ii] - kpv;
                d2 += df * df;
            }
        }
        float pb = 0.f;
        for (int c = 0; c < 64; c++) pb += pairS[kk][c] * wbm[c * 8 + h];
        float sp = log1pf(expf(gamma[h]));
        float lgt = 0.5773502691896258f * (qk + pb - (1.f / 12.f) * sp * d2);
        lg[kk * 8 + h] = pmS[kk] ? lgt : -1e9f;
    }
    __syncthreads();
    // softmax over kk per head; zero masked
    if (tid < 8) {
        int h = tid;
        float m = -INFINITY;
        for (int kk = 0; kk < KNB; kk++) m = fmaxf(m, lg[kk * 8 + h]);
        float s = 0.f;
        for (int kk = 0; kk < KNB; kk++) s += expf(lg[kk * 8 + h] - m);
        float invs = 1.f / s;
        for (int kk = 0; kk < KNB; kk++) {
            float a = expf(lg[kk * 8 + h] - m) * invs;
            lg[kk * 8 + h] = pmS[kk] ? a : 0.f;
        }
    }
    __syncthreads();
    // o_s
    {
        int h = tid >> 5, d = tid & 31;
        float s = 0.f;
        for (int kk = 0; kk < KNB; kk++)
            s += lg[kk * 8 + h] * B2F(vbh[(size_t)idxS[kk] * 256 + h * 32 + d]);
        ipaS[h * 32 + d] = s;
    }
    // o_pr
    for (int u = tid; u < 512; u += 256) {
        int h = u >> 6, c = u & 63;
        float s = 0.f;
        for (int kk = 0; kk < KNB; kk++) s += lg[kk * 8 + h] * pairS[kk][c];
        ipaS[256 + u] = s;
    }
    // o_pt global: rotate neighbour vp points on the fly
    if (tid < 192) {
        int ii = tid % 3, hp = tid / 3, h = hp >> 3;
        float s = 0.f;
        for (int kk = 0; kk < KNB; kk++) {
            const bf16* vpj = vpl + (size_t)idxS[kk] * 192 + hp * 3;
            float vg = RjS[kk][ii * 3 + 0] * B2F(vpj[0]) + RjS[kk][ii * 3 + 1] * B2F(vpj[1]) +
                       RjS[kk][ii * 3 + 2] * B2F(vpj[2]) + tjS[kk][ii];
            s += lg[kk * 8 + h] * vg;
        }
        optg[tid] = s;
    }
    __syncthreads();
    // o_pt -> local frame
    if (tid < 192) {
        int hp = tid / 3, ii = tid % 3;
        float v0 = optg[hp * 3 + 0] - t0, v1 = optg[hp * 3 + 1] - t1, v2 = optg[hp * 3 + 2] - t2;
        ipaS[768 + tid] = R[0 + ii] * v0 + R[3 + ii] * v1 + R[6 + ii] * v2;
    }
    __syncthreads();
    if (tid < 64) {
        float a0 = ipaS[768 + tid * 3], a1 = ipaS[768 + tid * 3 + 1], a2 = ipaS[768 + tid * 3 + 2];
        ipaS[960 + tid] = sqrtf(a0 * a0 + a1 * a1 + a2 * a2 + 1e-8f);
    }
    __syncthreads();
    for (int u = tid; u < FOUT; u += 256) ipab[(size_t)i * FOUT + u] = F2B(ipaS[u]);
}

// Kernel D: d_out_local = lup + ipa @ wo + bo  (in-place on d_out)
__global__ __launch_bounds__(256) void kD(const bf16* __restrict__ ipab,
                                          const float* __restrict__ wo,
                                          const float* __restrict__ bo,
                                          float* __restrict__ dlocal) {
    int r0 = blockIdx.x * TR;
    int tid = threadIdx.x;
    __shared__ float ipaL[TR][FOUT];
    for (int u = tid; u < TR * FOUT; u += 256)
        ipaL[u >> 10][u & 1023] = B2F(ipab[(size_t)r0 * FOUT + u]);
    __syncthreads();
    float acc[TR] = {0.f, 0.f, 0.f, 0.f, 0.f, 0.f, 0.f, 0.f};
    for (int f = 0; f < FOUT; f++) {
        float w = wo[f * 256 + tid];
#pragma unroll
        for (int r = 0; r < TR; r++) acc[r] += ipaL[r][f] * w;
    }
    float bov = bo[tid];
    for (int r = 0; r < TR; r++) {
        size_t off = (size_t)(r0 + r) * 256 + tid;
        dlocal[off] = dlocal[off] + acc[r] + bov;  // same thread reads & writes same element
    }
}

// Kernel E: transition MLP in-place on d_out local region
__global__ __launch_bounds__(256) void kE(const float* __restrict__ ln2_s,
                                          const float* __restrict__ ln2_o,
                                          const float* __restrict__ wg,
                                          const float* __restrict__ wvm,
                                          const float* __restrict__ wom,
                                          float* __restrict__ dlocal) {
    int r0 = blockIdx.x * TR;
    int tid = threadIdx.x;
    __shared__ float x2[TR][DMODEL];
    __shared__ float hS[TR][DHID];
    __shared__ float red[8];
    float lv[TR];
    for (int r = 0; r < TR; r++) {
        float v = dlocal[(size_t)(r0 + r) * DMODEL + tid];
        lv[r] = v;
        float a = v, b = v * v;
        block_reduce2(a, b, red);
        float mu = a * (1.f / 256.f);
        float var = b * (1.f / 256.f) - mu * mu;
        x2[r][tid] = (v - mu) * rsqrtf(var + 1e-5f) * ln2_s[tid] + ln2_o[tid];
    }
    __syncthreads();
    for (int o = tid; o < DHID; o += 256) {
        float ag[TR] = {0.f, 0.f, 0.f, 0.f, 0.f, 0.f, 0.f, 0.f};
        float av[TR] = {0.f, 0.f, 0.f, 0.f, 0.f, 0.f, 0.f, 0.f};
        for (int f = 0; f < 256; f++) {
            float wgv = wg[f * DHID + o], wvv = wvm[f * DHID + o];
#pragma unroll
            for (int r = 0; r < TR; r++) { ag[r] += x2[r][f] * wgv; av[r] += x2[r][f] * wvv; }
        }
        for (int r = 0; r < TR; r++) hS[r][o] = gelu_t(ag[r]) * av[r];
    }
    __syncthreads();
    float acc[TR] = {0.f, 0.f, 0.f, 0.f, 0.f, 0.f, 0.f, 0.f};
    for (int f = 0; f < DHID; f++) {
        float w = wom[f * 256 + tid];
#pragma unroll
        for (int r = 0; r < TR; r++) acc[r] += hS[r][f] * w;
    }
    for (int r = 0; r < TR; r++)
        dlocal[(size_t)(r0 + r) * DMODEL + tid] = lv[r] + acc[r];
}

// Kernel F: LN3 + wpos + frame transform + update_mask; writes pos output (f32)
__global__ __launch_bounds__(256) void kF(const float* __restrict__ dlocal,
                                          const float* __restrict__ ln3_s,
                                          const float* __restrict__ ln3_o,
                                          const float* __restrict__ wpos,
                                          const float* __restrict__ lpw,
                                          const float* __restrict__ Rw,
                                          const float* __restrict__ pos,
                                          const int* __restrict__ umask,
                                          float* __restrict__ outp) {
    int i = blockIdx.x;
    int tid = threadIdx.x;
    __shared__ float x3[256];
    __shared__ float red[8];
    __shared__ float nl[15];
    float v = dlocal[(size_t)i * DMODEL + tid];
    float a = v, b = v * v;
    block_reduce2(a, b, red);
    float mu = a * (1.f / 256.f);
    float var = b * (1.f / 256.f) - mu * mu;
    x3[tid] = (v - mu) * rsqrtf(var + 1e-5f) * ln3_s[tid] + ln3_o[tid];
    __syncthreads();
    if (tid < 15) {
        float s = 0.f;
        for (int f = 0; f < 256; f++) s += x3[f] * wpos[f * 15 + tid];
        nl[tid] = lpw[(size_t)i * 15 + tid] + s;
    }
    __syncthreads();
    if (tid < 15) {
        int a2 = tid / 3, ii = tid % 3;
        float R0 = Rw[(size_t)i * 9 + ii * 3 + 0];
        float R1 = Rw[(size_t)i * 9 + ii * 3 + 1];
        float R2 = Rw[(size_t)i * 9 + ii * 3 + 2];
        float tt = pos[(size_t)i * 15 + 3 + ii];
        float np = R0 * nl[a2 * 3 + 0] + R1 * nl[a2 * 3 + 1] + R2 * nl[a2 * 3 + 2] + tt;
        float old = pos[(size_t)i * 15 + tid];
        outp[(size_t)i * 15 + tid] = (umask[i] != 0) ? np : old;
    }
}

extern "C" void kernel_launch(void* const* d_in, const int* in_sizes, int n_in,
                              void* d_out, int out_size, void* d_ws, size_t ws_size,
                              hipStream_t stream) {
    static const int map_dict[31] = {0, 1, 2, 3, 4, 5, 6, 7, 8, 9, 10, 11, 12, 13, 14, 15,
                                     16, 17, 18, 19, 20, 21, 22, 23, 24, 25, 26, 27, 28, 29, 30};
    static const int map_sig[31] = {0, 1, 25, 26, 27, 28, 29, 30, 2, 3, 4, 5, 6, 7, 8, 9,
                                    10, 11, 12, 13, 14, 15, 16, 17, 18, 19, 20, 21, 22, 23, 24};
    const int* M = (in_sizes[2] == FIN * DMODEL) ? map_sig : map_dict;

    const float* local = (const float*)d_in[M[0]];
    const float* pos = (const float*)d_in[M[1]];
    const int* nbr = (const int*)d_in[M[2]];
    const int* resi = (const int*)d_in[M[3]];
    const int* chain = (const int*)d_in[M[4]];
    const int* batch = (const int*)d_in[M[5]];
    const int* umask = (const int*)d_in[M[6]];   // bool -> int32 per harness convention
    const int* mask = (const int*)d_in[M[7]];    // bool -> int32 per harness convention
    const float* w_in = (const float*)d_in[M[8]];
    const float* w_pair = (const float*)d_in[M[9]];
    const float* b_pair = (const float*)d_in[M[10]];
    const float* ln1_s = (const float*)d_in[M[11]];
    const float* ln1_o = (const float*)d_in[M[12]];
    const float* wq = (const float*)d_in[M[13]];
    const float* wk = (const float*)d_in[M[14]];
    const float* wv = (const float*)d_in[M[15]];
    const float* wqp = (const float*)d_in[M[16]];
    const float* wkp = (const float*)d_in[M[17]];
    const float* wvp = (const float*)d_in[M[18]];
    const float* wbm = (const float*)d_in[M[19]];
    const float* gamma = (const float*)d_in[M[20]];
    const float* wo = (const float*)d_in[M[21]];
    const float* bo = (const float*)d_in[M[22]];
    const float* ln2_s = (const float*)d_in[M[23]];
    const float* ln2_o = (const float*)d_in[M[24]];
    const float* wg = (const float*)d_in[M[25]];
    const float* wvm = (const float*)d_in[M[26]];
    const float* wom = (const float*)d_in[M[27]];
    const float* ln3_s = (const float*)d_in[M[28]];
    const float* ln3_o = (const float*)d_in[M[29]];
    const float* wpos = (const float*)d_in[M[30]];

    int N = in_sizes[0] / DMODEL;

    float* out_local = (float*)d_out;             // doubles as lup -> l2 -> final local
    float* out_pos = out_local + (size_t)N * DMODEL;

    // workspace: ~79 MB total @ N=16384
    char* wsb = (char*)d_ws;
    float* Rw = (float*)wsb;   wsb += (size_t)N * 9 * 4;
    float* lpw = (float*)wsb;  wsb += (size_t)N * 15 * 4;
    bf16* qbh = (bf16*)wsb;    wsb += (size_t)N * 256 * 2;
    bf16* kbh = (bf16*)wsb;    wsb += (size_t)N * 256 * 2;
    bf16* vbh = (bf16*)wsb;    wsb += (size_t)N * 256 * 2;
    bf16* qpl = (bf16*)wsb;    wsb += (size_t)N * 192 * 2;
    bf16* kpl = (bf16*)wsb;    wsb += (size_t)N * 192 * 2;
    bf16* vpl = (bf16*)wsb;    wsb += (size_t)N * 192 * 2;
    bf16* ipab = (bf16*)wsb;   wsb += (size_t)N * 1024 * 2;

    dim3 blk(256);
    hipLaunchKernelGGL(kA, dim3(N), blk, 0, stream, local, pos, w_in, Rw, lpw, out_local);
    hipLaunchKernelGGL(kB, dim3(N / TR), blk, 0, stream, out_local, ln1_s, ln1_o,
                       wq, wk, wv, wqp, wkp, wvp, qbh, kbh, vbh, qpl, kpl, vpl);
    hipLaunchKernelGGL(kC, dim3(N), blk, 0, stream, pos, nbr, resi, chain, batch, mask, Rw,
                       w_pair, b_pair, wbm, gamma, qbh, kbh, vbh, qpl, kpl, vpl, ipab, N);
    hipLaunchKernelGGL(kD, dim3(N / TR), blk, 0, stream, ipab, wo, bo, out_local);
    hipLaunchKernelGGL(kE, dim3(N / TR), blk, 0, stream, ln2_s, ln2_o, wg, wvm, wom, out_local);
    hipLaunchKernelGGL(kF, dim3(N), blk, 0, stream, out_local, ln3_s, ln3_o, wpos, lpw, Rw, pos,
                       umask, out_pos);
}

// Round 7
// 1433.589 us; speedup vs baseline: 1.5301x; 1.5301x over previous
//
#include <hip/hip_runtime.h>
#include <hip/hip_bf16.h>
#include <math.h>

#define DMODEL 256
#define KNB 32
#define NHEAD 8
#define FIN 95
#define FPAIR 162
#define FPD 95        // dense part of pair features
#define KPAD 104      // padded K for MFMA staging (breaks LDS bank alignment)
#define FOUT 1024
#define DHID 512
#define TR 8

typedef __hip_bfloat16 bf16;
typedef __attribute__((ext_vector_type(8))) short short8;
typedef __attribute__((ext_vector_type(4))) float floatx4;

__device__ inline float B2F(bf16 x) { return __bfloat162float(x); }
__device__ inline bf16 F2B(float x) { return __float2bfloat16(x); }
__device__ inline unsigned short f2bs(float x) {
    bf16 h = __float2bfloat16(x);
    return *reinterpret_cast<unsigned short*>(&h);
}
__device__ inline float bs2f(short s) {
    return __uint_as_float(((unsigned)(unsigned short)s) << 16);
}

__device__ inline float gelu_t(float x) {
    return 0.5f * x * (1.f + tanhf(0.7978845608028654f * (x + 0.044715f * x * x * x)));
}

// block-wide reduce of two values; block = 256 threads (4 waves)
__device__ inline void block_reduce2(float& a, float& b, float* sm) {
    __syncthreads();
    for (int off = 32; off > 0; off >>= 1) {
        a += __shfl_down(a, off);
        b += __shfl_down(b, off);
    }
    int lane = threadIdx.x & 63, w = threadIdx.x >> 6;
    if (lane == 0) { sm[w * 2] = a; sm[w * 2 + 1] = b; }
    __syncthreads();
    if (threadIdx.x == 0) {
        float sa = 0.f, sb = 0.f;
        for (int i = 0; i < 4; i++) { sa += sm[i * 2]; sb += sm[i * 2 + 1]; }
        sm[0] = sa; sm[1] = sb;
    }
    __syncthreads();
    a = sm[0]; b = sm[1];
}

// Kernel W: pre-transpose dense part of w_pair to bf16 [n=64][k=KPAD] (k-contiguous)
__global__ __launch_bounds__(256) void kW(const float* __restrict__ w_pair,
                                          unsigned short* __restrict__ wT) {
    int tid = threadIdx.x;
    for (int u = tid; u < 64 * KPAD; u += 256) {
        int n = u / KPAD, k = u % KPAD;
        wT[u] = (k < FPD) ? f2bs(w_pair[k * 64 + n]) : (unsigned short)0;
    }
}

// Kernel A: frames, local_pos, feat, lup = local + feat @ w_in  (lup -> d_out local region, f32)
__global__ __launch_bounds__(256) void kA(const float* __restrict__ local,
                                          const float* __restrict__ pos,
                                          const float* __restrict__ w_in,
                                          float* __restrict__ Rw,
                                          float* __restrict__ lpw,
                                          float* __restrict__ lup) {
    int i = blockIdx.x;
    int tid = threadIdx.x;
    const float* pp = pos + (size_t)i * 15;
    float nx = pp[0], ny = pp[1], nz = pp[2];
    float cax = pp[3], cay = pp[4], caz = pp[5];
    float cx = pp[6], cy = pp[7], cz = pp[8];
    float e1x = cx - cax, e1y = cy - cay, e1z = cz - caz;
    float inv = rsqrtf(e1x * e1x + e1y * e1y + e1z * e1z + 1e-6f);
    e1x *= inv; e1y *= inv; e1z *= inv;
    float ux = nx - cax, uy = ny - cay, uz = nz - caz;
    float d = ux * e1x + uy * e1y + uz * e1z;
    float wx = ux - d * e1x, wy = uy - d * e1y, wz = uz - d * e1z;
    inv = rsqrtf(wx * wx + wy * wy + wz * wz + 1e-6f);
    float e2x = wx * inv, e2y = wy * inv, e2z = wz * inv;
    float e3x = e1y * e2z - e1z * e2y;
    float e3y = e1z * e2x - e1x * e2z;
    float e3z = e1x * e2y - e1y * e2x;
    float R[9] = {e1x, e2x, e3x, e1y, e2y, e3y, e1z, e2z, e3z};

    __shared__ float lp[15];
    __shared__ float feat[FIN];
    __shared__ float dd[5], dinv[5];

    if (tid < 9) Rw[(size_t)i * 9 + tid] = R[tid];
    if (tid < 15) {
        int a = tid / 3, ii = tid % 3;
        float px = pp[a * 3 + 0] - cax, py = pp[a * 3 + 1] - cay, pz = pp[a * 3 + 2] - caz;
        float v = R[0 * 3 + ii] * px + R[1 * 3 + ii] * py + R[2 * 3 + ii] * pz;
        lp[tid] = v;
        lpw[(size_t)i * 15 + tid] = v;
    }
    __syncthreads();
    if (tid < 5) {
        float s = lp[tid * 3] * lp[tid * 3] + lp[tid * 3 + 1] * lp[tid * 3 + 1] + lp[tid * 3 + 2] * lp[tid * 3 + 2];
        dd[tid] = sqrtf(s + 1e-12f);
        dinv[tid] = rsqrtf(s + 1e-6f);
    }
    __syncthreads();
    if (tid < 15) {
        feat[tid] = lp[tid] * dinv[tid / 3];
    } else if (tid < 95) {
        int u = tid - 15, a = u >> 4, b = u & 15;
        float z = (dd[a] - (float)b * (10.f / 15.f)) * (1.f / 0.625f);
        feat[tid] = expf(-z * z);
    }
    __syncthreads();
    float acc = local[(size_t)i * DMODEL + tid];
    for (int f = 0; f < FIN; f++) acc += feat[f] * w_in[f * DMODEL + tid];
    lup[(size_t)i * DMODEL + tid] = acc;
}

// Kernel B: LN1 + 6 projections; q/k/v bf16, point projections stored in LOCAL frame bf16
__global__ __launch_bounds__(256) void kB(const float* __restrict__ lup,
                                          const float* __restrict__ ln1_s,
                                          const float* __restrict__ ln1_o,
                                          const float* __restrict__ wq,
                                          const float* __restrict__ wk,
                                          const float* __restrict__ wv,
                                          const float* __restrict__ wqp,
                                          const float* __restrict__ wkp,
                                          const float* __restrict__ wvp,
                                          bf16* __restrict__ qbh,
                                          bf16* __restrict__ kbh,
                                          bf16* __restrict__ vbh,
                                          bf16* __restrict__ qpl,
                                          bf16* __restrict__ kpl,
                                          bf16* __restrict__ vpl) {
    int r0 = blockIdx.x * TR;
    int tid = threadIdx.x;
    __shared__ float xn[TR][DMODEL];
    __shared__ float red[8];

    for (int r = 0; r < TR; r++) {
        float v = lup[(size_t)(r0 + r) * DMODEL + tid];
        float a = v, b = v * v;
        block_reduce2(a, b, red);
        float mu = a * (1.f / 256.f);
        float var = b * (1.f / 256.f) - mu * mu;
        xn[r][tid] = (v - mu) * rsqrtf(var + 1e-5f) * ln1_s[tid] + ln1_o[tid];
    }
    __syncthreads();
    for (int o = tid; o < 1344; o += 256) {
        const float* W; bf16* O; int col, ncol;
        if (o < 256)       { W = wq;  O = qbh; col = o;        ncol = 256; }
        else if (o < 512)  { W = wk;  O = kbh; col = o - 256;  ncol = 256; }
        else if (o < 768)  { W = wv;  O = vbh; col = o - 512;  ncol = 256; }
        else if (o < 960)  { W = wqp; O = qpl; col = o - 768;  ncol = 192; }
        else if (o < 1152) { W = wkp; O = kpl; col = o - 960;  ncol = 192; }
        else               { W = wvp; O = vpl; col = o - 1152; ncol = 192; }
        float acc[TR] = {0.f, 0.f, 0.f, 0.f, 0.f, 0.f, 0.f, 0.f};
        for (int f = 0; f < 256; f++) {
            float w = W[f * ncol + col];
#pragma unroll
            for (int r = 0; r < TR; r++) acc[r] += xn[r][f] * w;
        }
        for (int r = 0; r < TR; r++) O[(size_t)(r0 + r) * ncol + col] = F2B(acc[r]);
    }
}

// Kernel C: pair features (MFMA pair MLP) + attention + IPA concat (bf16 out)
__global__ __launch_bounds__(256) void kC(const float* __restrict__ pos,
                                          const int* __restrict__ nbr,
                                          const int* __restrict__ resi,
                                          const int* __restrict__ chain,
                                          const int* __restrict__ batch,
                                          const int* __restrict__ mask,
                                          const float* __restrict__ Rw,
                                          const float* __restrict__ w_pair,
                                          const unsigned short* __restrict__ wT,
                                          const float* __restrict__ b_pair,
                                          const float* __restrict__ wbm,
                                          const float* __restrict__ gamma,
                                          const bf16* __restrict__ qbh,
                                          const bf16* __restrict__ kbh,
                                          const bf16* __restrict__ vbh,
                                          const bf16* __restrict__ qpl,
                                          const bf16* __restrict__ kpl,
                                          const bf16* __restrict__ vpl,
                                          bf16* __restrict__ ipab,
                                          int N) {
    int i = blockIdx.x;
    int tid = threadIdx.x;
    __shared__ __align__(16) float qS[256];
    __shared__ __align__(16) float qpS[192];
    __shared__ __align__(16) unsigned short pfA[KNB * KPAD];   // dense pair features, bf16
    __shared__ __align__(16) float pairS[KNB][68];             // pair post-gelu (padded)
    __shared__ __align__(16) float wbmS[NHEAD][68];            // wbm transposed (padded)
    __shared__ float lg[KNB * NHEAD];
    __shared__ float optg[192];
    __shared__ float ipaS[FOUT];
    __shared__ float RjS[KNB][9];
    __shared__ float tjS[KNB][3];
    __shared__ int idxS[KNB], rpS[KNB], scS[KNB], sbS[KNB], pmS[KNB];

    float R[9];
#pragma unroll
    for (int u = 0; u < 9; u++) R[u] = Rw[(size_t)i * 9 + u];
    float t0 = pos[(size_t)i * 15 + 3];
    float t1 = pos[(size_t)i * 15 + 4];
    float t2 = pos[(size_t)i * 15 + 5];

    qS[tid] = B2F(qbh[(size_t)i * 256 + tid]);
    if (tid < KNB) {
        int nb = nbr[(size_t)i * KNB + tid];
        int j = min(max(nb, 0), N - 1);
        idxS[tid] = j;
        int rp = resi[j] - resi[i];
        rp = min(max(rp, -32), 32) + 32;
        rpS[tid] = rp;
        scS[tid] = (chain[j] == chain[i]) ? 1 : 0;
        sbS[tid] = (batch[j] == batch[i]) ? 1 : 0;
        pmS[tid] = (mask[i] != 0 && mask[j] != 0 && nb >= 0 && batch[j] == batch[i]) ? 1 : 0;
    }
    __syncthreads();
    // gather neighbour frames
    for (int u = tid; u < KNB * 9; u += 256) RjS[u / 9][u % 9] = Rw[(size_t)idxS[u / 9] * 9 + (u % 9)];
    if (tid < KNB * 3) tjS[tid / 3][tid % 3] = pos[(size_t)idxS[tid / 3] * 15 + 3 + (tid % 3)];
    // wbm transpose stage
    for (int u = tid; u < 512; u += 256) {
        int h = u & 7, c = u >> 3;
        wbmS[h][c] = wbm[c * 8 + h];
    }
    // qp -> global frame (f32)
    if (tid < 192) {
        int hp = tid / 3, ii = tid % 3;
        float p0 = B2F(qpl[(size_t)i * 192 + hp * 3 + 0]);
        float p1 = B2F(qpl[(size_t)i * 192 + hp * 3 + 1]);
        float p2 = B2F(qpl[(size_t)i * 192 + hp * 3 + 2]);
        float tc = (ii == 0) ? t0 : (ii == 1 ? t1 : t2);
        qpS[tid] = R[ii * 3 + 0] * p0 + R[ii * 3 + 1] * p1 + R[ii * 3 + 2] * p2 + tc;
    }
    // dirs + rbf(dij) -> pfA (bf16, dense only); 160 threads = 32 neighbours x 5 atoms
    if (tid < 160) {
        int kk = tid & 31, a = tid >> 5;
        int j = idxS[kk];
        const float* pj = pos + (size_t)j * 15 + a * 3;
        float px = pj[0] - t0, py = pj[1] - t1, pz = pj[2] - t2;
        float r0_ = R[0] * px + R[3] * py + R[6] * pz;
        float r1_ = R[1] * px + R[4] * py + R[7] * pz;
        float r2_ = R[2] * px + R[5] * py + R[8] * pz;
        float s = r0_ * r0_ + r1_ * r1_ + r2_ * r2_;
        float dij = sqrtf(s + 1e-12f);
        float di = 1.f / (dij + 1e-6f);
        pfA[kk * KPAD + a * 3 + 0] = f2bs(r0_ * di);
        pfA[kk * KPAD + a * 3 + 1] = f2bs(r1_ * di);
        pfA[kk * KPAD + a * 3 + 2] = f2bs(r2_ * di);
        for (int b = 0; b < 16; b++) {
            float z = (dij - (float)b * (10.f / 15.f)) * (1.f / 0.625f);
            pfA[kk * KPAD + 15 + a * 16 + b] = f2bs(expf(-z * z));
        }
    }
    if (tid < KNB) pfA[tid * KPAD + FPD] = 0;  // k index 95 is touched by the 3rd K-step
    __syncthreads();

    // ---- pair MLP via MFMA: (32 x 96 bf16) @ (96 x 64 bf16) -> 32 x 64 f32 ----
    {
        int lane = tid & 63;
        int wv = tid >> 6;           // wave -> N-tile
        int n0 = wv * 16;
        int mrow = lane & 15;
        int quad = lane >> 4;
        floatx4 c0 = {0.f, 0.f, 0.f, 0.f};
        floatx4 c1 = {0.f, 0.f, 0.f, 0.f};
#pragma unroll
        for (int ks = 0; ks < 3; ks++) {
            int k0 = ks * 32 + quad * 8;
            short8 a0 = *reinterpret_cast<const short8*>(&pfA[mrow * KPAD + k0]);
            short8 a1 = *reinterpret_cast<const short8*>(&pfA[(16 + mrow) * KPAD + k0]);
            short8 bb = *reinterpret_cast<const short8*>(&wT[(n0 + mrow) * KPAD + k0]);
            c0 = __builtin_amdgcn_mfma_f32_16x16x32_bf16(a0, bb, c0, 0, 0, 0);
            c1 = __builtin_amdgcn_mfma_f32_16x16x32_bf16(a1, bb, c1, 0, 0, 0);
        }
        // epilogue: + bias + one-hot relpos/chain/batch contributions, gelu
        int col = n0 + mrow;
        float bp = b_pair[col];
        float w160 = w_pair[160 * 64 + col];
        float w161 = w_pair[161 * 64 + col];
#pragma unroll
        for (int mt = 0; mt < 2; mt++) {
            floatx4 cc = mt ? c1 : c0;
#pragma unroll
            for (int r = 0; r < 4; r++) {
                int row = mt * 16 + quad * 4 + r;
                float s = cc[r] + bp + w_pair[(95 + rpS[row]) * 64 + col] +
                          (scS[row] ? w160 : 0.f) + (sbS[row] ? w161 : 0.f);
                pairS[row][col] = gelu_t(s);
            }
        }
    }
    __syncthreads();

    // ---- logits (vectorized loads) ----
    {
        int kk = tid >> 3, h = tid & 7;
        int j = idxS[kk];
        // qk dot (k in bf16x8 chunks)
        float qk = 0.f;
        const short8* kj8 = reinterpret_cast<const short8*>(kbh + (size_t)j * 256 + h * 32);
        const floatx4* qh4 = reinterpret_cast<const floatx4*>(qS + h * 32);
#pragma unroll
        for (int e = 0; e < 4; e++) {
            short8 kv = kj8[e];
            floatx4 qa = qh4[2 * e], qb = qh4[2 * e + 1];
            qk += qa[0] * bs2f(kv[0]) + qa[1] * bs2f(kv[1]) + qa[2] * bs2f(kv[2]) + qa[3] * bs2f(kv[3]) +
                  qb[0] * bs2f(kv[4]) + qb[1] * bs2f(kv[5]) + qb[2] * bs2f(kv[6]) + qb[3] * bs2f(kv[7]);
        }
        qk *= 0.17677669529663687f;  // 1/sqrt(32)
        // point distance term
        float kparr[24], qparr[24];
        {
            const short8* kp8 = reinterpret_cast<const short8*>(kpl + (size_t)j * 192 + h * 24);
#pragma unroll
            for (int e = 0; e < 3; e++) {
                short8 v = kp8[e];
#pragma unroll
                for (int q = 0; q < 8; q++) kparr[e * 8 + q] = bs2f(v[q]);
            }
            const floatx4* qp4 = reinterpret_cast<const floatx4*>(qpS + h * 24);
#pragma unroll
            for (int e = 0; e < 6; e++) {
                floatx4 v = qp4[e];
#pragma unroll
                for (int q = 0; q < 4; q++) qparr[e * 4 + q] = v[q];
            }
        }
        float Rj[9], tj[3];
#pragma unroll
        for (int u = 0; u < 9; u++) Rj[u] = RjS[kk][u];
#pragma unroll
        for (int u = 0; u < 3; u++) tj[u] = tjS[kk][u];
        float d2 = 0.f;
#pragma unroll
        for (int p = 0; p < 8; p++) {
            float p0 = kparr[p * 3 + 0], p1 = kparr[p * 3 + 1], p2 = kparr[p * 3 + 2];
#pragma unroll
            for (int ii = 0; ii < 3; ii++) {
                float kpv = Rj[ii * 3 + 0] * p0 + Rj[ii * 3 + 1] * p1 + Rj[ii * 3 + 2] * p2 + tj[ii];
                float df = qparr[p * 3 + ii] - kpv;
                d2 += df * df;
            }
        }
        // pair bias
        float pb = 0.f;
        const floatx4* ps4 = reinterpret_cast<const floatx4*>(&pairS[kk][0]);
        const floatx4* wb4 = reinterpret_cast<const floatx4*>(&wbmS[h][0]);
#pragma unroll
        for (int e = 0; e < 16; e++) {
            floatx4 pv = ps4[e], wv4 = wb4[e];
            pb += pv[0] * wv4[0] + pv[1] * wv4[1] + pv[2] * wv4[2] + pv[3] * wv4[3];
        }
        float sp = log1pf(expf(gamma[h]));
        float lgt = 0.5773502691896258f * (qk + pb - (1.f / 12.f) * sp * d2);
        lg[kk * 8 + h] = pmS[kk] ? lgt : -1e9f;
    }
    __syncthreads();
    // softmax over kk per head; zero masked
    if (tid < 8) {
        int h = tid;
        float m = -INFINITY;
        for (int kk = 0; kk < KNB; kk++) m = fmaxf(m, lg[kk * 8 + h]);
        float s = 0.f;
        for (int kk = 0; kk < KNB; kk++) s += expf(lg[kk * 8 + h] - m);
        float invs = 1.f / s;
        for (int kk = 0; kk < KNB; kk++) {
            float a = expf(lg[kk * 8 + h] - m) * invs;
            lg[kk * 8 + h] = pmS[kk] ? a : 0.f;
        }
    }
    __syncthreads();
    // o_s
    {
        int h = tid >> 5, d = tid & 31;
        float s = 0.f;
        for (int kk = 0; kk < KNB; kk++)
            s += lg[kk * 8 + h] * B2F(vbh[(size_t)idxS[kk] * 256 + h * 32 + d]);
        ipaS[h * 32 + d] = s;
    }
    // o_pr
    for (int u = tid; u < 512; u += 256) {
        int h = u >> 6, c = u & 63;
        float s = 0.f;
        for (int kk = 0; kk < KNB; kk++) s += lg[kk * 8 + h] * pairS[kk][c];
        ipaS[256 + u] = s;
    }
    // o_pt global: rotate neighbour vp points on the fly
    if (tid < 192) {
        int ii = tid % 3, hp = tid / 3, h = hp >> 3;
        float s = 0.f;
        for (int kk = 0; kk < KNB; kk++) {
            const bf16* vpj = vpl + (size_t)idxS[kk] * 192 + hp * 3;
            float vg = RjS[kk][ii * 3 + 0] * B2F(vpj[0]) + RjS[kk][ii * 3 + 1] * B2F(vpj[1]) +
                       RjS[kk][ii * 3 + 2] * B2F(vpj[2]) + tjS[kk][ii];
            s += lg[kk * 8 + h] * vg;
        }
        optg[tid] = s;
    }
    __syncthreads();
    // o_pt -> local frame
    if (tid < 192) {
        int hp = tid / 3, ii = tid % 3;
        float v0 = optg[hp * 3 + 0] - t0, v1 = optg[hp * 3 + 1] - t1, v2 = optg[hp * 3 + 2] - t2;
        ipaS[768 + tid] = R[0 + ii] * v0 + R[3 + ii] * v1 + R[6 + ii] * v2;
    }
    __syncthreads();
    if (tid < 64) {
        float a0 = ipaS[768 + tid * 3], a1 = ipaS[768 + tid * 3 + 1], a2 = ipaS[768 + tid * 3 + 2];
        ipaS[960 + tid] = sqrtf(a0 * a0 + a1 * a1 + a2 * a2 + 1e-8f);
    }
    __syncthreads();
    for (int u = tid; u < FOUT; u += 256) ipab[(size_t)i * FOUT + u] = F2B(ipaS[u]);
}

// Kernel D: d_out_local = lup + ipa @ wo + bo  (in-place on d_out)
__global__ __launch_bounds__(256) void kD(const bf16* __restrict__ ipab,
                                          const float* __restrict__ wo,
                                          const float* __restrict__ bo,
                                          float* __restrict__ dlocal) {
    int r0 = blockIdx.x * TR;
    int tid = threadIdx.x;
    __shared__ float ipaL[TR][FOUT];
    for (int u = tid; u < TR * FOUT; u += 256)
        ipaL[u >> 10][u & 1023] = B2F(ipab[(size_t)r0 * FOUT + u]);
    __syncthreads();
    float acc[TR] = {0.f, 0.f, 0.f, 0.f, 0.f, 0.f, 0.f, 0.f};
    for (int f = 0; f < FOUT; f++) {
        float w = wo[f * 256 + tid];
#pragma unroll
        for (int r = 0; r < TR; r++) acc[r] += ipaL[r][f] * w;
    }
    float bov = bo[tid];
    for (int r = 0; r < TR; r++) {
        size_t off = (size_t)(r0 + r) * 256 + tid;
        dlocal[off] = dlocal[off] + acc[r] + bov;
    }
}

// Kernel E: transition MLP in-place on d_out local region
__global__ __launch_bounds__(256) void kE(const float* __restrict__ ln2_s,
                                          const float* __restrict__ ln2_o,
                                          const float* __restrict__ wg,
                                          const float* __restrict__ wvm,
                                          const float* __restrict__ wom,
                                          float* __restrict__ dlocal) {
    int r0 = blockIdx.x * TR;
    int tid = threadIdx.x;
    __shared__ float x2[TR][DMODEL];
    __shared__ float hS[TR][DHID];
    __shared__ float red[8];
    float lv[TR];
    for (int r = 0; r < TR; r++) {
        float v = dlocal[(size_t)(r0 + r) * DMODEL + tid];
        lv[r] = v;
        float a = v, b = v * v;
        block_reduce2(a, b, red);
        float mu = a * (1.f / 256.f);
        float var = b * (1.f / 256.f) - mu * mu;
        x2[r][tid] = (v - mu) * rsqrtf(var + 1e-5f) * ln2_s[tid] + ln2_o[tid];
    }
    __syncthreads();
    for (int o = tid; o < DHID; o += 256) {
        float ag[TR] = {0.f, 0.f, 0.f, 0.f, 0.f, 0.f, 0.f, 0.f};
        float av[TR] = {0.f, 0.f, 0.f, 0.f, 0.f, 0.f, 0.f, 0.f};
        for (int f = 0; f < 256; f++) {
            float wgv = wg[f * DHID + o], wvv = wvm[f * DHID + o];
#pragma unroll
            for (int r = 0; r < TR; r++) { ag[r] += x2[r][f] * wgv; av[r] += x2[r][f] * wvv; }
        }
        for (int r = 0; r < TR; r++) hS[r][o] = gelu_t(ag[r]) * av[r];
    }
    __syncthreads();
    float acc[TR] = {0.f, 0.f, 0.f, 0.f, 0.f, 0.f, 0.f, 0.f};
    for (int f = 0; f < DHID; f++) {
        float w = wom[f * 256 + tid];
#pragma unroll
        for (int r = 0; r < TR; r++) acc[r] += hS[r][f] * w;
    }
    for (int r = 0; r < TR; r++)
        dlocal[(size_t)(r0 + r) * DMODEL + tid] = lv[r] + acc[r];
}

// Kernel F: LN3 + wpos + frame transform + update_mask; writes pos output (f32)
__global__ __launch_bounds__(256) void kF(const float* __restrict__ dlocal,
                                          const float* __restrict__ ln3_s,
                                          const float* __restrict__ ln3_o,
                                          const float* __restrict__ wpos,
                                          const float* __restrict__ lpw,
                                          const float* __restrict__ Rw,
                                          const float* __restrict__ pos,
                                          const int* __restrict__ umask,
                                          float* __restrict__ outp) {
    int i = blockIdx.x;
    int tid = threadIdx.x;
    __shared__ float x3[256];
    __shared__ float red[8];
    __shared__ float nl[15];
    float v = dlocal[(size_t)i * DMODEL + tid];
    float a = v, b = v * v;
    block_reduce2(a, b, red);
    float mu = a * (1.f / 256.f);
    float var = b * (1.f / 256.f) - mu * mu;
    x3[tid] = (v - mu) * rsqrtf(var + 1e-5f) * ln3_s[tid] + ln3_o[tid];
    __syncthreads();
    if (tid < 15) {
        float s = 0.f;
        for (int f = 0; f < 256; f++) s += x3[f] * wpos[f * 15 + tid];
        nl[tid] = lpw[(size_t)i * 15 + tid] + s;
    }
    __syncthreads();
    if (tid < 15) {
        int a2 = tid / 3, ii = tid % 3;
        float R0 = Rw[(size_t)i * 9 + ii * 3 + 0];
        float R1 = Rw[(size_t)i * 9 + ii * 3 + 1];
        float R2 = Rw[(size_t)i * 9 + ii * 3 + 2];
        float tt = pos[(size_t)i * 15 + 3 + ii];
        float np = R0 * nl[a2 * 3 + 0] + R1 * nl[a2 * 3 + 1] + R2 * nl[a2 * 3 + 2] + tt;
        float old = pos[(size_t)i * 15 + tid];
        outp[(size_t)i * 15 + tid] = (umask[i] != 0) ? np : old;
    }
}

extern "C" void kernel_launch(void* const* d_in, const int* in_sizes, int n_in,
                              void* d_out, int out_size, void* d_ws, size_t ws_size,
                              hipStream_t stream) {
    static const int map_dict[31] = {0, 1, 2, 3, 4, 5, 6, 7, 8, 9, 10, 11, 12, 13, 14, 15,
                                     16, 17, 18, 19, 20, 21, 22, 23, 24, 25, 26, 27, 28, 29, 30};
    static const int map_sig[31] = {0, 1, 25, 26, 27, 28, 29, 30, 2, 3, 4, 5, 6, 7, 8, 9,
                                    10, 11, 12, 13, 14, 15, 16, 17, 18, 19, 20, 21, 22, 23, 24};
    const int* M = (in_sizes[2] == FIN * DMODEL) ? map_sig : map_dict;

    const float* local = (const float*)d_in[M[0]];
    const float* pos = (const float*)d_in[M[1]];
    const int* nbr = (const int*)d_in[M[2]];
    const int* resi = (const int*)d_in[M[3]];
    const int* chain = (const int*)d_in[M[4]];
    const int* batch = (const int*)d_in[M[5]];
    const int* umask = (const int*)d_in[M[6]];
    const int* mask = (const int*)d_in[M[7]];
    const float* w_in = (const float*)d_in[M[8]];
    const float* w_pair = (const float*)d_in[M[9]];
    const float* b_pair = (const float*)d_in[M[10]];
    const float* ln1_s = (const float*)d_in[M[11]];
    const float* ln1_o = (const float*)d_in[M[12]];
    const float* wq = (const float*)d_in[M[13]];
    const float* wk = (const float*)d_in[M[14]];
    const float* wv = (const float*)d_in[M[15]];
    const float* wqp = (const float*)d_in[M[16]];
    const float* wkp = (const float*)d_in[M[17]];
    const float* wvp = (const float*)d_in[M[18]];
    const float* wbm = (const float*)d_in[M[19]];
    const float* gamma = (const float*)d_in[M[20]];
    const float* wo = (const float*)d_in[M[21]];
    const float* bo = (const float*)d_in[M[22]];
    const float* ln2_s = (const float*)d_in[M[23]];
    const float* ln2_o = (const float*)d_in[M[24]];
    const float* wg = (const float*)d_in[M[25]];
    const float* wvm = (const float*)d_in[M[26]];
    const float* wom = (const float*)d_in[M[27]];
    const float* ln3_s = (const float*)d_in[M[28]];
    const float* ln3_o = (const float*)d_in[M[29]];
    const float* wpos = (const float*)d_in[M[30]];

    int N = in_sizes[0] / DMODEL;

    float* out_local = (float*)d_out;             // doubles as lup -> l2 -> final local
    float* out_pos = out_local + (size_t)N * DMODEL;

    char* wsb = (char*)d_ws;
    float* Rw = (float*)wsb;   wsb += (size_t)N * 9 * 4;
    float* lpw = (float*)wsb;  wsb += (size_t)N * 15 * 4;
    bf16* qbh = (bf16*)wsb;    wsb += (size_t)N * 256 * 2;
    bf16* kbh = (bf16*)wsb;    wsb += (size_t)N * 256 * 2;
    bf16* vbh = (bf16*)wsb;    wsb += (size_t)N * 256 * 2;
    bf16* qpl = (bf16*)wsb;    wsb += (size_t)N * 192 * 2;
    bf16* kpl = (bf16*)wsb;    wsb += (size_t)N * 192 * 2;
    bf16* vpl = (bf16*)wsb;    wsb += (size_t)N * 192 * 2;
    bf16* ipab = (bf16*)wsb;   wsb += (size_t)N * 1024 * 2;
    unsigned short* wT = (unsigned short*)wsb; wsb += (size_t)64 * KPAD * 2;

    dim3 blk(256);
    hipLaunchKernelGGL(kW, dim3(1), blk, 0, stream, w_pair, wT);
    hipLaunchKernelGGL(kA, dim3(N), blk, 0, stream, local, pos, w_in, Rw, lpw, out_local);
    hipLaunchKernelGGL(kB, dim3(N / TR), blk, 0, stream, out_local, ln1_s, ln1_o,
                       wq, wk, wv, wqp, wkp, wvp, qbh, kbh, vbh, qpl, kpl, vpl);
    hipLaunchKernelGGL(kC, dim3(N), blk, 0, stream, pos, nbr, resi, chain, batch, mask, Rw,
                       w_pair, wT, b_pair, wbm, gamma, qbh, kbh, vbh, qpl, kpl, vpl, ipab, N);
    hipLaunchKernelGGL(kD, dim3(N / TR), blk, 0, stream, ipab, wo, bo, out_local);
    hipLaunchKernelGGL(kE, dim3(N / TR), blk, 0, stream, ln2_s, ln2_o, wg, wvm, wom, out_local);
    hipLaunchKernelGGL(kF, dim3(N), blk, 0, stream, out_local, ln3_s, ln3_o, wpos, lpw, Rw, pos,
                       umask, out_pos);
}

// Round 8
// 846.738 us; speedup vs baseline: 2.5905x; 1.6931x over previous
//
#include <hip/hip_runtime.h>
#include <hip/hip_bf16.h>
#include <math.h>

#define DMODEL 256
#define KNB 32
#define NHEAD 8
#define FIN 95
#define FPD 95        // dense part of pair features
#define KPAD 104      // padded K for pair MFMA staging
#define FOUT 1024
#define DHID 512

typedef __hip_bfloat16 bf16;
typedef __attribute__((ext_vector_type(8))) short short8;
typedef __attribute__((ext_vector_type(4))) float floatx4;

__device__ inline float B2F(bf16 x) { return __bfloat162float(x); }
__device__ inline bf16 F2B(float x) { return __float2bfloat16(x); }
__device__ inline unsigned short f2bs(float x) {
    bf16 h = __float2bfloat16(x);
    return *reinterpret_cast<unsigned short*>(&h);
}
__device__ inline float bs2f(short s) {
    return __uint_as_float(((unsigned)(unsigned short)s) << 16);
}

__device__ inline float gelu_t(float x) {
    return 0.5f * x * (1.f + tanhf(0.7978845608028654f * (x + 0.044715f * x * x * x)));
}

// block-wide reduce of two values; block = 256 threads (4 waves)
__device__ inline void block_reduce2(float& a, float& b, float* sm) {
    __syncthreads();
    for (int off = 32; off > 0; off >>= 1) {
        a += __shfl_down(a, off);
        b += __shfl_down(b, off);
    }
    int lane = threadIdx.x & 63, w = threadIdx.x >> 6;
    if (lane == 0) { sm[w * 2] = a; sm[w * 2 + 1] = b; }
    __syncthreads();
    if (threadIdx.x == 0) {
        float sa = 0.f, sb = 0.f;
        for (int i = 0; i < 4; i++) { sa += sm[i * 2]; sb += sm[i * 2 + 1]; }
        sm[0] = sa; sm[1] = sb;
    }
    __syncthreads();
    a = sm[0]; b = sm[1];
}

// ---- weight transpose buffer layout (bf16 elements) ----
#define OFF_WALL 0          // [1344][256]  q|k|v|qp|kp|vp columns
#define OFF_WO   344064     // [256][1024]
#define OFF_WG   606208     // [512][256]
#define OFF_WVM  737280     // [512][256]
#define OFF_WOM  868352     // [256][512]
#define OFF_WP   999424     // [64][KPAD]
#define WT_TOTAL 1006080

// Kernel T: transpose/convert all weights to bf16 [n][k] (k-contiguous)
__global__ __launch_bounds__(256) void kT(const float* __restrict__ wq, const float* __restrict__ wk,
                                          const float* __restrict__ wv, const float* __restrict__ wqp,
                                          const float* __restrict__ wkp, const float* __restrict__ wvp,
                                          const float* __restrict__ wo, const float* __restrict__ wg,
                                          const float* __restrict__ wvm, const float* __restrict__ wom,
                                          const float* __restrict__ w_pair,
                                          unsigned short* __restrict__ wt) {
    int stride = gridDim.x * 256;
    for (int e = blockIdx.x * 256 + threadIdx.x; e < WT_TOTAL; e += stride) {
        float v;
        if (e < OFF_WO) {
            int n = e >> 8, k = e & 255;
            if (n < 256) v = wq[k * 256 + n];
            else if (n < 512) v = wk[k * 256 + n - 256];
            else if (n < 768) v = wv[k * 256 + n - 512];
            else if (n < 960) v = wqp[k * 192 + n - 768];
            else if (n < 1152) v = wkp[k * 192 + n - 960];
            else v = wvp[k * 192 + n - 1152];
        } else if (e < OFF_WG) {
            int u = e - OFF_WO; int n = u >> 10, k = u & 1023;
            v = wo[k * 256 + n];
        } else if (e < OFF_WVM) {
            int u = e - OFF_WG; int n = u >> 8, k = u & 255;
            v = wg[k * 512 + n];
        } else if (e < OFF_WOM) {
            int u = e - OFF_WVM; int n = u >> 8, k = u & 255;
            v = wvm[k * 512 + n];
        } else if (e < OFF_WP) {
            int u = e - OFF_WOM; int n = u >> 9, k = u & 511;
            v = wom[k * 256 + n];
        } else {
            int u = e - OFF_WP; int n = u / KPAD, k = u % KPAD;
            v = (k < FPD) ? w_pair[k * 64 + n] : 0.f;
        }
        wt[e] = f2bs(v);
    }
}

// Kernel A: frames, local_pos, feat, lup = local + feat @ w_in  (-> d_out local region, f32)
__global__ __launch_bounds__(256) void kA(const float* __restrict__ local,
                                          const float* __restrict__ pos,
                                          const float* __restrict__ w_in,
                                          float* __restrict__ Rw,
                                          float* __restrict__ lpw,
                                          float* __restrict__ lup) {
    int i = blockIdx.x;
    int tid = threadIdx.x;
    const float* pp = pos + (size_t)i * 15;
    float nx = pp[0], ny = pp[1], nz = pp[2];
    float cax = pp[3], cay = pp[4], caz = pp[5];
    float cx = pp[6], cy = pp[7], cz = pp[8];
    float e1x = cx - cax, e1y = cy - cay, e1z = cz - caz;
    float inv = rsqrtf(e1x * e1x + e1y * e1y + e1z * e1z + 1e-6f);
    e1x *= inv; e1y *= inv; e1z *= inv;
    float ux = nx - cax, uy = ny - cay, uz = nz - caz;
    float d = ux * e1x + uy * e1y + uz * e1z;
    float wx = ux - d * e1x, wy = uy - d * e1y, wz = uz - d * e1z;
    inv = rsqrtf(wx * wx + wy * wy + wz * wz + 1e-6f);
    float e2x = wx * inv, e2y = wy * inv, e2z = wz * inv;
    float e3x = e1y * e2z - e1z * e2y;
    float e3y = e1z * e2x - e1x * e2z;
    float e3z = e1x * e2y - e1y * e2x;
    float R[9] = {e1x, e2x, e3x, e1y, e2y, e3y, e1z, e2z, e3z};

    __shared__ float lp[15];
    __shared__ float feat[FIN];
    __shared__ float dd[5], dinv[5];

    if (tid < 9) Rw[(size_t)i * 9 + tid] = R[tid];
    if (tid < 15) {
        int a = tid / 3, ii = tid % 3;
        float px = pp[a * 3 + 0] - cax, py = pp[a * 3 + 1] - cay, pz = pp[a * 3 + 2] - caz;
        float v = R[0 * 3 + ii] * px + R[1 * 3 + ii] * py + R[2 * 3 + ii] * pz;
        lp[tid] = v;
        lpw[(size_t)i * 15 + tid] = v;
    }
    __syncthreads();
    if (tid < 5) {
        float s = lp[tid * 3] * lp[tid * 3] + lp[tid * 3 + 1] * lp[tid * 3 + 1] + lp[tid * 3 + 2] * lp[tid * 3 + 2];
        dd[tid] = sqrtf(s + 1e-12f);
        dinv[tid] = rsqrtf(s + 1e-6f);
    }
    __syncthreads();
    if (tid < 15) {
        feat[tid] = lp[tid] * dinv[tid / 3];
    } else if (tid < 95) {
        int u = tid - 15, a = u >> 4, b = u & 15;
        float z = (dd[a] - (float)b * (10.f / 15.f)) * (1.f / 0.625f);
        feat[tid] = expf(-z * z);
    }
    __syncthreads();
    float acc = local[(size_t)i * DMODEL + tid];
    for (int f = 0; f < FIN; f++) acc += feat[f] * w_in[f * DMODEL + tid];
    lup[(size_t)i * DMODEL + tid] = acc;
}

// Kernel B: LN1 + all 6 projections via MFMA. 32 rows/block.
__global__ __launch_bounds__(256) void kB(const float* __restrict__ lup,
                                          const float* __restrict__ ln1_s,
                                          const float* __restrict__ ln1_o,
                                          const unsigned short* __restrict__ wAllT,
                                          bf16* __restrict__ qbh, bf16* __restrict__ kbh,
                                          bf16* __restrict__ vbh, bf16* __restrict__ qpl,
                                          bf16* __restrict__ kpl, bf16* __restrict__ vpl) {
    int r0 = blockIdx.x * 32;
    int tid = threadIdx.x;
    __shared__ __align__(16) unsigned short xbf[32 * 264];
    {
        int row = tid >> 3, seg = tid & 7;
        const floatx4* src = reinterpret_cast<const floatx4*>(lup + (size_t)(r0 + row) * 256 + seg * 32);
        floatx4 vv[8];
        float s = 0.f, ss = 0.f;
#pragma unroll
        for (int e = 0; e < 8; e++) {
            vv[e] = src[e];
#pragma unroll
            for (int q = 0; q < 4; q++) { s += vv[e][q]; ss += vv[e][q] * vv[e][q]; }
        }
        s += __shfl_xor(s, 1); ss += __shfl_xor(ss, 1);
        s += __shfl_xor(s, 2); ss += __shfl_xor(ss, 2);
        s += __shfl_xor(s, 4); ss += __shfl_xor(ss, 4);
        float mu = s * (1.f / 256.f);
        float var = ss * (1.f / 256.f) - mu * mu;
        float rs = rsqrtf(var + 1e-5f);
#pragma unroll
        for (int e = 0; e < 8; e++) {
#pragma unroll
            for (int q = 0; q < 4; q++) {
                int f = seg * 32 + e * 4 + q;
                xbf[row * 264 + f] = f2bs((vv[e][q] - mu) * rs * ln1_s[f] + ln1_o[f]);
            }
        }
    }
    __syncthreads();
    int lane = tid & 63, w = tid >> 6;
    int mtile = w & 1, m = lane & 15, quad = lane >> 4;
    short8 afr[8];
#pragma unroll
    for (int ks = 0; ks < 8; ks++)
        afr[ks] = *reinterpret_cast<const short8*>(&xbf[(mtile * 16 + m) * 264 + ks * 32 + quad * 8]);
    for (int nt = (w >> 1); nt < 84; nt += 2) {
        floatx4 c = {0.f, 0.f, 0.f, 0.f};
        const short8* bp = reinterpret_cast<const short8*>(wAllT + (size_t)(nt * 16 + m) * 256);
#pragma unroll
        for (int ks = 0; ks < 8; ks++)
            c = __builtin_amdgcn_mfma_f32_16x16x32_bf16(afr[ks], bp[ks * 4 + quad], c, 0, 0, 0);
        int colg = nt * 16 + m;
        bf16* O; int c0, ncol;
        if (colg < 256)       { O = qbh; c0 = colg;        ncol = 256; }
        else if (colg < 512)  { O = kbh; c0 = colg - 256;  ncol = 256; }
        else if (colg < 768)  { O = vbh; c0 = colg - 512;  ncol = 256; }
        else if (colg < 960)  { O = qpl; c0 = colg - 768;  ncol = 192; }
        else if (colg < 1152) { O = kpl; c0 = colg - 960;  ncol = 192; }
        else                  { O = vpl; c0 = colg - 1152; ncol = 192; }
#pragma unroll
        for (int r = 0; r < 4; r++) {
            int rg = r0 + mtile * 16 + quad * 4 + r;
            O[(size_t)rg * ncol + c0] = F2B(c[r]);
        }
    }
}

// Kernel C: pair features (MFMA pair MLP) + attention + IPA concat (bf16 out)
__global__ __launch_bounds__(256) void kC(const float* __restrict__ pos,
                                          const int* __restrict__ nbr,
                                          const int* __restrict__ resi,
                                          const int* __restrict__ chain,
                                          const int* __restrict__ batch,
                                          const int* __restrict__ mask,
                                          const float* __restrict__ Rw,
                                          const float* __restrict__ w_pair,
                                          const unsigned short* __restrict__ wT,
                                          const float* __restrict__ b_pair,
                                          const float* __restrict__ wbm,
                                          const float* __restrict__ gamma,
                                          const bf16* __restrict__ qbh,
                                          const bf16* __restrict__ kbh,
                                          const bf16* __restrict__ vbh,
                                          const bf16* __restrict__ qpl,
                                          const bf16* __restrict__ kpl,
                                          const bf16* __restrict__ vpl,
                                          bf16* __restrict__ ipab,
                                          int N) {
    int i = blockIdx.x;
    int tid = threadIdx.x;
    __shared__ __align__(16) float qS[256];
    __shared__ __align__(16) float qpS[192];
    __shared__ __align__(16) unsigned short pfA[KNB * KPAD];
    __shared__ __align__(16) float pairS[KNB][68];
    __shared__ __align__(16) float wbmS[NHEAD][68];
    __shared__ float lg[KNB * NHEAD];
    __shared__ float optg[192];
    __shared__ float ipaS[FOUT];
    __shared__ float RjS[KNB][9];
    __shared__ float tjS[KNB][3];
    __shared__ int idxS[KNB], rpS[KNB], scS[KNB], sbS[KNB], pmS[KNB];

    float R[9];
#pragma unroll
    for (int u = 0; u < 9; u++) R[u] = Rw[(size_t)i * 9 + u];
    float t0 = pos[(size_t)i * 15 + 3];
    float t1 = pos[(size_t)i * 15 + 4];
    float t2 = pos[(size_t)i * 15 + 5];

    qS[tid] = B2F(qbh[(size_t)i * 256 + tid]);
    if (tid < KNB) {
        int nb = nbr[(size_t)i * KNB + tid];
        int j = min(max(nb, 0), N - 1);
        idxS[tid] = j;
        int rp = resi[j] - resi[i];
        rp = min(max(rp, -32), 32) + 32;
        rpS[tid] = rp;
        scS[tid] = (chain[j] == chain[i]) ? 1 : 0;
        sbS[tid] = (batch[j] == batch[i]) ? 1 : 0;
        pmS[tid] = (mask[i] != 0 && mask[j] != 0 && nb >= 0 && batch[j] == batch[i]) ? 1 : 0;
    }
    __syncthreads();
    for (int u = tid; u < KNB * 9; u += 256) RjS[u / 9][u % 9] = Rw[(size_t)idxS[u / 9] * 9 + (u % 9)];
    if (tid < KNB * 3) tjS[tid / 3][tid % 3] = pos[(size_t)idxS[tid / 3] * 15 + 3 + (tid % 3)];
    for (int u = tid; u < 512; u += 256) {
        int h = u & 7, c = u >> 3;
        wbmS[h][c] = wbm[c * 8 + h];
    }
    if (tid < 192) {
        int hp = tid / 3, ii = tid % 3;
        float p0 = B2F(qpl[(size_t)i * 192 + hp * 3 + 0]);
        float p1 = B2F(qpl[(size_t)i * 192 + hp * 3 + 1]);
        float p2 = B2F(qpl[(size_t)i * 192 + hp * 3 + 2]);
        float tc = (ii == 0) ? t0 : (ii == 1 ? t1 : t2);
        qpS[tid] = R[ii * 3 + 0] * p0 + R[ii * 3 + 1] * p1 + R[ii * 3 + 2] * p2 + tc;
    }
    if (tid < 160) {
        int kk = tid & 31, a = tid >> 5;
        int j = idxS[kk];
        const float* pj = pos + (size_t)j * 15 + a * 3;
        float px = pj[0] - t0, py = pj[1] - t1, pz = pj[2] - t2;
        float r0_ = R[0] * px + R[3] * py + R[6] * pz;
        float r1_ = R[1] * px + R[4] * py + R[7] * pz;
        float r2_ = R[2] * px + R[5] * py + R[8] * pz;
        float s = r0_ * r0_ + r1_ * r1_ + r2_ * r2_;
        float dij = sqrtf(s + 1e-12f);
        float di = 1.f / (dij + 1e-6f);
        pfA[kk * KPAD + a * 3 + 0] = f2bs(r0_ * di);
        pfA[kk * KPAD + a * 3 + 1] = f2bs(r1_ * di);
        pfA[kk * KPAD + a * 3 + 2] = f2bs(r2_ * di);
        for (int b = 0; b < 16; b++) {
            float z = (dij - (float)b * (10.f / 15.f)) * (1.f / 0.625f);
            pfA[kk * KPAD + 15 + a * 16 + b] = f2bs(expf(-z * z));
        }
    }
    if (tid < KNB) pfA[tid * KPAD + FPD] = 0;
    __syncthreads();

    // pair MLP via MFMA
    {
        int lane = tid & 63;
        int wv = tid >> 6;
        int n0 = wv * 16;
        int mrow = lane & 15;
        int quad = lane >> 4;
        floatx4 c0 = {0.f, 0.f, 0.f, 0.f};
        floatx4 c1 = {0.f, 0.f, 0.f, 0.f};
#pragma unroll
        for (int ks = 0; ks < 3; ks++) {
            int k0 = ks * 32 + quad * 8;
            short8 a0 = *reinterpret_cast<const short8*>(&pfA[mrow * KPAD + k0]);
            short8 a1 = *reinterpret_cast<const short8*>(&pfA[(16 + mrow) * KPAD + k0]);
            short8 bb = *reinterpret_cast<const short8*>(&wT[(n0 + mrow) * KPAD + k0]);
            c0 = __builtin_amdgcn_mfma_f32_16x16x32_bf16(a0, bb, c0, 0, 0, 0);
            c1 = __builtin_amdgcn_mfma_f32_16x16x32_bf16(a1, bb, c1, 0, 0, 0);
        }
        int col = n0 + mrow;
        float bp = b_pair[col];
        float w160 = w_pair[160 * 64 + col];
        float w161 = w_pair[161 * 64 + col];
#pragma unroll
        for (int mt = 0; mt < 2; mt++) {
            floatx4 cc = mt ? c1 : c0;
#pragma unroll
            for (int r = 0; r < 4; r++) {
                int row = mt * 16 + quad * 4 + r;
                float s = cc[r] + bp + w_pair[(95 + rpS[row]) * 64 + col] +
                          (scS[row] ? w160 : 0.f) + (sbS[row] ? w161 : 0.f);
                pairS[row][col] = gelu_t(s);
            }
        }
    }
    __syncthreads();

    // logits
    {
        int kk = tid >> 3, h = tid & 7;
        int j = idxS[kk];
        float qk = 0.f;
        const short8* kj8 = reinterpret_cast<const short8*>(kbh + (size_t)j * 256 + h * 32);
        const floatx4* qh4 = reinterpret_cast<const floatx4*>(qS + h * 32);
#pragma unroll
        for (int e = 0; e < 4; e++) {
            short8 kv = kj8[e];
            floatx4 qa = qh4[2 * e], qb = qh4[2 * e + 1];
            qk += qa[0] * bs2f(kv[0]) + qa[1] * bs2f(kv[1]) + qa[2] * bs2f(kv[2]) + qa[3] * bs2f(kv[3]) +
                  qb[0] * bs2f(kv[4]) + qb[1] * bs2f(kv[5]) + qb[2] * bs2f(kv[6]) + qb[3] * bs2f(kv[7]);
        }
        qk *= 0.17677669529663687f;
        float kparr[24], qparr[24];
        {
            const short8* kp8 = reinterpret_cast<const short8*>(kpl + (size_t)j * 192 + h * 24);
#pragma unroll
            for (int e = 0; e < 3; e++) {
                short8 v = kp8[e];
#pragma unroll
                for (int q = 0; q < 8; q++) kparr[e * 8 + q] = bs2f(v[q]);
            }
            const floatx4* qp4 = reinterpret_cast<const floatx4*>(qpS + h * 24);
#pragma unroll
            for (int e = 0; e < 6; e++) {
                floatx4 v = qp4[e];
#pragma unroll
                for (int q = 0; q < 4; q++) qparr[e * 4 + q] = v[q];
            }
        }
        float Rj[9], tj[3];
#pragma unroll
        for (int u = 0; u < 9; u++) Rj[u] = RjS[kk][u];
#pragma unroll
        for (int u = 0; u < 3; u++) tj[u] = tjS[kk][u];
        float d2 = 0.f;
#pragma unroll
        for (int p = 0; p < 8; p++) {
            float p0 = kparr[p * 3 + 0], p1 = kparr[p * 3 + 1], p2 = kparr[p * 3 + 2];
#pragma unroll
            for (int ii = 0; ii < 3; ii++) {
                float kpv = Rj[ii * 3 + 0] * p0 + Rj[ii * 3 + 1] * p1 + Rj[ii * 3 + 2] * p2 + tj[ii];
                float df = qparr[p * 3 + ii] - kpv;
                d2 += df * df;
            }
        }
        float pb = 0.f;
        const floatx4* ps4 = reinterpret_cast<const floatx4*>(&pairS[kk][0]);
        const floatx4* wb4 = reinterpret_cast<const floatx4*>(&wbmS[h][0]);
#pragma unroll
        for (int e = 0; e < 16; e++) {
            floatx4 pv = ps4[e], wv4 = wb4[e];
            pb += pv[0] * wv4[0] + pv[1] * wv4[1] + pv[2] * wv4[2] + pv[3] * wv4[3];
        }
        float sp = log1pf(expf(gamma[h]));
        float lgt = 0.5773502691896258f * (qk + pb - (1.f / 12.f) * sp * d2);
        lg[kk * 8 + h] = pmS[kk] ? lgt : -1e9f;
    }
    __syncthreads();
    if (tid < 8) {
        int h = tid;
        float m = -INFINITY;
        for (int kk = 0; kk < KNB; kk++) m = fmaxf(m, lg[kk * 8 + h]);
        float s = 0.f;
        for (int kk = 0; kk < KNB; kk++) s += expf(lg[kk * 8 + h] - m);
        float invs = 1.f / s;
        for (int kk = 0; kk < KNB; kk++) {
            float a = expf(lg[kk * 8 + h] - m) * invs;
            lg[kk * 8 + h] = pmS[kk] ? a : 0.f;
        }
    }
    __syncthreads();
    {
        int h = tid >> 5, d = tid & 31;
        float s = 0.f;
        for (int kk = 0; kk < KNB; kk++)
            s += lg[kk * 8 + h] * B2F(vbh[(size_t)idxS[kk] * 256 + h * 32 + d]);
        ipaS[h * 32 + d] = s;
    }
    for (int u = tid; u < 512; u += 256) {
        int h = u >> 6, c = u & 63;
        float s = 0.f;
        for (int kk = 0; kk < KNB; kk++) s += lg[kk * 8 + h] * pairS[kk][c];
        ipaS[256 + u] = s;
    }
    if (tid < 192) {
        int ii = tid % 3, hp = tid / 3, h = hp >> 3;
        float s = 0.f;
        for (int kk = 0; kk < KNB; kk++) {
            const bf16* vpj = vpl + (size_t)idxS[kk] * 192 + hp * 3;
            float vg = RjS[kk][ii * 3 + 0] * B2F(vpj[0]) + RjS[kk][ii * 3 + 1] * B2F(vpj[1]) +
                       RjS[kk][ii * 3 + 2] * B2F(vpj[2]) + tjS[kk][ii];
            s += lg[kk * 8 + h] * vg;
        }
        optg[tid] = s;
    }
    __syncthreads();
    if (tid < 192) {
        int hp = tid / 3, ii = tid % 3;
        float v0 = optg[hp * 3 + 0] - t0, v1 = optg[hp * 3 + 1] - t1, v2 = optg[hp * 3 + 2] - t2;
        ipaS[768 + tid] = R[0 + ii] * v0 + R[3 + ii] * v1 + R[6 + ii] * v2;
    }
    __syncthreads();
    if (tid < 64) {
        float a0 = ipaS[768 + tid * 3], a1 = ipaS[768 + tid * 3 + 1], a2 = ipaS[768 + tid * 3 + 2];
        ipaS[960 + tid] = sqrtf(a0 * a0 + a1 * a1 + a2 * a2 + 1e-8f);
    }
    __syncthreads();
    for (int u = tid; u < FOUT; u += 256) ipab[(size_t)i * FOUT + u] = F2B(ipaS[u]);
}

// Kernel D: dlocal += ipa @ wo + bo via MFMA. 32 rows/block. A from global ipab.
__global__ __launch_bounds__(256) void kD(const bf16* __restrict__ ipab,
                                          const unsigned short* __restrict__ woT,
                                          const float* __restrict__ bo,
                                          float* __restrict__ dlocal) {
    int r0 = blockIdx.x * 32;
    int tid = threadIdx.x;
    int lane = tid & 63, w = tid >> 6;
    int mtile = w & 1, m = lane & 15, quad = lane >> 4;
    floatx4 acc[8];
#pragma unroll
    for (int j = 0; j < 8; j++) acc[j] = {0.f, 0.f, 0.f, 0.f};
    const short8* arow = reinterpret_cast<const short8*>(ipab + (size_t)(r0 + mtile * 16 + m) * 1024);
    for (int ks = 0; ks < 32; ks++) {
        short8 a = arow[ks * 4 + quad];
#pragma unroll
        for (int j = 0; j < 8; j++) {
            int nt = (w >> 1) + 2 * j;
            const short8* bp = reinterpret_cast<const short8*>(woT + (size_t)(nt * 16 + m) * 1024);
            acc[j] = __builtin_amdgcn_mfma_f32_16x16x32_bf16(a, bp[ks * 4 + quad], acc[j], 0, 0, 0);
        }
    }
#pragma unroll
    for (int j = 0; j < 8; j++) {
        int nt = (w >> 1) + 2 * j;
        int colg = nt * 16 + m;
        float bov = bo[colg];
#pragma unroll
        for (int r = 0; r < 4; r++) {
            size_t off = (size_t)(r0 + mtile * 16 + quad * 4 + r) * 256 + colg;
            dlocal[off] += acc[j][r] + bov;
        }
    }
}

// Kernel E: LN2 + transition MLP via MFMA, in-place on dlocal. 32 rows/block.
__global__ __launch_bounds__(256) void kE(const float* __restrict__ ln2_s,
                                          const float* __restrict__ ln2_o,
                                          const unsigned short* __restrict__ wgT,
                                          const unsigned short* __restrict__ wvmT,
                                          const unsigned short* __restrict__ womT,
                                          float* __restrict__ dlocal) {
    int r0 = blockIdx.x * 32;
    int tid = threadIdx.x;
    __shared__ __align__(16) unsigned short xbf[32 * 264];
    __shared__ __align__(16) unsigned short hbf[32 * 520];
    {
        int row = tid >> 3, seg = tid & 7;
        const floatx4* src = reinterpret_cast<const floatx4*>(dlocal + (size_t)(r0 + row) * 256 + seg * 32);
        floatx4 vv[8];
        float s = 0.f, ss = 0.f;
#pragma unroll
        for (int e = 0; e < 8; e++) {
            vv[e] = src[e];
#pragma unroll
            for (int q = 0; q < 4; q++) { s += vv[e][q]; ss += vv[e][q] * vv[e][q]; }
        }
        s += __shfl_xor(s, 1); ss += __shfl_xor(ss, 1);
        s += __shfl_xor(s, 2); ss += __shfl_xor(ss, 2);
        s += __shfl_xor(s, 4); ss += __shfl_xor(ss, 4);
        float mu = s * (1.f / 256.f);
        float var = ss * (1.f / 256.f) - mu * mu;
        float rs = rsqrtf(var + 1e-5f);
#pragma unroll
        for (int e = 0; e < 8; e++) {
#pragma unroll
            for (int q = 0; q < 4; q++) {
                int f = seg * 32 + e * 4 + q;
                xbf[row * 264 + f] = f2bs((vv[e][q] - mu) * rs * ln2_s[f] + ln2_o[f]);
            }
        }
    }
    __syncthreads();
    int lane = tid & 63, w = tid >> 6;
    int mtile = w & 1, m = lane & 15, quad = lane >> 4;
    short8 afr[8];
#pragma unroll
    for (int ks = 0; ks < 8; ks++)
        afr[ks] = *reinterpret_cast<const short8*>(&xbf[(mtile * 16 + m) * 264 + ks * 32 + quad * 8]);
    // GEMM1: x @ [wg|wvm] -> h = gelu(ag)*av, bf16 in LDS
    for (int nt = (w >> 1); nt < 32; nt += 2) {
        floatx4 cg = {0.f, 0.f, 0.f, 0.f};
        floatx4 cv = {0.f, 0.f, 0.f, 0.f};
        const short8* bg = reinterpret_cast<const short8*>(wgT + (size_t)(nt * 16 + m) * 256);
        const short8* bv = reinterpret_cast<const short8*>(wvmT + (size_t)(nt * 16 + m) * 256);
#pragma unroll
        for (int ks = 0; ks < 8; ks++) {
            cg = __builtin_amdgcn_mfma_f32_16x16x32_bf16(afr[ks], bg[ks * 4 + quad], cg, 0, 0, 0);
            cv = __builtin_amdgcn_mfma_f32_16x16x32_bf16(afr[ks], bv[ks * 4 + quad], cv, 0, 0, 0);
        }
#pragma unroll
        for (int r = 0; r < 4; r++) {
            int row = mtile * 16 + quad * 4 + r;
            hbf[row * 520 + nt * 16 + m] = f2bs(gelu_t(cg[r]) * cv[r]);
        }
    }
    __syncthreads();
    // GEMM2: h @ wom -> += dlocal
    floatx4 acc[8];
#pragma unroll
    for (int j = 0; j < 8; j++) acc[j] = {0.f, 0.f, 0.f, 0.f};
    for (int ks = 0; ks < 16; ks++) {
        short8 a = *reinterpret_cast<const short8*>(&hbf[(mtile * 16 + m) * 520 + ks * 32 + quad * 8]);
#pragma unroll
        for (int j = 0; j < 8; j++) {
            int nt = (w >> 1) + 2 * j;
            const short8* bp = reinterpret_cast<const short8*>(womT + (size_t)(nt * 16 + m) * 512);
            acc[j] = __builtin_amdgcn_mfma_f32_16x16x32_bf16(a, bp[ks * 4 + quad], acc[j], 0, 0, 0);
        }
    }
#pragma unroll
    for (int j = 0; j < 8; j++) {
        int nt = (w >> 1) + 2 * j;
        int colg = nt * 16 + m;
#pragma unroll
        for (int r = 0; r < 4; r++) {
            size_t off = (size_t)(r0 + mtile * 16 + quad * 4 + r) * 256 + colg;
            dlocal[off] += acc[j][r];
        }
    }
}

// Kernel F: LN3 + wpos + frame transform + update_mask; writes pos output (f32)
__global__ __launch_bounds__(256) void kF(const float* __restrict__ dlocal,
                                          const float* __restrict__ ln3_s,
                                          const float* __restrict__ ln3_o,
                                          const float* __restrict__ wpos,
                                          const float* __restrict__ lpw,
                                          const float* __restrict__ Rw,
                                          const float* __restrict__ pos,
                                          const int* __restrict__ umask,
                                          float* __restrict__ outp) {
    int i = blockIdx.x;
    int tid = threadIdx.x;
    __shared__ float x3[256];
    __shared__ float red[8];
    __shared__ float nl[15];
    float v = dlocal[(size_t)i * DMODEL + tid];
    float a = v, b = v * v;
    block_reduce2(a, b, red);
    float mu = a * (1.f / 256.f);
    float var = b * (1.f / 256.f) - mu * mu;
    x3[tid] = (v - mu) * rsqrtf(var + 1e-5f) * ln3_s[tid] + ln3_o[tid];
    __syncthreads();
    if (tid < 15) {
        float s = 0.f;
        for (int f = 0; f < 256; f++) s += x3[f] * wpos[f * 15 + tid];
        nl[tid] = lpw[(size_t)i * 15 + tid] + s;
    }
    __syncthreads();
    if (tid < 15) {
        int a2 = tid / 3, ii = tid % 3;
        float R0 = Rw[(size_t)i * 9 + ii * 3 + 0];
        float R1 = Rw[(size_t)i * 9 + ii * 3 + 1];
        float R2 = Rw[(size_t)i * 9 + ii * 3 + 2];
        float tt = pos[(size_t)i * 15 + 3 + ii];
        float np = R0 * nl[a2 * 3 + 0] + R1 * nl[a2 * 3 + 1] + R2 * nl[a2 * 3 + 2] + tt;
        float old = pos[(size_t)i * 15 + tid];
        outp[(size_t)i * 15 + tid] = (umask[i] != 0) ? np : old;
    }
}

extern "C" void kernel_launch(void* const* d_in, const int* in_sizes, int n_in,
                              void* d_out, int out_size, void* d_ws, size_t ws_size,
                              hipStream_t stream) {
    static const int map_dict[31] = {0, 1, 2, 3, 4, 5, 6, 7, 8, 9, 10, 11, 12, 13, 14, 15,
                                     16, 17, 18, 19, 20, 21, 22, 23, 24, 25, 26, 27, 28, 29, 30};
    static const int map_sig[31] = {0, 1, 25, 26, 27, 28, 29, 30, 2, 3, 4, 5, 6, 7, 8, 9,
                                    10, 11, 12, 13, 14, 15, 16, 17, 18, 19, 20, 21, 22, 23, 24};
    const int* M = (in_sizes[2] == FIN * DMODEL) ? map_sig : map_dict;

    const float* local = (const float*)d_in[M[0]];
    const float* pos = (const float*)d_in[M[1]];
    const int* nbr = (const int*)d_in[M[2]];
    const int* resi = (const int*)d_in[M[3]];
    const int* chain = (const int*)d_in[M[4]];
    const int* batch = (const int*)d_in[M[5]];
    const int* umask = (const int*)d_in[M[6]];
    const int* mask = (const int*)d_in[M[7]];
    const float* w_in = (const float*)d_in[M[8]];
    const float* w_pair = (const float*)d_in[M[9]];
    const float* b_pair = (const float*)d_in[M[10]];
    const float* ln1_s = (const float*)d_in[M[11]];
    const float* ln1_o = (const float*)d_in[M[12]];
    const float* wq = (const float*)d_in[M[13]];
    const float* wk = (const float*)d_in[M[14]];
    const float* wv = (const float*)d_in[M[15]];
    const float* wqp = (const float*)d_in[M[16]];
    const float* wkp = (const float*)d_in[M[17]];
    const float* wvp = (const float*)d_in[M[18]];
    const float* wbm = (const float*)d_in[M[19]];
    const float* gamma = (const float*)d_in[M[20]];
    const float* wo = (const float*)d_in[M[21]];
    const float* bo = (const float*)d_in[M[22]];
    const float* ln2_s = (const float*)d_in[M[23]];
    const float* ln2_o = (const float*)d_in[M[24]];
    const float* wg = (const float*)d_in[M[25]];
    const float* wvm = (const float*)d_in[M[26]];
    const float* wom = (const float*)d_in[M[27]];
    const float* ln3_s = (const float*)d_in[M[28]];
    const float* ln3_o = (const float*)d_in[M[29]];
    const float* wpos = (const float*)d_in[M[30]];

    int N = in_sizes[0] / DMODEL;

    float* out_local = (float*)d_out;
    float* out_pos = out_local + (size_t)N * DMODEL;

    char* wsb = (char*)d_ws;
    float* Rw = (float*)wsb;   wsb += (size_t)N * 9 * 4;
    float* lpw = (float*)wsb;  wsb += (size_t)N * 15 * 4;
    bf16* qbh = (bf16*)wsb;    wsb += (size_t)N * 256 * 2;
    bf16* kbh = (bf16*)wsb;    wsb += (size_t)N * 256 * 2;
    bf16* vbh = (bf16*)wsb;    wsb += (size_t)N * 256 * 2;
    bf16* qpl = (bf16*)wsb;    wsb += (size_t)N * 192 * 2;
    bf16* kpl = (bf16*)wsb;    wsb += (size_t)N * 192 * 2;
    bf16* vpl = (bf16*)wsb;    wsb += (size_t)N * 192 * 2;
    bf16* ipab = (bf16*)wsb;   wsb += (size_t)N * 1024 * 2;
    unsigned short* wtrans = (unsigned short*)wsb; wsb += (size_t)WT_TOTAL * 2;
    unsigned short* wAllT = wtrans + OFF_WALL;
    unsigned short* woT   = wtrans + OFF_WO;
    unsigned short* wgT   = wtrans + OFF_WG;
    unsigned short* wvmT  = wtrans + OFF_WVM;
    unsigned short* womT  = wtrans + OFF_WOM;
    unsigned short* wpT   = wtrans + OFF_WP;

    dim3 blk(256);
    hipLaunchKernelGGL(kT, dim3(512), blk, 0, stream, wq, wk, wv, wqp, wkp, wvp,
                       wo, wg, wvm, wom, w_pair, wtrans);
    hipLaunchKernelGGL(kA, dim3(N), blk, 0, stream, local, pos, w_in, Rw, lpw, out_local);
    hipLaunchKernelGGL(kB, dim3(N / 32), blk, 0, stream, out_local, ln1_s, ln1_o, wAllT,
                       qbh, kbh, vbh, qpl, kpl, vpl);
    hipLaunchKernelGGL(kC, dim3(N), blk, 0, stream, pos, nbr, resi, chain, batch, mask, Rw,
                       w_pair, wpT, b_pair, wbm, gamma, qbh, kbh, vbh, qpl, kpl, vpl, ipab, N);
    hipLaunchKernelGGL(kD, dim3(N / 32), blk, 0, stream, ipab, woT, bo, out_local);
    hipLaunchKernelGGL(kE, dim3(N / 32), blk, 0, stream, ln2_s, ln2_o, wgT, wvmT, womT, out_local);
    hipLaunchKernelGGL(kF, dim3(N), blk, 0, stream, out_local, ln3_s, ln3_o, wpos, lpw, Rw, pos,
                       umask, out_pos);
}

// Round 9
// 787.650 us; speedup vs baseline: 2.7848x; 1.0750x over previous
//
#include <hip/hip_runtime.h>
#include <hip/hip_bf16.h>
#include <math.h>

#define DMODEL 256
#define KNB 32
#define NHEAD 8
#define FIN 95
#define FPD 95        // dense part of pair features
#define KPAD 104      // padded K for pair MFMA staging
#define FOUT 1024
#define DHID 512

typedef __hip_bfloat16 bf16;
typedef __attribute__((ext_vector_type(8))) short short8;
typedef __attribute__((ext_vector_type(4))) float floatx4;

__device__ inline float B2F(bf16 x) { return __bfloat162float(x); }
__device__ inline bf16 F2B(float x) { return __float2bfloat16(x); }
__device__ inline unsigned short f2bs(float x) {
    bf16 h = __float2bfloat16(x);
    return *reinterpret_cast<unsigned short*>(&h);
}
__device__ inline float bs2f(short s) {
    return __uint_as_float(((unsigned)(unsigned short)s) << 16);
}

__device__ inline float gelu_t(float x) {
    return 0.5f * x * (1.f + tanhf(0.7978845608028654f * (x + 0.044715f * x * x * x)));
}

// block-wide reduce of two values; block = 256 threads (4 waves)
__device__ inline void block_reduce2(float& a, float& b, float* sm) {
    __syncthreads();
    for (int off = 32; off > 0; off >>= 1) {
        a += __shfl_down(a, off);
        b += __shfl_down(b, off);
    }
    int lane = threadIdx.x & 63, w = threadIdx.x >> 6;
    if (lane == 0) { sm[w * 2] = a; sm[w * 2 + 1] = b; }
    __syncthreads();
    if (threadIdx.x == 0) {
        float sa = 0.f, sb = 0.f;
        for (int i = 0; i < 4; i++) { sa += sm[i * 2]; sb += sm[i * 2 + 1]; }
        sm[0] = sa; sm[1] = sb;
    }
    __syncthreads();
    a = sm[0]; b = sm[1];
}

// ---- weight transpose buffer layout (bf16 elements) ----
#define OFF_WALL 0          // [1344][256]  q|k|v|qp|kp|vp columns
#define OFF_WO   344064     // [256][1024]
#define OFF_WG   606208     // [512][256]
#define OFF_WVM  737280     // [512][256]
#define OFF_WOM  868352     // [256][512]
#define OFF_WP   999424     // [64][KPAD]
#define WT_TOTAL 1006080

// Kernel T: transpose/convert all weights to bf16 [n][k] (k-contiguous)
__global__ __launch_bounds__(256) void kT(const float* __restrict__ wq, const float* __restrict__ wk,
                                          const float* __restrict__ wv, const float* __restrict__ wqp,
                                          const float* __restrict__ wkp, const float* __restrict__ wvp,
                                          const float* __restrict__ wo, const float* __restrict__ wg,
                                          const float* __restrict__ wvm, const float* __restrict__ wom,
                                          const float* __restrict__ w_pair,
                                          unsigned short* __restrict__ wt) {
    int stride = gridDim.x * 256;
    for (int e = blockIdx.x * 256 + threadIdx.x; e < WT_TOTAL; e += stride) {
        float v;
        if (e < OFF_WO) {
            int n = e >> 8, k = e & 255;
            if (n < 256) v = wq[k * 256 + n];
            else if (n < 512) v = wk[k * 256 + n - 256];
            else if (n < 768) v = wv[k * 256 + n - 512];
            else if (n < 960) v = wqp[k * 192 + n - 768];
            else if (n < 1152) v = wkp[k * 192 + n - 960];
            else v = wvp[k * 192 + n - 1152];
        } else if (e < OFF_WG) {
            int u = e - OFF_WO; int n = u >> 10, k = u & 1023;
            v = wo[k * 256 + n];
        } else if (e < OFF_WVM) {
            int u = e - OFF_WG; int n = u >> 8, k = u & 255;
            v = wg[k * 512 + n];
        } else if (e < OFF_WOM) {
            int u = e - OFF_WVM; int n = u >> 8, k = u & 255;
            v = wvm[k * 512 + n];
        } else if (e < OFF_WP) {
            int u = e - OFF_WOM; int n = u >> 9, k = u & 511;
            v = wom[k * 256 + n];
        } else {
            int u = e - OFF_WP; int n = u / KPAD, k = u % KPAD;
            v = (k < FPD) ? w_pair[k * 64 + n] : 0.f;
        }
        wt[e] = f2bs(v);
    }
}

// Kernel A: frames, local_pos, feat, lup = local + feat @ w_in  (-> d_out local region, f32)
__global__ __launch_bounds__(256) void kA(const float* __restrict__ local,
                                          const float* __restrict__ pos,
                                          const float* __restrict__ w_in,
                                          float* __restrict__ Rw,
                                          float* __restrict__ lpw,
                                          float* __restrict__ lup) {
    int i = blockIdx.x;
    int tid = threadIdx.x;
    const float* pp = pos + (size_t)i * 15;
    float nx = pp[0], ny = pp[1], nz = pp[2];
    float cax = pp[3], cay = pp[4], caz = pp[5];
    float cx = pp[6], cy = pp[7], cz = pp[8];
    float e1x = cx - cax, e1y = cy - cay, e1z = cz - caz;
    float inv = rsqrtf(e1x * e1x + e1y * e1y + e1z * e1z + 1e-6f);
    e1x *= inv; e1y *= inv; e1z *= inv;
    float ux = nx - cax, uy = ny - cay, uz = nz - caz;
    float d = ux * e1x + uy * e1y + uz * e1z;
    float wx = ux - d * e1x, wy = uy - d * e1y, wz = uz - d * e1z;
    inv = rsqrtf(wx * wx + wy * wy + wz * wz + 1e-6f);
    float e2x = wx * inv, e2y = wy * inv, e2z = wz * inv;
    float e3x = e1y * e2z - e1z * e2y;
    float e3y = e1z * e2x - e1x * e2z;
    float e3z = e1x * e2y - e1y * e2x;
    float R[9] = {e1x, e2x, e3x, e1y, e2y, e3y, e1z, e2z, e3z};

    __shared__ float lp[15];
    __shared__ float feat[FIN];
    __shared__ float dd[5], dinv[5];

    if (tid < 9) Rw[(size_t)i * 9 + tid] = R[tid];
    if (tid < 15) {
        int a = tid / 3, ii = tid % 3;
        float px = pp[a * 3 + 0] - cax, py = pp[a * 3 + 1] - cay, pz = pp[a * 3 + 2] - caz;
        float v = R[0 * 3 + ii] * px + R[1 * 3 + ii] * py + R[2 * 3 + ii] * pz;
        lp[tid] = v;
        lpw[(size_t)i * 15 + tid] = v;
    }
    __syncthreads();
    if (tid < 5) {
        float s = lp[tid * 3] * lp[tid * 3] + lp[tid * 3 + 1] * lp[tid * 3 + 1] + lp[tid * 3 + 2] * lp[tid * 3 + 2];
        dd[tid] = sqrtf(s + 1e-12f);
        dinv[tid] = rsqrtf(s + 1e-6f);
    }
    __syncthreads();
    if (tid < 15) {
        feat[tid] = lp[tid] * dinv[tid / 3];
    } else if (tid < 95) {
        int u = tid - 15, a = u >> 4, b = u & 15;
        float z = (dd[a] - (float)b * (10.f / 15.f)) * (1.f / 0.625f);
        feat[tid] = expf(-z * z);
    }
    __syncthreads();
    float acc = local[(size_t)i * DMODEL + tid];
    for (int f = 0; f < FIN; f++) acc += feat[f] * w_in[f * DMODEL + tid];
    lup[(size_t)i * DMODEL + tid] = acc;
}

// Kernel B: LN1 + all 6 projections via MFMA. 32 rows/block.
__global__ __launch_bounds__(256) void kB(const float* __restrict__ lup,
                                          const float* __restrict__ ln1_s,
                                          const float* __restrict__ ln1_o,
                                          const unsigned short* __restrict__ wAllT,
                                          bf16* __restrict__ qbh, bf16* __restrict__ kbh,
                                          bf16* __restrict__ vbh, bf16* __restrict__ qpl,
                                          bf16* __restrict__ kpl, bf16* __restrict__ vpl) {
    int r0 = blockIdx.x * 32;
    int tid = threadIdx.x;
    __shared__ __align__(16) unsigned short xbf[32 * 264];
    {
        int row = tid >> 3, seg = tid & 7;
        const floatx4* src = reinterpret_cast<const floatx4*>(lup + (size_t)(r0 + row) * 256 + seg * 32);
        floatx4 vv[8];
        float s = 0.f, ss = 0.f;
#pragma unroll
        for (int e = 0; e < 8; e++) {
            vv[e] = src[e];
#pragma unroll
            for (int q = 0; q < 4; q++) { s += vv[e][q]; ss += vv[e][q] * vv[e][q]; }
        }
        s += __shfl_xor(s, 1); ss += __shfl_xor(ss, 1);
        s += __shfl_xor(s, 2); ss += __shfl_xor(ss, 2);
        s += __shfl_xor(s, 4); ss += __shfl_xor(ss, 4);
        float mu = s * (1.f / 256.f);
        float var = ss * (1.f / 256.f) - mu * mu;
        float rs = rsqrtf(var + 1e-5f);
#pragma unroll
        for (int e = 0; e < 8; e++) {
#pragma unroll
            for (int q = 0; q < 4; q++) {
                int f = seg * 32 + e * 4 + q;
                xbf[row * 264 + f] = f2bs((vv[e][q] - mu) * rs * ln1_s[f] + ln1_o[f]);
            }
        }
    }
    __syncthreads();
    int lane = tid & 63, w = tid >> 6;
    int mtile = w & 1, m = lane & 15, quad = lane >> 4;
    short8 afr[8];
#pragma unroll
    for (int ks = 0; ks < 8; ks++)
        afr[ks] = *reinterpret_cast<const short8*>(&xbf[(mtile * 16 + m) * 264 + ks * 32 + quad * 8]);
    for (int nt = (w >> 1); nt < 84; nt += 2) {
        floatx4 c = {0.f, 0.f, 0.f, 0.f};
        const short8* bp = reinterpret_cast<const short8*>(wAllT + (size_t)(nt * 16 + m) * 256);
#pragma unroll
        for (int ks = 0; ks < 8; ks++)
            c = __builtin_amdgcn_mfma_f32_16x16x32_bf16(afr[ks], bp[ks * 4 + quad], c, 0, 0, 0);
        int colg = nt * 16 + m;
        bf16* O; int c0, ncol;
        if (colg < 256)       { O = qbh; c0 = colg;        ncol = 256; }
        else if (colg < 512)  { O = kbh; c0 = colg - 256;  ncol = 256; }
        else if (colg < 768)  { O = vbh; c0 = colg - 512;  ncol = 256; }
        else if (colg < 960)  { O = qpl; c0 = colg - 768;  ncol = 192; }
        else if (colg < 1152) { O = kpl; c0 = colg - 960;  ncol = 192; }
        else                  { O = vpl; c0 = colg - 1152; ncol = 192; }
#pragma unroll
        for (int r = 0; r < 4; r++) {
            int rg = r0 + mtile * 16 + quad * 4 + r;
            O[(size_t)rg * ncol + c0] = F2B(c[r]);
        }
    }
}

// Kernel P: rotate local-frame points (bf16) to global-frame f32: g = R_i @ p + t_i
__global__ __launch_bounds__(256) void kP(const bf16* __restrict__ qpl,
                                          const bf16* __restrict__ kpl,
                                          const bf16* __restrict__ vpl,
                                          const float* __restrict__ Rw,
                                          const float* __restrict__ pos,
                                          float* __restrict__ qpg,
                                          float* __restrict__ kpg,
                                          float* __restrict__ vpg) {
    int r0 = blockIdx.x * 4;
    int tid = threadIdx.x;
    for (int u = tid; u < 4 * 192; u += 256) {
        int r = u / 192, e = u % 192, hp = e / 3, ii = e % 3;
        int ri = r0 + r;
        float R0 = Rw[(size_t)ri * 9 + ii * 3 + 0];
        float R1 = Rw[(size_t)ri * 9 + ii * 3 + 1];
        float R2 = Rw[(size_t)ri * 9 + ii * 3 + 2];
        float tt = pos[(size_t)ri * 15 + 3 + ii];
        size_t base = (size_t)ri * 192 + hp * 3;
        qpg[(size_t)ri * 192 + e] = R0 * B2F(qpl[base]) + R1 * B2F(qpl[base + 1]) + R2 * B2F(qpl[base + 2]) + tt;
        kpg[(size_t)ri * 192 + e] = R0 * B2F(kpl[base]) + R1 * B2F(kpl[base + 1]) + R2 * B2F(kpl[base + 2]) + tt;
        vpg[(size_t)ri * 192 + e] = R0 * B2F(vpl[base]) + R1 * B2F(vpl[base + 1]) + R2 * B2F(vpl[base + 2]) + tt;
    }
}

// Kernel C: pair features (MFMA pair MLP) + attention + IPA concat (bf16 out)
__global__ __launch_bounds__(256) void kC(const float* __restrict__ pos,
                                          const int* __restrict__ nbr,
                                          const int* __restrict__ resi,
                                          const int* __restrict__ chain,
                                          const int* __restrict__ batch,
                                          const int* __restrict__ mask,
                                          const float* __restrict__ Rw,
                                          const float* __restrict__ w_pair,
                                          const unsigned short* __restrict__ wT,
                                          const float* __restrict__ b_pair,
                                          const float* __restrict__ wbm,
                                          const float* __restrict__ gamma,
                                          const bf16* __restrict__ qbh,
                                          const bf16* __restrict__ kbh,
                                          const bf16* __restrict__ vbh,
                                          const float* __restrict__ qpg,
                                          const float* __restrict__ kpg,
                                          const float* __restrict__ vpg,
                                          bf16* __restrict__ ipab,
                                          int N) {
    int i = blockIdx.x;
    int tid = threadIdx.x;
    __shared__ __align__(16) float qS[256];
    __shared__ __align__(16) float qpS[192];
    __shared__ __align__(16) unsigned short pfA[KNB * KPAD];
    __shared__ __align__(16) float pairS[KNB][68];
    __shared__ __align__(16) float wbmS[NHEAD][68];
    __shared__ float lg[KNB * NHEAD];
    __shared__ float optg[192];
    __shared__ float ipaS[FOUT];
    __shared__ int idxS[KNB], rpS[KNB], scS[KNB], sbS[KNB], pmS[KNB];

    float R[9];
#pragma unroll
    for (int u = 0; u < 9; u++) R[u] = Rw[(size_t)i * 9 + u];
    float t0 = pos[(size_t)i * 15 + 3];
    float t1 = pos[(size_t)i * 15 + 4];
    float t2 = pos[(size_t)i * 15 + 5];

    qS[tid] = B2F(qbh[(size_t)i * 256 + tid]);
    if (tid < 192) qpS[tid] = qpg[(size_t)i * 192 + tid];
    if (tid < KNB) {
        int nb = nbr[(size_t)i * KNB + tid];
        int j = min(max(nb, 0), N - 1);
        idxS[tid] = j;
        int rp = resi[j] - resi[i];
        rp = min(max(rp, -32), 32) + 32;
        rpS[tid] = rp;
        scS[tid] = (chain[j] == chain[i]) ? 1 : 0;
        sbS[tid] = (batch[j] == batch[i]) ? 1 : 0;
        pmS[tid] = (mask[i] != 0 && mask[j] != 0 && nb >= 0 && batch[j] == batch[i]) ? 1 : 0;
    }
    __syncthreads();
    for (int u = tid; u < 512; u += 256) {
        int h = u & 7, c = u >> 3;
        wbmS[h][c] = wbm[c * 8 + h];
    }
    if (tid < 160) {
        int kk = tid & 31, a = tid >> 5;
        int j = idxS[kk];
        const float* pj = pos + (size_t)j * 15 + a * 3;
        float px = pj[0] - t0, py = pj[1] - t1, pz = pj[2] - t2;
        float r0_ = R[0] * px + R[3] * py + R[6] * pz;
        float r1_ = R[1] * px + R[4] * py + R[7] * pz;
        float r2_ = R[2] * px + R[5] * py + R[8] * pz;
        float s = r0_ * r0_ + r1_ * r1_ + r2_ * r2_;
        float dij = sqrtf(s + 1e-12f);
        float di = 1.f / (dij + 1e-6f);
        pfA[kk * KPAD + a * 3 + 0] = f2bs(r0_ * di);
        pfA[kk * KPAD + a * 3 + 1] = f2bs(r1_ * di);
        pfA[kk * KPAD + a * 3 + 2] = f2bs(r2_ * di);
        for (int b = 0; b < 16; b++) {
            float z = (dij - (float)b * (10.f / 15.f)) * (1.f / 0.625f);
            pfA[kk * KPAD + 15 + a * 16 + b] = f2bs(expf(-z * z));
        }
    }
    if (tid < KNB) pfA[tid * KPAD + FPD] = 0;
    __syncthreads();

    // pair MLP via MFMA
    {
        int lane = tid & 63;
        int wv = tid >> 6;
        int n0 = wv * 16;
        int mrow = lane & 15;
        int quad = lane >> 4;
        floatx4 c0 = {0.f, 0.f, 0.f, 0.f};
        floatx4 c1 = {0.f, 0.f, 0.f, 0.f};
#pragma unroll
        for (int ks = 0; ks < 3; ks++) {
            int k0 = ks * 32 + quad * 8;
            short8 a0 = *reinterpret_cast<const short8*>(&pfA[mrow * KPAD + k0]);
            short8 a1 = *reinterpret_cast<const short8*>(&pfA[(16 + mrow) * KPAD + k0]);
            short8 bb = *reinterpret_cast<const short8*>(&wT[(n0 + mrow) * KPAD + k0]);
            c0 = __builtin_amdgcn_mfma_f32_16x16x32_bf16(a0, bb, c0, 0, 0, 0);
            c1 = __builtin_amdgcn_mfma_f32_16x16x32_bf16(a1, bb, c1, 0, 0, 0);
        }
        int col = n0 + mrow;
        float bp = b_pair[col];
        float w160 = w_pair[160 * 64 + col];
        float w161 = w_pair[161 * 64 + col];
#pragma unroll
        for (int mt = 0; mt < 2; mt++) {
            floatx4 cc = mt ? c1 : c0;
#pragma unroll
            for (int r = 0; r < 4; r++) {
                int row = mt * 16 + quad * 4 + r;
                float s = cc[r] + bp + w_pair[(95 + rpS[row]) * 64 + col] +
                          (scS[row] ? w160 : 0.f) + (sbS[row] ? w161 : 0.f);
                pairS[row][col] = gelu_t(s);
            }
        }
    }
    __syncthreads();

    // logits
    {
        int kk = tid >> 3, h = tid & 7;
        int j = idxS[kk];
        float qk = 0.f;
        const short8* kj8 = reinterpret_cast<const short8*>(kbh + (size_t)j * 256 + h * 32);
        const floatx4* qh4 = reinterpret_cast<const floatx4*>(qS + h * 32);
#pragma unroll
        for (int e = 0; e < 4; e++) {
            short8 kv = kj8[e];
            floatx4 qa = qh4[2 * e], qb = qh4[2 * e + 1];
            qk += qa[0] * bs2f(kv[0]) + qa[1] * bs2f(kv[1]) + qa[2] * bs2f(kv[2]) + qa[3] * bs2f(kv[3]) +
                  qb[0] * bs2f(kv[4]) + qb[1] * bs2f(kv[5]) + qb[2] * bs2f(kv[6]) + qb[3] * bs2f(kv[7]);
        }
        qk *= 0.17677669529663687f;
        // d2 from global-frame f32 points (no rotation)
        float d2 = 0.f;
        const floatx4* kp4 = reinterpret_cast<const floatx4*>(kpg + (size_t)j * 192 + h * 24);
        const floatx4* qp4 = reinterpret_cast<const floatx4*>(qpS + h * 24);
#pragma unroll
        for (int e = 0; e < 6; e++) {
            floatx4 kv = kp4[e], qv = qp4[e];
#pragma unroll
            for (int q = 0; q < 4; q++) {
                float df = qv[q] - kv[q];
                d2 += df * df;
            }
        }
        float pb = 0.f;
        const floatx4* ps4 = reinterpret_cast<const floatx4*>(&pairS[kk][0]);
        const floatx4* wb4 = reinterpret_cast<const floatx4*>(&wbmS[h][0]);
#pragma unroll
        for (int e = 0; e < 16; e++) {
            floatx4 pv = ps4[e], wv4 = wb4[e];
            pb += pv[0] * wv4[0] + pv[1] * wv4[1] + pv[2] * wv4[2] + pv[3] * wv4[3];
        }
        float sp = log1pf(expf(gamma[h]));
        float lgt = 0.5773502691896258f * (qk + pb - (1.f / 12.f) * sp * d2);
        lg[kk * 8 + h] = pmS[kk] ? lgt : -1e9f;
    }
    __syncthreads();
    if (tid < 8) {
        int h = tid;
        float m = -INFINITY;
        for (int kk = 0; kk < KNB; kk++) m = fmaxf(m, lg[kk * 8 + h]);
        float s = 0.f;
        for (int kk = 0; kk < KNB; kk++) s += expf(lg[kk * 8 + h] - m);
        float invs = 1.f / s;
        for (int kk = 0; kk < KNB; kk++) {
            float a = expf(lg[kk * 8 + h] - m) * invs;
            lg[kk * 8 + h] = pmS[kk] ? a : 0.f;
        }
    }
    __syncthreads();
    {
        int h = tid >> 5, d = tid & 31;
        float s = 0.f;
        for (int kk = 0; kk < KNB; kk++)
            s += lg[kk * 8 + h] * B2F(vbh[(size_t)idxS[kk] * 256 + h * 32 + d]);
        ipaS[h * 32 + d] = s;
    }
    for (int u = tid; u < 512; u += 256) {
        int h = u >> 6, c = u & 63;
        float s = 0.f;
        for (int kk = 0; kk < KNB; kk++) s += lg[kk * 8 + h] * pairS[kk][c];
        ipaS[256 + u] = s;
    }
    // o_pt global from precomputed f32 vpg
    if (tid < 192) {
        int h = tid / 24;
        float s = 0.f;
        for (int kk = 0; kk < KNB; kk++)
            s += lg[kk * 8 + h] * vpg[(size_t)idxS[kk] * 192 + tid];
        optg[tid] = s;
    }
    __syncthreads();
    if (tid < 192) {
        int hp = tid / 3, ii = tid % 3;
        float v0 = optg[hp * 3 + 0] - t0, v1 = optg[hp * 3 + 1] - t1, v2 = optg[hp * 3 + 2] - t2;
        ipaS[768 + tid] = R[0 + ii] * v0 + R[3 + ii] * v1 + R[6 + ii] * v2;
    }
    __syncthreads();
    if (tid < 64) {
        float a0 = ipaS[768 + tid * 3], a1 = ipaS[768 + tid * 3 + 1], a2 = ipaS[768 + tid * 3 + 2];
        ipaS[960 + tid] = sqrtf(a0 * a0 + a1 * a1 + a2 * a2 + 1e-8f);
    }
    __syncthreads();
    for (int u = tid; u < FOUT; u += 256) ipab[(size_t)i * FOUT + u] = F2B(ipaS[u]);
}

// Kernel D: dlocal += ipa @ wo + bo via MFMA. 32 rows/block. A from global ipab.
__global__ __launch_bounds__(256) void kD(const bf16* __restrict__ ipab,
                                          const unsigned short* __restrict__ woT,
                                          const float* __restrict__ bo,
                                          float* __restrict__ dlocal) {
    int r0 = blockIdx.x * 32;
    int tid = threadIdx.x;
    int lane = tid & 63, w = tid >> 6;
    int mtile = w & 1, m = lane & 15, quad = lane >> 4;
    floatx4 acc[8];
#pragma unroll
    for (int j = 0; j < 8; j++) acc[j] = {0.f, 0.f, 0.f, 0.f};
    const short8* arow = reinterpret_cast<const short8*>(ipab + (size_t)(r0 + mtile * 16 + m) * 1024);
    for (int ks = 0; ks < 32; ks++) {
        short8 a = arow[ks * 4 + quad];
#pragma unroll
        for (int j = 0; j < 8; j++) {
            int nt = (w >> 1) + 2 * j;
            const short8* bp = reinterpret_cast<const short8*>(woT + (size_t)(nt * 16 + m) * 1024);
            acc[j] = __builtin_amdgcn_mfma_f32_16x16x32_bf16(a, bp[ks * 4 + quad], acc[j], 0, 0, 0);
        }
    }
#pragma unroll
    for (int j = 0; j < 8; j++) {
        int nt = (w >> 1) + 2 * j;
        int colg = nt * 16 + m;
        float bov = bo[colg];
#pragma unroll
        for (int r = 0; r < 4; r++) {
            size_t off = (size_t)(r0 + mtile * 16 + quad * 4 + r) * 256 + colg;
            dlocal[off] += acc[j][r] + bov;
        }
    }
}

// Kernel E: LN2 + transition MLP via MFMA, in-place on dlocal. 32 rows/block.
__global__ __launch_bounds__(256) void kE(const float* __restrict__ ln2_s,
                                          const float* __restrict__ ln2_o,
                                          const unsigned short* __restrict__ wgT,
                                          const unsigned short* __restrict__ wvmT,
                                          const unsigned short* __restrict__ womT,
                                          float* __restrict__ dlocal) {
    int r0 = blockIdx.x * 32;
    int tid = threadIdx.x;
    __shared__ __align__(16) unsigned short xbf[32 * 264];
    __shared__ __align__(16) unsigned short hbf[32 * 520];
    {
        int row = tid >> 3, seg = tid & 7;
        const floatx4* src = reinterpret_cast<const floatx4*>(dlocal + (size_t)(r0 + row) * 256 + seg * 32);
        floatx4 vv[8];
        float s = 0.f, ss = 0.f;
#pragma unroll
        for (int e = 0; e < 8; e++) {
            vv[e] = src[e];
#pragma unroll
            for (int q = 0; q < 4; q++) { s += vv[e][q]; ss += vv[e][q] * vv[e][q]; }
        }
        s += __shfl_xor(s, 1); ss += __shfl_xor(ss, 1);
        s += __shfl_xor(s, 2); ss += __shfl_xor(ss, 2);
        s += __shfl_xor(s, 4); ss += __shfl_xor(ss, 4);
        float mu = s * (1.f / 256.f);
        float var = ss * (1.f / 256.f) - mu * mu;
        float rs = rsqrtf(var + 1e-5f);
#pragma unroll
        for (int e = 0; e < 8; e++) {
#pragma unroll
            for (int q = 0; q < 4; q++) {
                int f = seg * 32 + e * 4 + q;
                xbf[row * 264 + f] = f2bs((vv[e][q] - mu) * rs * ln2_s[f] + ln2_o[f]);
            }
        }
    }
    __syncthreads();
    int lane = tid & 63, w = tid >> 6;
    int mtile = w & 1, m = lane & 15, quad = lane >> 4;
    short8 afr[8];
#pragma unroll
    for (int ks = 0; ks < 8; ks++)
        afr[ks] = *reinterpret_cast<const short8*>(&xbf[(mtile * 16 + m) * 264 + ks * 32 + quad * 8]);
    // GEMM1: x @ [wg|wvm] -> h = gelu(ag)*av, bf16 in LDS
    for (int nt = (w >> 1); nt < 32; nt += 2) {
        floatx4 cg = {0.f, 0.f, 0.f, 0.f};
        floatx4 cv = {0.f, 0.f, 0.f, 0.f};
        const short8* bg = reinterpret_cast<const short8*>(wgT + (size_t)(nt * 16 + m) * 256);
        const short8* bv = reinterpret_cast<const short8*>(wvmT + (size_t)(nt * 16 + m) * 256);
#pragma unroll
        for (int ks = 0; ks < 8; ks++) {
            cg = __builtin_amdgcn_mfma_f32_16x16x32_bf16(afr[ks], bg[ks * 4 + quad], cg, 0, 0, 0);
            cv = __builtin_amdgcn_mfma_f32_16x16x32_bf16(afr[ks], bv[ks * 4 + quad], cv, 0, 0, 0);
        }
#pragma unroll
        for (int r = 0; r < 4; r++) {
            int row = mtile * 16 + quad * 4 + r;
            hbf[row * 520 + nt * 16 + m] = f2bs(gelu_t(cg[r]) * cv[r]);
        }
    }
    __syncthreads();
    // GEMM2: h @ wom -> += dlocal
    floatx4 acc[8];
#pragma unroll
    for (int j = 0; j < 8; j++) acc[j] = {0.f, 0.f, 0.f, 0.f};
    for (int ks = 0; ks < 16; ks++) {
        short8 a = *reinterpret_cast<const short8*>(&hbf[(mtile * 16 + m) * 520 + ks * 32 + quad * 8]);
#pragma unroll
        for (int j = 0; j < 8; j++) {
            int nt = (w >> 1) + 2 * j;
            const short8* bp = reinterpret_cast<const short8*>(womT + (size_t)(nt * 16 + m) * 512);
            acc[j] = __builtin_amdgcn_mfma_f32_16x16x32_bf16(a, bp[ks * 4 + quad], acc[j], 0, 0, 0);
        }
    }
#pragma unroll
    for (int j = 0; j < 8; j++) {
        int nt = (w >> 1) + 2 * j;
        int colg = nt * 16 + m;
#pragma unroll
        for (int r = 0; r < 4; r++) {
            size_t off = (size_t)(r0 + mtile * 16 + quad * 4 + r) * 256 + colg;
            dlocal[off] += acc[j][r];
        }
    }
}

// Kernel F: LN3 + wpos + frame transform + update_mask; writes pos output (f32)
__global__ __launch_bounds__(256) void kF(const float* __restrict__ dlocal,
                                          const float* __restrict__ ln3_s,
                                          const float* __restrict__ ln3_o,
                                          const float* __restrict__ wpos,
                                          const float* __restrict__ lpw,
                                          const float* __restrict__ Rw,
                                          const float* __restrict__ pos,
                                          const int* __restrict__ umask,
                                          float* __restrict__ outp) {
    int i = blockIdx.x;
    int tid = threadIdx.x;
    __shared__ float x3[256];
    __shared__ float red[8];
    __shared__ float nl[15];
    float v = dlocal[(size_t)i * DMODEL + tid];
    float a = v, b = v * v;
    block_reduce2(a, b, red);
    float mu = a * (1.f / 256.f);
    float var = b * (1.f / 256.f) - mu * mu;
    x3[tid] = (v - mu) * rsqrtf(var + 1e-5f) * ln3_s[tid] + ln3_o[tid];
    __syncthreads();
    if (tid < 15) {
        float s = 0.f;
        for (int f = 0; f < 256; f++) s += x3[f] * wpos[f * 15 + tid];
        nl[tid] = lpw[(size_t)i * 15 + tid] + s;
    }
    __syncthreads();
    if (tid < 15) {
        int a2 = tid / 3, ii = tid % 3;
        float R0 = Rw[(size_t)i * 9 + ii * 3 + 0];
        float R1 = Rw[(size_t)i * 9 + ii * 3 + 1];
        float R2 = Rw[(size_t)i * 9 + ii * 3 + 2];
        float tt = pos[(size_t)i * 15 + 3 + ii];
        float np = R0 * nl[a2 * 3 + 0] + R1 * nl[a2 * 3 + 1] + R2 * nl[a2 * 3 + 2] + tt;
        float old = pos[(size_t)i * 15 + tid];
        outp[(size_t)i * 15 + tid] = (umask[i] != 0) ? np : old;
    }
}

extern "C" void kernel_launch(void* const* d_in, const int* in_sizes, int n_in,
                              void* d_out, int out_size, void* d_ws, size_t ws_size,
                              hipStream_t stream) {
    static const int map_dict[31] = {0, 1, 2, 3, 4, 5, 6, 7, 8, 9, 10, 11, 12, 13, 14, 15,
                                     16, 17, 18, 19, 20, 21, 22, 23, 24, 25, 26, 27, 28, 29, 30};
    static const int map_sig[31] = {0, 1, 25, 26, 27, 28, 29, 30, 2, 3, 4, 5, 6, 7, 8, 9,
                                    10, 11, 12, 13, 14, 15, 16, 17, 18, 19, 20, 21, 22, 23, 24};
    const int* M = (in_sizes[2] == FIN * DMODEL) ? map_sig : map_dict;

    const float* local = (const float*)d_in[M[0]];
    const float* pos = (const float*)d_in[M[1]];
    const int* nbr = (const int*)d_in[M[2]];
    const int* resi = (const int*)d_in[M[3]];
    const int* chain = (const int*)d_in[M[4]];
    const int* batch = (const int*)d_in[M[5]];
    const int* umask = (const int*)d_in[M[6]];
    const int* mask = (const int*)d_in[M[7]];
    const float* w_in = (const float*)d_in[M[8]];
    const float* w_pair = (const float*)d_in[M[9]];
    const float* b_pair = (const float*)d_in[M[10]];
    const float* ln1_s = (const float*)d_in[M[11]];
    const float* ln1_o = (const float*)d_in[M[12]];
    const float* wq = (const float*)d_in[M[13]];
    const float* wk = (const float*)d_in[M[14]];
    const float* wv = (const float*)d_in[M[15]];
    const float* wqp = (const float*)d_in[M[16]];
    const float* wkp = (const float*)d_in[M[17]];
    const float* wvp = (const float*)d_in[M[18]];
    const float* wbm = (const float*)d_in[M[19]];
    const float* gamma = (const float*)d_in[M[20]];
    const float* wo = (const float*)d_in[M[21]];
    const float* bo = (const float*)d_in[M[22]];
    const float* ln2_s = (const float*)d_in[M[23]];
    const float* ln2_o = (const float*)d_in[M[24]];
    const float* wg = (const float*)d_in[M[25]];
    const float* wvm = (const float*)d_in[M[26]];
    const float* wom = (const float*)d_in[M[27]];
    const float* ln3_s = (const float*)d_in[M[28]];
    const float* ln3_o = (const float*)d_in[M[29]];
    const float* wpos = (const float*)d_in[M[30]];

    int N = in_sizes[0] / DMODEL;

    float* out_local = (float*)d_out;
    float* out_pos = out_local + (size_t)N * DMODEL;

    char* wsb = (char*)d_ws;
    float* Rw = (float*)wsb;   wsb += (size_t)N * 9 * 4;
    float* lpw = (float*)wsb;  wsb += (size_t)N * 15 * 4;
    bf16* qbh = (bf16*)wsb;    wsb += (size_t)N * 256 * 2;
    bf16* kbh = (bf16*)wsb;    wsb += (size_t)N * 256 * 2;
    bf16* vbh = (bf16*)wsb;    wsb += (size_t)N * 256 * 2;
    bf16* qpl = (bf16*)wsb;    wsb += (size_t)N * 192 * 2;
    bf16* kpl = (bf16*)wsb;    wsb += (size_t)N * 192 * 2;
    bf16* vpl = (bf16*)wsb;    wsb += (size_t)N * 192 * 2;
    bf16* ipab = (bf16*)wsb;   wsb += (size_t)N * 1024 * 2;
    float* qpg = (float*)wsb;  wsb += (size_t)N * 192 * 4;
    float* kpg = (float*)wsb;  wsb += (size_t)N * 192 * 4;
    float* vpg = (float*)wsb;  wsb += (size_t)N * 192 * 4;
    unsigned short* wtrans = (unsigned short*)wsb; wsb += (size_t)WT_TOTAL * 2;
    unsigned short* wAllT = wtrans + OFF_WALL;
    unsigned short* woT   = wtrans + OFF_WO;
    unsigned short* wgT   = wtrans + OFF_WG;
    unsigned short* wvmT  = wtrans + OFF_WVM;
    unsigned short* womT  = wtrans + OFF_WOM;
    unsigned short* wpT   = wtrans + OFF_WP;

    dim3 blk(256);
    hipLaunchKernelGGL(kT, dim3(512), blk, 0, stream, wq, wk, wv, wqp, wkp, wvp,
                       wo, wg, wvm, wom, w_pair, wtrans);
    hipLaunchKernelGGL(kA, dim3(N), blk, 0, stream, local, pos, w_in, Rw, lpw, out_local);
    hipLaunchKernelGGL(kB, dim3(N / 32), blk, 0, stream, out_local, ln1_s, ln1_o, wAllT,
                       qbh, kbh, vbh, qpl, kpl, vpl);
    hipLaunchKernelGGL(kP, dim3(N / 4), blk, 0, stream, qpl, kpl, vpl, Rw, pos, qpg, kpg, vpg);
    hipLaunchKernelGGL(kC, dim3(N), blk, 0, stream, pos, nbr, resi, chain, batch, mask, Rw,
                       w_pair, wpT, b_pair, wbm, gamma, qbh, kbh, vbh, qpg, kpg, vpg, ipab, N);
    hipLaunchKernelGGL(kD, dim3(N / 32), blk, 0, stream, ipab, woT, bo, out_local);
    hipLaunchKernelGGL(kE, dim3(N / 32), blk, 0, stream, ln2_s, ln2_o, wgT, wvmT, womT, out_local);
    hipLaunchKernelGGL(kF, dim3(N), blk, 0, stream, out_local, ln3_s, ln3_o, wpos, lpw, Rw, pos,
                       umask, out_pos);
}

// Round 10
// 731.676 us; speedup vs baseline: 2.9979x; 1.0765x over previous
//
#include <hip/hip_runtime.h>
#include <hip/hip_bf16.h>
#include <math.h>

#define DMODEL 256
#define KNB 32
#define NHEAD 8
#define FIN 95
#define FPD 95        // dense part of pair features
#define KPAD 104      // padded K for pair/feat MFMA staging
#define FOUT 1024
#define DHID 512

typedef __hip_bfloat16 bf16;
typedef __attribute__((ext_vector_type(8))) short short8;
typedef __attribute__((ext_vector_type(4))) float floatx4;

__device__ inline float B2F(bf16 x) { return __bfloat162float(x); }
__device__ inline bf16 F2B(float x) { return __float2bfloat16(x); }
__device__ inline unsigned short f2bs(float x) {
    bf16 h = __float2bfloat16(x);
    return *reinterpret_cast<unsigned short*>(&h);
}
__device__ inline float bs2f(short s) {
    return __uint_as_float(((unsigned)(unsigned short)s) << 16);
}

__device__ inline float gelu_t(float x) {
    return 0.5f * x * (1.f + tanhf(0.7978845608028654f * (x + 0.044715f * x * x * x)));
}

// ---- weight transpose buffer layout (bf16 elements) ----
#define OFF_WALL 0          // [1344][256]  q|k|v|qp|kp|vp columns
#define OFF_WO   344064     // [256][1024]
#define OFF_WG   606208     // [512][256]
#define OFF_WVM  737280     // [512][256]
#define OFF_WOM  868352     // [256][512]
#define OFF_WP   999424     // [64][KPAD]
#define OFF_WIN  1006080    // [256][KPAD]  w_in transposed
#define WT_TOTAL 1032704

// Kernel T: transpose/convert all weights to bf16 [n][k] (k-contiguous)
__global__ __launch_bounds__(256) void kT(const float* __restrict__ wq, const float* __restrict__ wk,
                                          const float* __restrict__ wv, const float* __restrict__ wqp,
                                          const float* __restrict__ wkp, const float* __restrict__ wvp,
                                          const float* __restrict__ wo, const float* __restrict__ wg,
                                          const float* __restrict__ wvm, const float* __restrict__ wom,
                                          const float* __restrict__ w_pair, const float* __restrict__ w_in,
                                          unsigned short* __restrict__ wt) {
    int stride = gridDim.x * 256;
    for (int e = blockIdx.x * 256 + threadIdx.x; e < WT_TOTAL; e += stride) {
        float v;
        if (e < OFF_WO) {
            int n = e >> 8, k = e & 255;
            if (n < 256) v = wq[k * 256 + n];
            else if (n < 512) v = wk[k * 256 + n - 256];
            else if (n < 768) v = wv[k * 256 + n - 512];
            else if (n < 960) v = wqp[k * 192 + n - 768];
            else if (n < 1152) v = wkp[k * 192 + n - 960];
            else v = wvp[k * 192 + n - 1152];
        } else if (e < OFF_WG) {
            int u = e - OFF_WO; int n = u >> 10, k = u & 1023;
            v = wo[k * 256 + n];
        } else if (e < OFF_WVM) {
            int u = e - OFF_WG; int n = u >> 8, k = u & 255;
            v = wg[k * 512 + n];
        } else if (e < OFF_WOM) {
            int u = e - OFF_WVM; int n = u >> 8, k = u & 255;
            v = wvm[k * 512 + n];
        } else if (e < OFF_WP) {
            int u = e - OFF_WOM; int n = u >> 9, k = u & 511;
            v = wom[k * 256 + n];
        } else if (e < OFF_WIN) {
            int u = e - OFF_WP; int n = u / KPAD, k = u % KPAD;
            v = (k < FPD) ? w_pair[k * 64 + n] : 0.f;
        } else {
            int u = e - OFF_WIN; int n = u / KPAD, k = u % KPAD;
            v = (k < FIN) ? w_in[k * 256 + n] : 0.f;
        }
        wt[e] = f2bs(v);
    }
}

// Kernel A1: frames + feat (bf16, 104-padded). 8 residues/block, 32 threads each.
__global__ __launch_bounds__(256) void kA1(const float* __restrict__ pos,
                                           float* __restrict__ Rw,
                                           float* __restrict__ lpw,
                                           unsigned short* __restrict__ featb) {
    int tid = threadIdx.x;
    int res = tid >> 5, lt = tid & 31;
    int ri = blockIdx.x * 8 + res;
    const float* pp = pos + (size_t)ri * 15;
    float nx = pp[0], ny = pp[1], nz = pp[2];
    float cax = pp[3], cay = pp[4], caz = pp[5];
    float cx = pp[6], cy = pp[7], cz = pp[8];
    float e1x = cx - cax, e1y = cy - cay, e1z = cz - caz;
    float inv = rsqrtf(e1x * e1x + e1y * e1y + e1z * e1z + 1e-6f);
    e1x *= inv; e1y *= inv; e1z *= inv;
    float ux = nx - cax, uy = ny - cay, uz = nz - caz;
    float d = ux * e1x + uy * e1y + uz * e1z;
    float wx = ux - d * e1x, wy = uy - d * e1y, wz = uz - d * e1z;
    inv = rsqrtf(wx * wx + wy * wy + wz * wz + 1e-6f);
    float e2x = wx * inv, e2y = wy * inv, e2z = wz * inv;
    float e3x = e1y * e2z - e1z * e2y;
    float e3y = e1z * e2x - e1x * e2z;
    float e3z = e1x * e2y - e1y * e2x;
    float R[9] = {e1x, e2x, e3x, e1y, e2y, e3y, e1z, e2z, e3z};

    __shared__ float lpS[8][15];
    __shared__ float ddS[8][5], dinvS[8][5];

    if (lt < 9) Rw[(size_t)ri * 9 + lt] = R[lt];
    if (lt < 15) {
        int a = lt / 3, ii = lt % 3;
        float px = pp[a * 3 + 0] - cax, py = pp[a * 3 + 1] - cay, pz = pp[a * 3 + 2] - caz;
        float v = R[0 * 3 + ii] * px + R[1 * 3 + ii] * py + R[2 * 3 + ii] * pz;
        lpS[res][lt] = v;
        lpw[(size_t)ri * 15 + lt] = v;
    }
    __syncthreads();
    if (lt < 5) {
        float s = lpS[res][lt * 3] * lpS[res][lt * 3] + lpS[res][lt * 3 + 1] * lpS[res][lt * 3 + 1] +
                  lpS[res][lt * 3 + 2] * lpS[res][lt * 3 + 2];
        ddS[res][lt] = sqrtf(s + 1e-12f);
        dinvS[res][lt] = rsqrtf(s + 1e-6f);
    }
    __syncthreads();
    for (int e = lt; e < KPAD; e += 32) {
        float v;
        if (e < 15) v = lpS[res][e] * dinvS[res][e / 3];
        else if (e < 95) {
            int u = e - 15, a = u >> 4, b = u & 15;
            float z = (ddS[res][a] - (float)b * (10.f / 15.f)) * (1.f / 0.625f);
            v = expf(-z * z);
        } else v = 0.f;
        featb[(size_t)ri * KPAD + e] = f2bs(v);
    }
}

// Kernel B: lup = local + feat@w_inT (MFMA) -> dlocal; LN1; 6 projections via MFMA. 32 rows/block.
__global__ __launch_bounds__(256) void kB(const float* __restrict__ local,
                                          const unsigned short* __restrict__ featb,
                                          const float* __restrict__ ln1_s,
                                          const float* __restrict__ ln1_o,
                                          const unsigned short* __restrict__ wAllT,
                                          const unsigned short* __restrict__ w_inT,
                                          float* __restrict__ dlocal,
                                          bf16* __restrict__ qbh, bf16* __restrict__ kbh,
                                          bf16* __restrict__ vbh, bf16* __restrict__ qpl,
                                          bf16* __restrict__ kpl, bf16* __restrict__ vpl) {
    int r0 = blockIdx.x * 32;
    int tid = threadIdx.x;
    __shared__ __align__(16) unsigned short featA[32 * KPAD];
    __shared__ __align__(16) unsigned short xbf[32 * 264];
    __shared__ float statsS[32 * 4];  // [row][par*2 + {sum,sumsq}]

    // stage feat rows (contiguous copy)
    {
        const short8* src = reinterpret_cast<const short8*>(featb + (size_t)r0 * KPAD);
        short8* dst = reinterpret_cast<short8*>(featA);
        for (int c = tid; c < 32 * KPAD / 8; c += 256) dst[c] = src[c];
    }
    __syncthreads();

    int lane = tid & 63, w = tid >> 6;
    int mtile = w & 1, par = w >> 1;
    int m = lane & 15, quad = lane >> 4;

    // lup GEMM: (32 x 96) @ (96 x 256)
    short8 fa[3];
#pragma unroll
    for (int ks = 0; ks < 3; ks++)
        fa[ks] = *reinterpret_cast<const short8*>(&featA[(mtile * 16 + m) * KPAD + ks * 32 + quad * 8]);
    float lupv[8][4];
#pragma unroll
    for (int j = 0; j < 8; j++) {
        int nt = par + 2 * j;
        floatx4 c = {0.f, 0.f, 0.f, 0.f};
        const short8* bp = reinterpret_cast<const short8*>(w_inT + (size_t)(nt * 16 + m) * KPAD);
#pragma unroll
        for (int ks = 0; ks < 3; ks++)
            c = __builtin_amdgcn_mfma_f32_16x16x32_bf16(fa[ks], bp[ks * 4 + quad], c, 0, 0, 0);
        int col = nt * 16 + m;
#pragma unroll
        for (int r = 0; r < 4; r++) {
            int row = mtile * 16 + quad * 4 + r;
            float lv = local[(size_t)(r0 + row) * 256 + col] + c[r];
            lupv[j][r] = lv;
            dlocal[(size_t)(r0 + row) * 256 + col] = lv;
        }
    }
    // LN stats: partial over this wave's 128 cols
    {
        float s[4] = {0.f, 0.f, 0.f, 0.f}, ss[4] = {0.f, 0.f, 0.f, 0.f};
#pragma unroll
        for (int j = 0; j < 8; j++)
#pragma unroll
            for (int r = 0; r < 4; r++) { s[r] += lupv[j][r]; ss[r] += lupv[j][r] * lupv[j][r]; }
#pragma unroll
        for (int mask = 1; mask < 16; mask <<= 1)
#pragma unroll
            for (int r = 0; r < 4; r++) { s[r] += __shfl_xor(s[r], mask); ss[r] += __shfl_xor(ss[r], mask); }
        if (m == 0) {
#pragma unroll
            for (int r = 0; r < 4; r++) {
                int row = mtile * 16 + quad * 4 + r;
                statsS[row * 4 + par * 2 + 0] = s[r];
                statsS[row * 4 + par * 2 + 1] = ss[r];
            }
        }
    }
    __syncthreads();
    {
        float mu[4], rs_[4];
#pragma unroll
        for (int r = 0; r < 4; r++) {
            int row = mtile * 16 + quad * 4 + r;
            float S = statsS[row * 4 + 0] + statsS[row * 4 + 2];
            float SS = statsS[row * 4 + 1] + statsS[row * 4 + 3];
            float m_ = S * (1.f / 256.f);
            mu[r] = m_;
            rs_[r] = rsqrtf(SS * (1.f / 256.f) - m_ * m_ + 1e-5f);
        }
#pragma unroll
        for (int j = 0; j < 8; j++) {
            int col = (par + 2 * j) * 16 + m;
            float g = ln1_s[col], o = ln1_o[col];
#pragma unroll
            for (int r = 0; r < 4; r++) {
                int row = mtile * 16 + quad * 4 + r;
                xbf[row * 264 + col] = f2bs((lupv[j][r] - mu[r]) * rs_[r] * g + o);
            }
        }
    }
    __syncthreads();

    // projections
    short8 afr[8];
#pragma unroll
    for (int ks = 0; ks < 8; ks++)
        afr[ks] = *reinterpret_cast<const short8*>(&xbf[(mtile * 16 + m) * 264 + ks * 32 + quad * 8]);
    for (int nt = par; nt < 84; nt += 2) {
        floatx4 c = {0.f, 0.f, 0.f, 0.f};
        const short8* bp = reinterpret_cast<const short8*>(wAllT + (size_t)(nt * 16 + m) * 256);
#pragma unroll
        for (int ks = 0; ks < 8; ks++)
            c = __builtin_amdgcn_mfma_f32_16x16x32_bf16(afr[ks], bp[ks * 4 + quad], c, 0, 0, 0);
        int colg = nt * 16 + m;
        bf16* O; int c0, ncol;
        if (colg < 256)       { O = qbh; c0 = colg;        ncol = 256; }
        else if (colg < 512)  { O = kbh; c0 = colg - 256;  ncol = 256; }
        else if (colg < 768)  { O = vbh; c0 = colg - 512;  ncol = 256; }
        else if (colg < 960)  { O = qpl; c0 = colg - 768;  ncol = 192; }
        else if (colg < 1152) { O = kpl; c0 = colg - 960;  ncol = 192; }
        else                  { O = vpl; c0 = colg - 1152; ncol = 192; }
#pragma unroll
        for (int r = 0; r < 4; r++) {
            int rg = r0 + mtile * 16 + quad * 4 + r;
            O[(size_t)rg * ncol + c0] = F2B(c[r]);
        }
    }
}

// Kernel P: rotate local-frame points (bf16) to global-frame f32: g = R_i @ p + t_i
__global__ __launch_bounds__(256) void kP(const bf16* __restrict__ qpl,
                                          const bf16* __restrict__ kpl,
                                          const bf16* __restrict__ vpl,
                                          const float* __restrict__ Rw,
                                          const float* __restrict__ pos,
                                          float* __restrict__ qpg,
                                          float* __restrict__ kpg,
                                          float* __restrict__ vpg) {
    int r0 = blockIdx.x * 4;
    int tid = threadIdx.x;
    for (int u = tid; u < 4 * 192; u += 256) {
        int r = u / 192, e = u % 192, hp = e / 3, ii = e % 3;
        int ri = r0 + r;
        float R0 = Rw[(size_t)ri * 9 + ii * 3 + 0];
        float R1 = Rw[(size_t)ri * 9 + ii * 3 + 1];
        float R2 = Rw[(size_t)ri * 9 + ii * 3 + 2];
        float tt = pos[(size_t)ri * 15 + 3 + ii];
        size_t base = (size_t)ri * 192 + hp * 3;
        qpg[(size_t)ri * 192 + e] = R0 * B2F(qpl[base]) + R1 * B2F(qpl[base + 1]) + R2 * B2F(qpl[base + 2]) + tt;
        kpg[(size_t)ri * 192 + e] = R0 * B2F(kpl[base]) + R1 * B2F(kpl[base + 1]) + R2 * B2F(kpl[base + 2]) + tt;
        vpg[(size_t)ri * 192 + e] = R0 * B2F(vpl[base]) + R1 * B2F(vpl[base + 1]) + R2 * B2F(vpl[base + 2]) + tt;
    }
}

// Kernel C: pair features (MFMA pair MLP) + attention + IPA concat (bf16 out)
__global__ __launch_bounds__(256) void kC(const float* __restrict__ pos,
                                          const int* __restrict__ nbr,
                                          const int* __restrict__ resi,
                                          const int* __restrict__ chain,
                                          const int* __restrict__ batch,
                                          const int* __restrict__ mask,
                                          const float* __restrict__ Rw,
                                          const float* __restrict__ w_pair,
                                          const unsigned short* __restrict__ wT,
                                          const float* __restrict__ b_pair,
                                          const float* __restrict__ wbm,
                                          const float* __restrict__ gamma,
                                          const bf16* __restrict__ qbh,
                                          const bf16* __restrict__ kbh,
                                          const bf16* __restrict__ vbh,
                                          const float* __restrict__ qpg,
                                          const float* __restrict__ kpg,
                                          const float* __restrict__ vpg,
                                          bf16* __restrict__ ipab,
                                          int N) {
    int i = blockIdx.x;
    int tid = threadIdx.x;
    __shared__ __align__(16) float qS[256];
    __shared__ __align__(16) float qpS[192];
    __shared__ __align__(16) unsigned short pfA[KNB * KPAD];
    __shared__ __align__(16) float pairS[KNB][68];
    __shared__ __align__(16) float wbmS[NHEAD][68];
    __shared__ float lg[KNB * NHEAD];
    __shared__ float optg[192];
    __shared__ float ipaS[FOUT];
    __shared__ int idxS[KNB], rpS[KNB], scS[KNB], sbS[KNB], pmS[KNB];

    float R[9];
#pragma unroll
    for (int u = 0; u < 9; u++) R[u] = Rw[(size_t)i * 9 + u];
    float t0 = pos[(size_t)i * 15 + 3];
    float t1 = pos[(size_t)i * 15 + 4];
    float t2 = pos[(size_t)i * 15 + 5];

    qS[tid] = B2F(qbh[(size_t)i * 256 + tid]);
    if (tid < 192) qpS[tid] = qpg[(size_t)i * 192 + tid];
    if (tid < KNB) {
        int nb = nbr[(size_t)i * KNB + tid];
        int j = min(max(nb, 0), N - 1);
        idxS[tid] = j;
        int rp = resi[j] - resi[i];
        rp = min(max(rp, -32), 32) + 32;
        rpS[tid] = rp;
        scS[tid] = (chain[j] == chain[i]) ? 1 : 0;
        sbS[tid] = (batch[j] == batch[i]) ? 1 : 0;
        pmS[tid] = (mask[i] != 0 && mask[j] != 0 && nb >= 0 && batch[j] == batch[i]) ? 1 : 0;
    }
    __syncthreads();
    for (int u = tid; u < 512; u += 256) {
        int h = u & 7, c = u >> 3;
        wbmS[h][c] = wbm[c * 8 + h];
    }
    if (tid < 160) {
        int kk = tid & 31, a = tid >> 5;
        int j = idxS[kk];
        const float* pj = pos + (size_t)j * 15 + a * 3;
        float px = pj[0] - t0, py = pj[1] - t1, pz = pj[2] - t2;
        float r0_ = R[0] * px + R[3] * py + R[6] * pz;
        float r1_ = R[1] * px + R[4] * py + R[7] * pz;
        float r2_ = R[2] * px + R[5] * py + R[8] * pz;
        float s = r0_ * r0_ + r1_ * r1_ + r2_ * r2_;
        float dij = sqrtf(s + 1e-12f);
        float di = 1.f / (dij + 1e-6f);
        pfA[kk * KPAD + a * 3 + 0] = f2bs(r0_ * di);
        pfA[kk * KPAD + a * 3 + 1] = f2bs(r1_ * di);
        pfA[kk * KPAD + a * 3 + 2] = f2bs(r2_ * di);
        for (int b = 0; b < 16; b++) {
            float z = (dij - (float)b * (10.f / 15.f)) * (1.f / 0.625f);
            pfA[kk * KPAD + 15 + a * 16 + b] = f2bs(expf(-z * z));
        }
    }
    if (tid < KNB) pfA[tid * KPAD + FPD] = 0;
    __syncthreads();

    // pair MLP via MFMA
    {
        int lane = tid & 63;
        int wv = tid >> 6;
        int n0 = wv * 16;
        int mrow = lane & 15;
        int quad = lane >> 4;
        floatx4 c0 = {0.f, 0.f, 0.f, 0.f};
        floatx4 c1 = {0.f, 0.f, 0.f, 0.f};
#pragma unroll
        for (int ks = 0; ks < 3; ks++) {
            int k0 = ks * 32 + quad * 8;
            short8 a0 = *reinterpret_cast<const short8*>(&pfA[mrow * KPAD + k0]);
            short8 a1 = *reinterpret_cast<const short8*>(&pfA[(16 + mrow) * KPAD + k0]);
            short8 bb = *reinterpret_cast<const short8*>(&wT[(n0 + mrow) * KPAD + k0]);
            c0 = __builtin_amdgcn_mfma_f32_16x16x32_bf16(a0, bb, c0, 0, 0, 0);
            c1 = __builtin_amdgcn_mfma_f32_16x16x32_bf16(a1, bb, c1, 0, 0, 0);
        }
        int col = n0 + mrow;
        float bp = b_pair[col];
        float w160 = w_pair[160 * 64 + col];
        float w161 = w_pair[161 * 64 + col];
#pragma unroll
        for (int mt = 0; mt < 2; mt++) {
            floatx4 cc = mt ? c1 : c0;
#pragma unroll
            for (int r = 0; r < 4; r++) {
                int row = mt * 16 + quad * 4 + r;
                float s = cc[r] + bp + w_pair[(95 + rpS[row]) * 64 + col] +
                          (scS[row] ? w160 : 0.f) + (sbS[row] ? w161 : 0.f);
                pairS[row][col] = gelu_t(s);
            }
        }
    }
    __syncthreads();

    // logits
    {
        int kk = tid >> 3, h = tid & 7;
        int j = idxS[kk];
        float qk = 0.f;
        const short8* kj8 = reinterpret_cast<const short8*>(kbh + (size_t)j * 256 + h * 32);
        const floatx4* qh4 = reinterpret_cast<const floatx4*>(qS + h * 32);
#pragma unroll
        for (int e = 0; e < 4; e++) {
            short8 kv = kj8[e];
            floatx4 qa = qh4[2 * e], qb = qh4[2 * e + 1];
            qk += qa[0] * bs2f(kv[0]) + qa[1] * bs2f(kv[1]) + qa[2] * bs2f(kv[2]) + qa[3] * bs2f(kv[3]) +
                  qb[0] * bs2f(kv[4]) + qb[1] * bs2f(kv[5]) + qb[2] * bs2f(kv[6]) + qb[3] * bs2f(kv[7]);
        }
        qk *= 0.17677669529663687f;
        float d2 = 0.f;
        const floatx4* kp4 = reinterpret_cast<const floatx4*>(kpg + (size_t)j * 192 + h * 24);
        const floatx4* qp4 = reinterpret_cast<const floatx4*>(qpS + h * 24);
#pragma unroll
        for (int e = 0; e < 6; e++) {
            floatx4 kv = kp4[e], qv = qp4[e];
#pragma unroll
            for (int q = 0; q < 4; q++) {
                float df = qv[q] - kv[q];
                d2 += df * df;
            }
        }
        float pb = 0.f;
        const floatx4* ps4 = reinterpret_cast<const floatx4*>(&pairS[kk][0]);
        const floatx4* wb4 = reinterpret_cast<const floatx4*>(&wbmS[h][0]);
#pragma unroll
        for (int e = 0; e < 16; e++) {
            floatx4 pv = ps4[e], wv4 = wb4[e];
            pb += pv[0] * wv4[0] + pv[1] * wv4[1] + pv[2] * wv4[2] + pv[3] * wv4[3];
        }
        float sp = log1pf(expf(gamma[h]));
        float lgt = 0.5773502691896258f * (qk + pb - (1.f / 12.f) * sp * d2);
        lg[kk * 8 + h] = pmS[kk] ? lgt : -1e9f;
    }
    __syncthreads();
    if (tid < 8) {
        int h = tid;
        float m = -INFINITY;
        for (int kk = 0; kk < KNB; kk++) m = fmaxf(m, lg[kk * 8 + h]);
        float s = 0.f;
        for (int kk = 0; kk < KNB; kk++) s += expf(lg[kk * 8 + h] - m);
        float invs = 1.f / s;
        for (int kk = 0; kk < KNB; kk++) {
            float a = expf(lg[kk * 8 + h] - m) * invs;
            lg[kk * 8 + h] = pmS[kk] ? a : 0.f;
        }
    }
    __syncthreads();
    {
        int h = tid >> 5, d = tid & 31;
        float s = 0.f;
        for (int kk = 0; kk < KNB; kk++)
            s += lg[kk * 8 + h] * B2F(vbh[(size_t)idxS[kk] * 256 + h * 32 + d]);
        ipaS[h * 32 + d] = s;
    }
    for (int u = tid; u < 512; u += 256) {
        int h = u >> 6, c = u & 63;
        float s = 0.f;
        for (int kk = 0; kk < KNB; kk++) s += lg[kk * 8 + h] * pairS[kk][c];
        ipaS[256 + u] = s;
    }
    if (tid < 192) {
        int h = tid / 24;
        float s = 0.f;
        for (int kk = 0; kk < KNB; kk++)
            s += lg[kk * 8 + h] * vpg[(size_t)idxS[kk] * 192 + tid];
        optg[tid] = s;
    }
    __syncthreads();
    if (tid < 192) {
        int hp = tid / 3, ii = tid % 3;
        float v0 = optg[hp * 3 + 0] - t0, v1 = optg[hp * 3 + 1] - t1, v2 = optg[hp * 3 + 2] - t2;
        ipaS[768 + tid] = R[0 + ii] * v0 + R[3 + ii] * v1 + R[6 + ii] * v2;
    }
    __syncthreads();
    if (tid < 64) {
        float a0 = ipaS[768 + tid * 3], a1 = ipaS[768 + tid * 3 + 1], a2 = ipaS[768 + tid * 3 + 2];
        ipaS[960 + tid] = sqrtf(a0 * a0 + a1 * a1 + a2 * a2 + 1e-8f);
    }
    __syncthreads();
    for (int u = tid; u < FOUT; u += 256) ipab[(size_t)i * FOUT + u] = F2B(ipaS[u]);
}

// Kernel D: dlocal += ipa @ wo + bo via MFMA. 32 rows/block. A from global ipab.
__global__ __launch_bounds__(256) void kD(const bf16* __restrict__ ipab,
                                          const unsigned short* __restrict__ woT,
                                          const float* __restrict__ bo,
                                          float* __restrict__ dlocal) {
    int r0 = blockIdx.x * 32;
    int tid = threadIdx.x;
    int lane = tid & 63, w = tid >> 6;
    int mtile = w & 1, m = lane & 15, quad = lane >> 4;
    floatx4 acc[8];
#pragma unroll
    for (int j = 0; j < 8; j++) acc[j] = {0.f, 0.f, 0.f, 0.f};
    const short8* arow = reinterpret_cast<const short8*>(ipab + (size_t)(r0 + mtile * 16 + m) * 1024);
    for (int ks = 0; ks < 32; ks++) {
        short8 a = arow[ks * 4 + quad];
#pragma unroll
        for (int j = 0; j < 8; j++) {
            int nt = (w >> 1) + 2 * j;
            const short8* bp = reinterpret_cast<const short8*>(woT + (size_t)(nt * 16 + m) * 1024);
            acc[j] = __builtin_amdgcn_mfma_f32_16x16x32_bf16(a, bp[ks * 4 + quad], acc[j], 0, 0, 0);
        }
    }
#pragma unroll
    for (int j = 0; j < 8; j++) {
        int nt = (w >> 1) + 2 * j;
        int colg = nt * 16 + m;
        float bov = bo[colg];
#pragma unroll
        for (int r = 0; r < 4; r++) {
            size_t off = (size_t)(r0 + mtile * 16 + quad * 4 + r) * 256 + colg;
            dlocal[off] += acc[j][r] + bov;
        }
    }
}

// Kernel E: LN2 + transition MLP via MFMA, in-place on dlocal. 32 rows/block.
__global__ __launch_bounds__(256) void kE(const float* __restrict__ ln2_s,
                                          const float* __restrict__ ln2_o,
                                          const unsigned short* __restrict__ wgT,
                                          const unsigned short* __restrict__ wvmT,
                                          const unsigned short* __restrict__ womT,
                                          float* __restrict__ dlocal) {
    int r0 = blockIdx.x * 32;
    int tid = threadIdx.x;
    __shared__ __align__(16) unsigned short xbf[32 * 264];
    __shared__ __align__(16) unsigned short hbf[32 * 520];
    {
        int row = tid >> 3, seg = tid & 7;
        const floatx4* src = reinterpret_cast<const floatx4*>(dlocal + (size_t)(r0 + row) * 256 + seg * 32);
        floatx4 vv[8];
        float s = 0.f, ss = 0.f;
#pragma unroll
        for (int e = 0; e < 8; e++) {
            vv[e] = src[e];
#pragma unroll
            for (int q = 0; q < 4; q++) { s += vv[e][q]; ss += vv[e][q] * vv[e][q]; }
        }
        s += __shfl_xor(s, 1); ss += __shfl_xor(ss, 1);
        s += __shfl_xor(s, 2); ss += __shfl_xor(ss, 2);
        s += __shfl_xor(s, 4); ss += __shfl_xor(ss, 4);
        float mu = s * (1.f / 256.f);
        float var = ss * (1.f / 256.f) - mu * mu;
        float rs = rsqrtf(var + 1e-5f);
#pragma unroll
        for (int e = 0; e < 8; e++) {
#pragma unroll
            for (int q = 0; q < 4; q++) {
                int f = seg * 32 + e * 4 + q;
                xbf[row * 264 + f] = f2bs((vv[e][q] - mu) * rs * ln2_s[f] + ln2_o[f]);
            }
        }
    }
    __syncthreads();
    int lane = tid & 63, w = tid >> 6;
    int mtile = w & 1, m = lane & 15, quad = lane >> 4;
    short8 afr[8];
#pragma unroll
    for (int ks = 0; ks < 8; ks++)
        afr[ks] = *reinterpret_cast<const short8*>(&xbf[(mtile * 16 + m) * 264 + ks * 32 + quad * 8]);
    for (int nt = (w >> 1); nt < 32; nt += 2) {
        floatx4 cg = {0.f, 0.f, 0.f, 0.f};
        floatx4 cv = {0.f, 0.f, 0.f, 0.f};
        const short8* bg = reinterpret_cast<const short8*>(wgT + (size_t)(nt * 16 + m) * 256);
        const short8* bv = reinterpret_cast<const short8*>(wvmT + (size_t)(nt * 16 + m) * 256);
#pragma unroll
        for (int ks = 0; ks < 8; ks++) {
            cg = __builtin_amdgcn_mfma_f32_16x16x32_bf16(afr[ks], bg[ks * 4 + quad], cg, 0, 0, 0);
            cv = __builtin_amdgcn_mfma_f32_16x16x32_bf16(afr[ks], bv[ks * 4 + quad], cv, 0, 0, 0);
        }
#pragma unroll
        for (int r = 0; r < 4; r++) {
            int row = mtile * 16 + quad * 4 + r;
            hbf[row * 520 + nt * 16 + m] = f2bs(gelu_t(cg[r]) * cv[r]);
        }
    }
    __syncthreads();
    floatx4 acc[8];
#pragma unroll
    for (int j = 0; j < 8; j++) acc[j] = {0.f, 0.f, 0.f, 0.f};
    for (int ks = 0; ks < 16; ks++) {
        short8 a = *reinterpret_cast<const short8*>(&hbf[(mtile * 16 + m) * 520 + ks * 32 + quad * 8]);
#pragma unroll
        for (int j = 0; j < 8; j++) {
            int nt = (w >> 1) + 2 * j;
            const short8* bp = reinterpret_cast<const short8*>(womT + (size_t)(nt * 16 + m) * 512);
            acc[j] = __builtin_amdgcn_mfma_f32_16x16x32_bf16(a, bp[ks * 4 + quad], acc[j], 0, 0, 0);
        }
    }
#pragma unroll
    for (int j = 0; j < 8; j++) {
        int nt = (w >> 1) + 2 * j;
        int colg = nt * 16 + m;
#pragma unroll
        for (int r = 0; r < 4; r++) {
            size_t off = (size_t)(r0 + mtile * 16 + quad * 4 + r) * 256 + colg;
            dlocal[off] += acc[j][r];
        }
    }
}

// Kernel F: LN3 + wpos + frame transform + update_mask. 8 rows/block.
__global__ __launch_bounds__(256) void kF(const float* __restrict__ dlocal,
                                          const float* __restrict__ ln3_s,
                                          const float* __restrict__ ln3_o,
                                          const float* __restrict__ wpos,
                                          const float* __restrict__ lpw,
                                          const float* __restrict__ Rw,
                                          const float* __restrict__ pos,
                                          const int* __restrict__ umask,
                                          float* __restrict__ outp) {
    int tid = threadIdx.x;
    int r = tid >> 5, lt = tid & 31;
    int ri = blockIdx.x * 8 + r;
    __shared__ float x3S[8][256];
    __shared__ float nlS[8][15];
    {
        const floatx4* src = reinterpret_cast<const floatx4*>(dlocal + (size_t)ri * 256 + lt * 8);
        floatx4 v0 = src[0], v1 = src[1];
        float s = 0.f, ss = 0.f;
#pragma unroll
        for (int q = 0; q < 4; q++) {
            s += v0[q] + v1[q];
            ss += v0[q] * v0[q] + v1[q] * v1[q];
        }
#pragma unroll
        for (int mask = 1; mask < 32; mask <<= 1) { s += __shfl_xor(s, mask); ss += __shfl_xor(ss, mask); }
        float mu = s * (1.f / 256.f);
        float var = ss * (1.f / 256.f) - mu * mu;
        float rs = rsqrtf(var + 1e-5f);
#pragma unroll
        for (int q = 0; q < 4; q++) {
            int f0 = lt * 8 + q, f1 = lt * 8 + 4 + q;
            x3S[r][f0] = (v0[q] - mu) * rs * ln3_s[f0] + ln3_o[f0];
            x3S[r][f1] = (v1[q] - mu) * rs * ln3_s[f1] + ln3_o[f1];
        }
    }
    __syncthreads();
    // wpos dot: 8 groups of 32 lanes; each group handles outputs out = g, g+8, ...
    {
        int g = tid >> 5, sub = tid & 31;
        for (int out = g; out < 120; out += 8) {
            int rr = out / 15, e = out % 15;
            float partial = 0.f;
#pragma unroll
            for (int i2 = 0; i2 < 8; i2++) {
                int f = sub + 32 * i2;
                partial += x3S[rr][f] * wpos[f * 15 + e];
            }
#pragma unroll
            for (int mask = 1; mask < 32; mask <<= 1) partial += __shfl_xor(partial, mask);
            if (sub == 0) nlS[rr][e] = lpw[(size_t)(blockIdx.x * 8 + rr) * 15 + e] + partial;
        }
    }
    __syncthreads();
    if (tid < 120) {
        int rr = tid / 15, e = tid % 15;
        int rj = blockIdx.x * 8 + rr;
        int a2 = e / 3, ii = e % 3;
        float R0 = Rw[(size_t)rj * 9 + ii * 3 + 0];
        float R1 = Rw[(size_t)rj * 9 + ii * 3 + 1];
        float R2 = Rw[(size_t)rj * 9 + ii * 3 + 2];
        float tt = pos[(size_t)rj * 15 + 3 + ii];
        float np = R0 * nlS[rr][a2 * 3 + 0] + R1 * nlS[rr][a2 * 3 + 1] + R2 * nlS[rr][a2 * 3 + 2] + tt;
        float old = pos[(size_t)rj * 15 + e];
        outp[(size_t)rj * 15 + e] = (umask[rj] != 0) ? np : old;
    }
}

extern "C" void kernel_launch(void* const* d_in, const int* in_sizes, int n_in,
                              void* d_out, int out_size, void* d_ws, size_t ws_size,
                              hipStream_t stream) {
    static const int map_dict[31] = {0, 1, 2, 3, 4, 5, 6, 7, 8, 9, 10, 11, 12, 13, 14, 15,
                                     16, 17, 18, 19, 20, 21, 22, 23, 24, 25, 26, 27, 28, 29, 30};
    static const int map_sig[31] = {0, 1, 25, 26, 27, 28, 29, 30, 2, 3, 4, 5, 6, 7, 8, 9,
                                    10, 11, 12, 13, 14, 15, 16, 17, 18, 19, 20, 21, 22, 23, 24};
    const int* M = (in_sizes[2] == FIN * DMODEL) ? map_sig : map_dict;

    const float* local = (const float*)d_in[M[0]];
    const float* pos = (const float*)d_in[M[1]];
    const int* nbr = (const int*)d_in[M[2]];
    const int* resi = (const int*)d_in[M[3]];
    const int* chain = (const int*)d_in[M[4]];
    const int* batch = (const int*)d_in[M[5]];
    const int* umask = (const int*)d_in[M[6]];
    const int* mask = (const int*)d_in[M[7]];
    const float* w_in = (const float*)d_in[M[8]];
    const float* w_pair = (const float*)d_in[M[9]];
    const float* b_pair = (const float*)d_in[M[10]];
    const float* ln1_s = (const float*)d_in[M[11]];
    const float* ln1_o = (const float*)d_in[M[12]];
    const float* wq = (const float*)d_in[M[13]];
    const float* wk = (const float*)d_in[M[14]];
    const float* wv = (const float*)d_in[M[15]];
    const float* wqp = (const float*)d_in[M[16]];
    const float* wkp = (const float*)d_in[M[17]];
    const float* wvp = (const float*)d_in[M[18]];
    const float* wbm = (const float*)d_in[M[19]];
    const float* gamma = (const float*)d_in[M[20]];
    const float* wo = (const float*)d_in[M[21]];
    const float* bo = (const float*)d_in[M[22]];
    const float* ln2_s = (const float*)d_in[M[23]];
    const float* ln2_o = (const float*)d_in[M[24]];
    const float* wg = (const float*)d_in[M[25]];
    const float* wvm = (const float*)d_in[M[26]];
    const float* wom = (const float*)d_in[M[27]];
    const float* ln3_s = (const float*)d_in[M[28]];
    const float* ln3_o = (const float*)d_in[M[29]];
    const float* wpos = (const float*)d_in[M[30]];

    int N = in_sizes[0] / DMODEL;

    float* out_local = (float*)d_out;
    float* out_pos = out_local + (size_t)N * DMODEL;

    char* wsb = (char*)d_ws;
    float* Rw = (float*)wsb;   wsb += (size_t)N * 9 * 4;
    float* lpw = (float*)wsb;  wsb += (size_t)N * 15 * 4;
    bf16* qbh = (bf16*)wsb;    wsb += (size_t)N * 256 * 2;
    bf16* kbh = (bf16*)wsb;    wsb += (size_t)N * 256 * 2;
    bf16* vbh = (bf16*)wsb;    wsb += (size_t)N * 256 * 2;
    bf16* qpl = (bf16*)wsb;    wsb += (size_t)N * 192 * 2;
    bf16* kpl = (bf16*)wsb;    wsb += (size_t)N * 192 * 2;
    bf16* vpl = (bf16*)wsb;    wsb += (size_t)N * 192 * 2;
    bf16* ipab = (bf16*)wsb;   wsb += (size_t)N * 1024 * 2;
    float* qpg = (float*)wsb;  wsb += (size_t)N * 192 * 4;
    float* kpg = (float*)wsb;  wsb += (size_t)N * 192 * 4;
    float* vpg = (float*)wsb;  wsb += (size_t)N * 192 * 4;
    unsigned short* featb = (unsigned short*)wsb; wsb += (size_t)N * KPAD * 2;
    unsigned short* wtrans = (unsigned short*)wsb; wsb += (size_t)WT_TOTAL * 2;
    unsigned short* wAllT = wtrans + OFF_WALL;
    unsigned short* woT   = wtrans + OFF_WO;
    unsigned short* wgT   = wtrans + OFF_WG;
    unsigned short* wvmT  = wtrans + OFF_WVM;
    unsigned short* womT  = wtrans + OFF_WOM;
    unsigned short* wpT   = wtrans + OFF_WP;
    unsigned short* winT  = wtrans + OFF_WIN;

    dim3 blk(256);
    hipLaunchKernelGGL(kT, dim3(512), blk, 0, stream, wq, wk, wv, wqp, wkp, wvp,
                       wo, wg, wvm, wom, w_pair, w_in, wtrans);
    hipLaunchKernelGGL(kA1, dim3(N / 8), blk, 0, stream, pos, Rw, lpw, featb);
    hipLaunchKernelGGL(kB, dim3(N / 32), blk, 0, stream, local, featb, ln1_s, ln1_o, wAllT, winT,
                       out_local, qbh, kbh, vbh, qpl, kpl, vpl);
    hipLaunchKernelGGL(kP, dim3(N / 4), blk, 0, stream, qpl, kpl, vpl, Rw, pos, qpg, kpg, vpg);
    hipLaunchKernelGGL(kC, dim3(N), blk, 0, stream, pos, nbr, resi, chain, batch, mask, Rw,
                       w_pair, wpT, b_pair, wbm, gamma, qbh, kbh, vbh, qpg, kpg, vpg, ipab, N);
    hipLaunchKernelGGL(kD, dim3(N / 32), blk, 0, stream, ipab, woT, bo, out_local);
    hipLaunchKernelGGL(kE, dim3(N / 32), blk, 0, stream, ln2_s, ln2_o, wgT, wvmT, womT, out_local);
    hipLaunchKernelGGL(kF, dim3(N / 8), blk, 0, stream, out_local, ln3_s, ln3_o, wpos, lpw, Rw, pos,
                       umask, out_pos);
}

// Round 11
// 669.833 us; speedup vs baseline: 3.2747x; 1.0923x over previous
//
#include <hip/hip_runtime.h>
#include <hip/hip_bf16.h>
#include <math.h>

#define DMODEL 256
#define KNB 32
#define NHEAD 8
#define FIN 95
#define FPD 95        // dense part of pair features
#define KPAD 104      // padded K for pair/feat MFMA staging
#define FOUT 1024
#define DHID 512

typedef __hip_bfloat16 bf16;
typedef __attribute__((ext_vector_type(8))) short short8;
typedef __attribute__((ext_vector_type(4))) float floatx4;

__device__ inline float B2F(bf16 x) { return __bfloat162float(x); }
__device__ inline bf16 F2B(float x) { return __float2bfloat16(x); }
__device__ inline unsigned short f2bs(float x) {
    bf16 h = __float2bfloat16(x);
    return *reinterpret_cast<unsigned short*>(&h);
}
__device__ inline float bs2f(short s) {
    return __uint_as_float(((unsigned)(unsigned short)s) << 16);
}

__device__ inline float gelu_t(float x) {
    return 0.5f * x * (1.f + tanhf(0.7978845608028654f * (x + 0.044715f * x * x * x)));
}

// ---- weight transpose buffer layout (bf16 elements) ----
#define OFF_WALL 0          // [1344][256]  q|k|v|qp|kp|vp columns
#define OFF_WO   344064     // [256][1024]
#define OFF_WG   606208     // [512][256]
#define OFF_WVM  737280     // [512][256]
#define OFF_WOM  868352     // [256][512]
#define OFF_WP   999424     // [64][KPAD]
#define OFF_WIN  1006080    // [256][KPAD]  w_in transposed
#define WT_TOTAL 1032704

// Kernel T: transpose/convert all weights to bf16 [n][k] (k-contiguous)
__global__ __launch_bounds__(256) void kT(const float* __restrict__ wq, const float* __restrict__ wk,
                                          const float* __restrict__ wv, const float* __restrict__ wqp,
                                          const float* __restrict__ wkp, const float* __restrict__ wvp,
                                          const float* __restrict__ wo, const float* __restrict__ wg,
                                          const float* __restrict__ wvm, const float* __restrict__ wom,
                                          const float* __restrict__ w_pair, const float* __restrict__ w_in,
                                          unsigned short* __restrict__ wt) {
    int stride = gridDim.x * 256;
    for (int e = blockIdx.x * 256 + threadIdx.x; e < WT_TOTAL; e += stride) {
        float v;
        if (e < OFF_WO) {
            int n = e >> 8, k = e & 255;
            if (n < 256) v = wq[k * 256 + n];
            else if (n < 512) v = wk[k * 256 + n - 256];
            else if (n < 768) v = wv[k * 256 + n - 512];
            else if (n < 960) v = wqp[k * 192 + n - 768];
            else if (n < 1152) v = wkp[k * 192 + n - 960];
            else v = wvp[k * 192 + n - 1152];
        } else if (e < OFF_WG) {
            int u = e - OFF_WO; int n = u >> 10, k = u & 1023;
            v = wo[k * 256 + n];
        } else if (e < OFF_WVM) {
            int u = e - OFF_WG; int n = u >> 8, k = u & 255;
            v = wg[k * 512 + n];
        } else if (e < OFF_WOM) {
            int u = e - OFF_WVM; int n = u >> 8, k = u & 255;
            v = wvm[k * 512 + n];
        } else if (e < OFF_WP) {
            int u = e - OFF_WOM; int n = u >> 9, k = u & 511;
            v = wom[k * 256 + n];
        } else if (e < OFF_WIN) {
            int u = e - OFF_WP; int n = u / KPAD, k = u % KPAD;
            v = (k < FPD) ? w_pair[k * 64 + n] : 0.f;
        } else {
            int u = e - OFF_WIN; int n = u / KPAD, k = u % KPAD;
            v = (k < FIN) ? w_in[k * 256 + n] : 0.f;
        }
        wt[e] = f2bs(v);
    }
}

// Kernel A1: frames + feat (bf16, 104-padded). 8 residues/block, 32 threads each.
__global__ __launch_bounds__(256) void kA1(const float* __restrict__ pos,
                                           float* __restrict__ Rw,
                                           float* __restrict__ lpw,
                                           unsigned short* __restrict__ featb) {
    int tid = threadIdx.x;
    int res = tid >> 5, lt = tid & 31;
    int ri = blockIdx.x * 8 + res;
    const float* pp = pos + (size_t)ri * 15;
    float nx = pp[0], ny = pp[1], nz = pp[2];
    float cax = pp[3], cay = pp[4], caz = pp[5];
    float cx = pp[6], cy = pp[7], cz = pp[8];
    float e1x = cx - cax, e1y = cy - cay, e1z = cz - caz;
    float inv = rsqrtf(e1x * e1x + e1y * e1y + e1z * e1z + 1e-6f);
    e1x *= inv; e1y *= inv; e1z *= inv;
    float ux = nx - cax, uy = ny - cay, uz = nz - caz;
    float d = ux * e1x + uy * e1y + uz * e1z;
    float wx = ux - d * e1x, wy = uy - d * e1y, wz = uz - d * e1z;
    inv = rsqrtf(wx * wx + wy * wy + wz * wz + 1e-6f);
    float e2x = wx * inv, e2y = wy * inv, e2z = wz * inv;
    float e3x = e1y * e2z - e1z * e2y;
    float e3y = e1z * e2x - e1x * e2z;
    float e3z = e1x * e2y - e1y * e2x;
    float R[9] = {e1x, e2x, e3x, e1y, e2y, e3y, e1z, e2z, e3z};

    __shared__ float lpS[8][15];
    __shared__ float ddS[8][5], dinvS[8][5];

    if (lt < 9) Rw[(size_t)ri * 9 + lt] = R[lt];
    if (lt < 15) {
        int a = lt / 3, ii = lt % 3;
        float px = pp[a * 3 + 0] - cax, py = pp[a * 3 + 1] - cay, pz = pp[a * 3 + 2] - caz;
        float v = R[0 * 3 + ii] * px + R[1 * 3 + ii] * py + R[2 * 3 + ii] * pz;
        lpS[res][lt] = v;
        lpw[(size_t)ri * 15 + lt] = v;
    }
    __syncthreads();
    if (lt < 5) {
        float s = lpS[res][lt * 3] * lpS[res][lt * 3] + lpS[res][lt * 3 + 1] * lpS[res][lt * 3 + 1] +
                  lpS[res][lt * 3 + 2] * lpS[res][lt * 3 + 2];
        ddS[res][lt] = sqrtf(s + 1e-12f);
        dinvS[res][lt] = rsqrtf(s + 1e-6f);
    }
    __syncthreads();
    for (int e = lt; e < KPAD; e += 32) {
        float v;
        if (e < 15) v = lpS[res][e] * dinvS[res][e / 3];
        else if (e < 95) {
            int u = e - 15, a = u >> 4, b = u & 15;
            float z = (ddS[res][a] - (float)b * (10.f / 15.f)) * (1.f / 0.625f);
            v = expf(-z * z);
        } else v = 0.f;
        featb[(size_t)ri * KPAD + e] = f2bs(v);
    }
}

// Kernel B: lup = local + feat@w_inT (MFMA) -> dlocal; LN1; 6 projections via MFMA. 32 rows/block.
// k/v interleaved into kvb[N][512] (k: 0..255, v: 256..511).
__global__ __launch_bounds__(256) void kB(const float* __restrict__ local,
                                          const unsigned short* __restrict__ featb,
                                          const float* __restrict__ ln1_s,
                                          const float* __restrict__ ln1_o,
                                          const unsigned short* __restrict__ wAllT,
                                          const unsigned short* __restrict__ w_inT,
                                          float* __restrict__ dlocal,
                                          bf16* __restrict__ qbh, bf16* __restrict__ kvb,
                                          bf16* __restrict__ qpl, bf16* __restrict__ kpl,
                                          bf16* __restrict__ vpl) {
    int r0 = blockIdx.x * 32;
    int tid = threadIdx.x;
    __shared__ __align__(16) unsigned short featA[32 * KPAD];
    __shared__ __align__(16) unsigned short xbf[32 * 264];
    __shared__ float statsS[32 * 4];

    {
        const short8* src = reinterpret_cast<const short8*>(featb + (size_t)r0 * KPAD);
        short8* dst = reinterpret_cast<short8*>(featA);
        for (int c = tid; c < 32 * KPAD / 8; c += 256) dst[c] = src[c];
    }
    __syncthreads();

    int lane = tid & 63, w = tid >> 6;
    int mtile = w & 1, par = w >> 1;
    int m = lane & 15, quad = lane >> 4;

    short8 fa[3];
#pragma unroll
    for (int ks = 0; ks < 3; ks++)
        fa[ks] = *reinterpret_cast<const short8*>(&featA[(mtile * 16 + m) * KPAD + ks * 32 + quad * 8]);
    float lupv[8][4];
#pragma unroll
    for (int j = 0; j < 8; j++) {
        int nt = par + 2 * j;
        floatx4 c = {0.f, 0.f, 0.f, 0.f};
        const short8* bp = reinterpret_cast<const short8*>(w_inT + (size_t)(nt * 16 + m) * KPAD);
#pragma unroll
        for (int ks = 0; ks < 3; ks++)
            c = __builtin_amdgcn_mfma_f32_16x16x32_bf16(fa[ks], bp[ks * 4 + quad], c, 0, 0, 0);
        int col = nt * 16 + m;
#pragma unroll
        for (int r = 0; r < 4; r++) {
            int row = mtile * 16 + quad * 4 + r;
            float lv = local[(size_t)(r0 + row) * 256 + col] + c[r];
            lupv[j][r] = lv;
            dlocal[(size_t)(r0 + row) * 256 + col] = lv;
        }
    }
    {
        float s[4] = {0.f, 0.f, 0.f, 0.f}, ss[4] = {0.f, 0.f, 0.f, 0.f};
#pragma unroll
        for (int j = 0; j < 8; j++)
#pragma unroll
            for (int r = 0; r < 4; r++) { s[r] += lupv[j][r]; ss[r] += lupv[j][r] * lupv[j][r]; }
#pragma unroll
        for (int mask = 1; mask < 16; mask <<= 1)
#pragma unroll
            for (int r = 0; r < 4; r++) { s[r] += __shfl_xor(s[r], mask); ss[r] += __shfl_xor(ss[r], mask); }
        if (m == 0) {
#pragma unroll
            for (int r = 0; r < 4; r++) {
                int row = mtile * 16 + quad * 4 + r;
                statsS[row * 4 + par * 2 + 0] = s[r];
                statsS[row * 4 + par * 2 + 1] = ss[r];
            }
        }
    }
    __syncthreads();
    {
        float mu[4], rs_[4];
#pragma unroll
        for (int r = 0; r < 4; r++) {
            int row = mtile * 16 + quad * 4 + r;
            float S = statsS[row * 4 + 0] + statsS[row * 4 + 2];
            float SS = statsS[row * 4 + 1] + statsS[row * 4 + 3];
            float m_ = S * (1.f / 256.f);
            mu[r] = m_;
            rs_[r] = rsqrtf(SS * (1.f / 256.f) - m_ * m_ + 1e-5f);
        }
#pragma unroll
        for (int j = 0; j < 8; j++) {
            int col = (par + 2 * j) * 16 + m;
            float g = ln1_s[col], o = ln1_o[col];
#pragma unroll
            for (int r = 0; r < 4; r++) {
                int row = mtile * 16 + quad * 4 + r;
                xbf[row * 264 + col] = f2bs((lupv[j][r] - mu[r]) * rs_[r] * g + o);
            }
        }
    }
    __syncthreads();

    short8 afr[8];
#pragma unroll
    for (int ks = 0; ks < 8; ks++)
        afr[ks] = *reinterpret_cast<const short8*>(&xbf[(mtile * 16 + m) * 264 + ks * 32 + quad * 8]);
    for (int nt = par; nt < 84; nt += 2) {
        floatx4 c = {0.f, 0.f, 0.f, 0.f};
        const short8* bp = reinterpret_cast<const short8*>(wAllT + (size_t)(nt * 16 + m) * 256);
#pragma unroll
        for (int ks = 0; ks < 8; ks++)
            c = __builtin_amdgcn_mfma_f32_16x16x32_bf16(afr[ks], bp[ks * 4 + quad], c, 0, 0, 0);
        int colg = nt * 16 + m;
        bf16* O; int c0, ncol;
        if (colg < 256)       { O = qbh; c0 = colg;        ncol = 256; }
        else if (colg < 768)  { O = kvb; c0 = colg - 256;  ncol = 512; }  // k then v interleaved
        else if (colg < 960)  { O = qpl; c0 = colg - 768;  ncol = 192; }
        else if (colg < 1152) { O = kpl; c0 = colg - 960;  ncol = 192; }
        else                  { O = vpl; c0 = colg - 1152; ncol = 192; }
#pragma unroll
        for (int r = 0; r < 4; r++) {
            int rg = r0 + mtile * 16 + quad * 4 + r;
            O[(size_t)rg * ncol + c0] = F2B(c[r]);
        }
    }
}

// Kernel P: rotate local-frame points (bf16) to global-frame f32.
// kp/vp interleaved into kvpg[N][384] (kp: 0..191, vp: 192..383); qpg separate.
__global__ __launch_bounds__(256) void kP(const bf16* __restrict__ qpl,
                                          const bf16* __restrict__ kpl,
                                          const bf16* __restrict__ vpl,
                                          const float* __restrict__ Rw,
                                          const float* __restrict__ pos,
                                          float* __restrict__ qpg,
                                          float* __restrict__ kvpg) {
    int r0 = blockIdx.x * 4;
    int tid = threadIdx.x;
    for (int u = tid; u < 4 * 192; u += 256) {
        int r = u / 192, e = u % 192, hp = e / 3, ii = e % 3;
        int ri = r0 + r;
        float R0 = Rw[(size_t)ri * 9 + ii * 3 + 0];
        float R1 = Rw[(size_t)ri * 9 + ii * 3 + 1];
        float R2 = Rw[(size_t)ri * 9 + ii * 3 + 2];
        float tt = pos[(size_t)ri * 15 + 3 + ii];
        size_t base = (size_t)ri * 192 + hp * 3;
        qpg[(size_t)ri * 192 + e] = R0 * B2F(qpl[base]) + R1 * B2F(qpl[base + 1]) + R2 * B2F(qpl[base + 2]) + tt;
        kvpg[(size_t)ri * 384 + e] = R0 * B2F(kpl[base]) + R1 * B2F(kpl[base + 1]) + R2 * B2F(kpl[base + 2]) + tt;
        kvpg[(size_t)ri * 384 + 192 + e] = R0 * B2F(vpl[base]) + R1 * B2F(vpl[base + 1]) + R2 * B2F(vpl[base + 2]) + tt;
    }
}

// Kernel C: pair features (MFMA pair MLP) + attention + IPA concat (bf16 out)
__global__ __launch_bounds__(256) void kC(const float* __restrict__ pos,
                                          const int* __restrict__ nbr,
                                          const int* __restrict__ resi,
                                          const int* __restrict__ chain,
                                          const int* __restrict__ batch,
                                          const int* __restrict__ mask,
                                          const float* __restrict__ Rw,
                                          const float* __restrict__ w_pair,
                                          const unsigned short* __restrict__ wT,
                                          const float* __restrict__ b_pair,
                                          const float* __restrict__ wbm,
                                          const float* __restrict__ gamma,
                                          const bf16* __restrict__ qbh,
                                          const bf16* __restrict__ kvb,
                                          const float* __restrict__ qpg,
                                          const float* __restrict__ kvpg,
                                          bf16* __restrict__ ipab,
                                          int N) {
    int i = blockIdx.x;
    int tid = threadIdx.x;
    __shared__ __align__(16) float qS[256];
    __shared__ __align__(16) float qpS[192];
    __shared__ __align__(16) unsigned short pfA[KNB * KPAD];
    __shared__ __align__(16) float pairS[KNB][68];
    __shared__ __align__(16) float wbmS[NHEAD][68];
    __shared__ float spS[NHEAD];
    __shared__ float lg[KNB * NHEAD];
    __shared__ float optg[192];
    __shared__ float ipaS[FOUT];
    __shared__ int idxS[KNB], rpS[KNB], scS[KNB], sbS[KNB], pmS[KNB];

    float R[9];
#pragma unroll
    for (int u = 0; u < 9; u++) R[u] = Rw[(size_t)i * 9 + u];
    float t0 = pos[(size_t)i * 15 + 3];
    float t1 = pos[(size_t)i * 15 + 4];
    float t2 = pos[(size_t)i * 15 + 5];

    qS[tid] = B2F(qbh[(size_t)i * 256 + tid]);
    if (tid < 192) qpS[tid] = qpg[(size_t)i * 192 + tid];
    if (tid < KNB) {
        int nb = nbr[(size_t)i * KNB + tid];
        int j = min(max(nb, 0), N - 1);
        idxS[tid] = j;
        int rp = resi[j] - resi[i];
        rp = min(max(rp, -32), 32) + 32;
        rpS[tid] = rp;
        scS[tid] = (chain[j] == chain[i]) ? 1 : 0;
        sbS[tid] = (batch[j] == batch[i]) ? 1 : 0;
        pmS[tid] = (mask[i] != 0 && mask[j] != 0 && nb >= 0 && batch[j] == batch[i]) ? 1 : 0;
    }
    __syncthreads();
    for (int u = tid; u < 512; u += 256) {
        int h = u & 7, c = u >> 3;
        wbmS[h][c] = wbm[c * 8 + h];
    }
    if (tid >= 192 && tid < 200) spS[tid - 192] = log1pf(expf(gamma[tid - 192]));
    if (tid < 160) {
        int kk = tid & 31, a = tid >> 5;
        int j = idxS[kk];
        const float* pj = pos + (size_t)j * 15 + a * 3;
        float px = pj[0] - t0, py = pj[1] - t1, pz = pj[2] - t2;
        float r0_ = R[0] * px + R[3] * py + R[6] * pz;
        float r1_ = R[1] * px + R[4] * py + R[7] * pz;
        float r2_ = R[2] * px + R[5] * py + R[8] * pz;
        float s = r0_ * r0_ + r1_ * r1_ + r2_ * r2_;
        float dij = sqrtf(s + 1e-12f);
        float di = 1.f / (dij + 1e-6f);
        pfA[kk * KPAD + a * 3 + 0] = f2bs(r0_ * di);
        pfA[kk * KPAD + a * 3 + 1] = f2bs(r1_ * di);
        pfA[kk * KPAD + a * 3 + 2] = f2bs(r2_ * di);
        for (int b = 0; b < 16; b++) {
            float z = (dij - (float)b * (10.f / 15.f)) * (1.f / 0.625f);
            pfA[kk * KPAD + 15 + a * 16 + b] = f2bs(expf(-z * z));
        }
    }
    if (tid < KNB) pfA[tid * KPAD + FPD] = 0;
    __syncthreads();

    // pair MLP via MFMA
    {
        int lane = tid & 63;
        int wv = tid >> 6;
        int n0 = wv * 16;
        int mrow = lane & 15;
        int quad = lane >> 4;
        floatx4 c0 = {0.f, 0.f, 0.f, 0.f};
        floatx4 c1 = {0.f, 0.f, 0.f, 0.f};
#pragma unroll
        for (int ks = 0; ks < 3; ks++) {
            int k0 = ks * 32 + quad * 8;
            short8 a0 = *reinterpret_cast<const short8*>(&pfA[mrow * KPAD + k0]);
            short8 a1 = *reinterpret_cast<const short8*>(&pfA[(16 + mrow) * KPAD + k0]);
            short8 bb = *reinterpret_cast<const short8*>(&wT[(n0 + mrow) * KPAD + k0]);
            c0 = __builtin_amdgcn_mfma_f32_16x16x32_bf16(a0, bb, c0, 0, 0, 0);
            c1 = __builtin_amdgcn_mfma_f32_16x16x32_bf16(a1, bb, c1, 0, 0, 0);
        }
        int col = n0 + mrow;
        float bp = b_pair[col];
        float w160 = w_pair[160 * 64 + col];
        float w161 = w_pair[161 * 64 + col];
#pragma unroll
        for (int mt = 0; mt < 2; mt++) {
            floatx4 cc = mt ? c1 : c0;
#pragma unroll
            for (int r = 0; r < 4; r++) {
                int row = mt * 16 + quad * 4 + r;
                float s = cc[r] + bp + w_pair[(95 + rpS[row]) * 64 + col] +
                          (scS[row] ? w160 : 0.f) + (sbS[row] ? w161 : 0.f);
                pairS[row][col] = gelu_t(s);
            }
        }
    }
    __syncthreads();

    // logits
    {
        int kk = tid >> 3, h = tid & 7;
        int j = idxS[kk];
        float qk = 0.f;
        const short8* kj8 = reinterpret_cast<const short8*>(kvb + (size_t)j * 512 + h * 32);
        const floatx4* qh4 = reinterpret_cast<const floatx4*>(qS + h * 32);
#pragma unroll
        for (int e = 0; e < 4; e++) {
            short8 kv = kj8[e];
            floatx4 qa = qh4[2 * e], qb = qh4[2 * e + 1];
            qk += qa[0] * bs2f(kv[0]) + qa[1] * bs2f(kv[1]) + qa[2] * bs2f(kv[2]) + qa[3] * bs2f(kv[3]) +
                  qb[0] * bs2f(kv[4]) + qb[1] * bs2f(kv[5]) + qb[2] * bs2f(kv[6]) + qb[3] * bs2f(kv[7]);
        }
        qk *= 0.17677669529663687f;
        float d2 = 0.f;
        const floatx4* kp4 = reinterpret_cast<const floatx4*>(kvpg + (size_t)j * 384 + h * 24);
        const floatx4* qp4 = reinterpret_cast<const floatx4*>(qpS + h * 24);
#pragma unroll
        for (int e = 0; e < 6; e++) {
            floatx4 kv = kp4[e], qv = qp4[e];
#pragma unroll
            for (int q = 0; q < 4; q++) {
                float df = qv[q] - kv[q];
                d2 += df * df;
            }
        }
        float pb = 0.f;
        const floatx4* ps4 = reinterpret_cast<const floatx4*>(&pairS[kk][0]);
        const floatx4* wb4 = reinterpret_cast<const floatx4*>(&wbmS[h][0]);
#pragma unroll
        for (int e = 0; e < 16; e++) {
            floatx4 pv = ps4[e], wv4 = wb4[e];
            pb += pv[0] * wv4[0] + pv[1] * wv4[1] + pv[2] * wv4[2] + pv[3] * wv4[3];
        }
        float lgt = 0.5773502691896258f * (qk + pb - (1.f / 12.f) * spS[h] * d2);
        lg[kk * 8 + h] = pmS[kk] ? lgt : -1e9f;
    }
    __syncthreads();
    // softmax over kk per head; 64 lanes: 8 heads x 8 sub-lanes, 4 kk each
    if (tid < 64) {
        int h = tid >> 3, sub = tid & 7;
        float m = -INFINITY;
        float lv[4];
#pragma unroll
        for (int q = 0; q < 4; q++) {
            lv[q] = lg[(sub + 8 * q) * 8 + h];
            m = fmaxf(m, lv[q]);
        }
#pragma unroll
        for (int mk = 1; mk < 8; mk <<= 1) m = fmaxf(m, __shfl_xor(m, mk));
        float s = 0.f, ex[4];
#pragma unroll
        for (int q = 0; q < 4; q++) { ex[q] = expf(lv[q] - m); s += ex[q]; }
#pragma unroll
        for (int mk = 1; mk < 8; mk <<= 1) s += __shfl_xor(s, mk);
        float invs = 1.f / s;
#pragma unroll
        for (int q = 0; q < 4; q++) {
            int kk = sub + 8 * q;
            lg[kk * 8 + h] = pmS[kk] ? ex[q] * invs : 0.f;
        }
    }
    __syncthreads();
    {
        int h = tid >> 5, d = tid & 31;
        float s = 0.f;
        for (int kk = 0; kk < KNB; kk++)
            s += lg[kk * 8 + h] * B2F(kvb[(size_t)idxS[kk] * 512 + 256 + h * 32 + d]);
        ipaS[h * 32 + d] = s;
    }
    for (int u = tid; u < 512; u += 256) {
        int h = u >> 6, c = u & 63;
        float s = 0.f;
        for (int kk = 0; kk < KNB; kk++) s += lg[kk * 8 + h] * pairS[kk][c];
        ipaS[256 + u] = s;
    }
    if (tid < 192) {
        int h = tid / 24;
        float s = 0.f;
        for (int kk = 0; kk < KNB; kk++)
            s += lg[kk * 8 + h] * kvpg[(size_t)idxS[kk] * 384 + 192 + tid];
        optg[tid] = s;
    }
    __syncthreads();
    if (tid < 192) {
        int hp = tid / 3, ii = tid % 3;
        float v0 = optg[hp * 3 + 0] - t0, v1 = optg[hp * 3 + 1] - t1, v2 = optg[hp * 3 + 2] - t2;
        ipaS[768 + tid] = R[0 + ii] * v0 + R[3 + ii] * v1 + R[6 + ii] * v2;
    }
    __syncthreads();
    if (tid < 64) {
        float a0 = ipaS[768 + tid * 3], a1 = ipaS[768 + tid * 3 + 1], a2 = ipaS[768 + tid * 3 + 2];
        ipaS[960 + tid] = sqrtf(a0 * a0 + a1 * a1 + a2 * a2 + 1e-8f);
    }
    __syncthreads();
    for (int u = tid; u < FOUT; u += 256) ipab[(size_t)i * FOUT + u] = F2B(ipaS[u]);
}

// Kernel DE: fused output projection + LN2 + transition MLP. 32 rows/block.
// l2 (= lup + ipa@wo + bo) stays in registers; final = l2 + mlp.
__global__ __launch_bounds__(256) void kDE(const bf16* __restrict__ ipab,
                                           const unsigned short* __restrict__ woT,
                                           const float* __restrict__ bo,
                                           const float* __restrict__ ln2_s,
                                           const float* __restrict__ ln2_o,
                                           const unsigned short* __restrict__ wgT,
                                           const unsigned short* __restrict__ wvmT,
                                           const unsigned short* __restrict__ womT,
                                           float* __restrict__ dlocal) {
    int r0 = blockIdx.x * 32;
    int tid = threadIdx.x;
    __shared__ __align__(16) unsigned short xbf[32 * 264];
    __shared__ __align__(16) unsigned short hbf[32 * 520];
    __shared__ float statsS[32 * 4];
    int lane = tid & 63, w = tid >> 6;
    int mtile = w & 1, par = w >> 1, m = lane & 15, quad = lane >> 4;

    // GEMM0: ipa @ wo
    floatx4 l2[8];
#pragma unroll
    for (int j = 0; j < 8; j++) l2[j] = {0.f, 0.f, 0.f, 0.f};
    const short8* arow = reinterpret_cast<const short8*>(ipab + (size_t)(r0 + mtile * 16 + m) * 1024);
    for (int ks = 0; ks < 32; ks++) {
        short8 a = arow[ks * 4 + quad];
#pragma unroll
        for (int j = 0; j < 8; j++) {
            int nt = par + 2 * j;
            const short8* bp = reinterpret_cast<const short8*>(woT + (size_t)(nt * 16 + m) * 1024);
            l2[j] = __builtin_amdgcn_mfma_f32_16x16x32_bf16(a, bp[ks * 4 + quad], l2[j], 0, 0, 0);
        }
    }
    // += lup + bo
#pragma unroll
    for (int j = 0; j < 8; j++) {
        int colg = (par + 2 * j) * 16 + m;
        float bov = bo[colg];
#pragma unroll
        for (int r = 0; r < 4; r++) {
            int row = mtile * 16 + quad * 4 + r;
            l2[j][r] += dlocal[(size_t)(r0 + row) * 256 + colg] + bov;
        }
    }
    // LN2 stats
    {
        float s[4] = {0.f, 0.f, 0.f, 0.f}, ss[4] = {0.f, 0.f, 0.f, 0.f};
#pragma unroll
        for (int j = 0; j < 8; j++)
#pragma unroll
            for (int r = 0; r < 4; r++) { s[r] += l2[j][r]; ss[r] += l2[j][r] * l2[j][r]; }
#pragma unroll
        for (int mask = 1; mask < 16; mask <<= 1)
#pragma unroll
            for (int r = 0; r < 4; r++) { s[r] += __shfl_xor(s[r], mask); ss[r] += __shfl_xor(ss[r], mask); }
        if (m == 0) {
#pragma unroll
            for (int r = 0; r < 4; r++) {
                int row = mtile * 16 + quad * 4 + r;
                statsS[row * 4 + par * 2 + 0] = s[r];
                statsS[row * 4 + par * 2 + 1] = ss[r];
            }
        }
    }
    __syncthreads();
    {
        float mu[4], rs_[4];
#pragma unroll
        for (int r = 0; r < 4; r++) {
            int row = mtile * 16 + quad * 4 + r;
            float S = statsS[row * 4 + 0] + statsS[row * 4 + 2];
            float SS = statsS[row * 4 + 1] + statsS[row * 4 + 3];
            float m_ = S * (1.f / 256.f);
            mu[r] = m_;
            rs_[r] = rsqrtf(SS * (1.f / 256.f) - m_ * m_ + 1e-5f);
        }
#pragma unroll
        for (int j = 0; j < 8; j++) {
            int colg = (par + 2 * j) * 16 + m;
            float g = ln2_s[colg], o = ln2_o[colg];
#pragma unroll
            for (int r = 0; r < 4; r++) {
                int row = mtile * 16 + quad * 4 + r;
                xbf[row * 264 + colg] = f2bs((l2[j][r] - mu[r]) * rs_[r] * g + o);
            }
        }
    }
    __syncthreads();
    // GEMM1: x @ [wg|wvm] -> h = gelu(ag)*av
    short8 afr[8];
#pragma unroll
    for (int ks = 0; ks < 8; ks++)
        afr[ks] = *reinterpret_cast<const short8*>(&xbf[(mtile * 16 + m) * 264 + ks * 32 + quad * 8]);
    for (int nt = par; nt < 32; nt += 2) {
        floatx4 cg = {0.f, 0.f, 0.f, 0.f};
        floatx4 cv = {0.f, 0.f, 0.f, 0.f};
        const short8* bg = reinterpret_cast<const short8*>(wgT + (size_t)(nt * 16 + m) * 256);
        const short8* bv = reinterpret_cast<const short8*>(wvmT + (size_t)(nt * 16 + m) * 256);
#pragma unroll
        for (int ks = 0; ks < 8; ks++) {
            cg = __builtin_amdgcn_mfma_f32_16x16x32_bf16(afr[ks], bg[ks * 4 + quad], cg, 0, 0, 0);
            cv = __builtin_amdgcn_mfma_f32_16x16x32_bf16(afr[ks], bv[ks * 4 + quad], cv, 0, 0, 0);
        }
#pragma unroll
        for (int r = 0; r < 4; r++) {
            int row = mtile * 16 + quad * 4 + r;
            hbf[row * 520 + nt * 16 + m] = f2bs(gelu_t(cg[r]) * cv[r]);
        }
    }
    __syncthreads();
    // GEMM2: h @ wom; final = l2 + acc
    floatx4 acc[8];
#pragma unroll
    for (int j = 0; j < 8; j++) acc[j] = {0.f, 0.f, 0.f, 0.f};
    for (int ks = 0; ks < 16; ks++) {
        short8 a = *reinterpret_cast<const short8*>(&hbf[(mtile * 16 + m) * 520 + ks * 32 + quad * 8]);
#pragma unroll
        for (int j = 0; j < 8; j++) {
            int nt = par + 2 * j;
            const short8* bp = reinterpret_cast<const short8*>(womT + (size_t)(nt * 16 + m) * 512);
            acc[j] = __builtin_amdgcn_mfma_f32_16x16x32_bf16(a, bp[ks * 4 + quad], acc[j], 0, 0, 0);
        }
    }
#pragma unroll
    for (int j = 0; j < 8; j++) {
        int colg = (par + 2 * j) * 16 + m;
#pragma unroll
        for (int r = 0; r < 4; r++) {
            int row = mtile * 16 + quad * 4 + r;
            dlocal[(size_t)(r0 + row) * 256 + colg] = l2[j][r] + acc[j][r];
        }
    }
}

// Kernel F: LN3 + wpos + frame transform + update_mask. 8 rows/block.
__global__ __launch_bounds__(256) void kF(const float* __restrict__ dlocal,
                                          const float* __restrict__ ln3_s,
                                          const float* __restrict__ ln3_o,
                                          const float* __restrict__ wpos,
                                          const float* __restrict__ lpw,
                                          const float* __restrict__ Rw,
                                          const float* __restrict__ pos,
                                          const int* __restrict__ umask,
                                          float* __restrict__ outp) {
    int tid = threadIdx.x;
    int r = tid >> 5, lt = tid & 31;
    int ri = blockIdx.x * 8 + r;
    __shared__ float x3S[8][256];
    __shared__ float nlS[8][15];
    {
        const floatx4* src = reinterpret_cast<const floatx4*>(dlocal + (size_t)ri * 256 + lt * 8);
        floatx4 v0 = src[0], v1 = src[1];
        float s = 0.f, ss = 0.f;
#pragma unroll
        for (int q = 0; q < 4; q++) {
            s += v0[q] + v1[q];
            ss += v0[q] * v0[q] + v1[q] * v1[q];
        }
#pragma unroll
        for (int mask = 1; mask < 32; mask <<= 1) { s += __shfl_xor(s, mask); ss += __shfl_xor(ss, mask); }
        float mu = s * (1.f / 256.f);
        float var = ss * (1.f / 256.f) - mu * mu;
        float rs = rsqrtf(var + 1e-5f);
#pragma unroll
        for (int q = 0; q < 4; q++) {
            int f0 = lt * 8 + q, f1 = lt * 8 + 4 + q;
            x3S[r][f0] = (v0[q] - mu) * rs * ln3_s[f0] + ln3_o[f0];
            x3S[r][f1] = (v1[q] - mu) * rs * ln3_s[f1] + ln3_o[f1];
        }
    }
    __syncthreads();
    {
        int g = tid >> 5, sub = tid & 31;
        for (int out = g; out < 120; out += 8) {
            int rr = out / 15, e = out % 15;
            float partial = 0.f;
#pragma unroll
            for (int i2 = 0; i2 < 8; i2++) {
                int f = sub + 32 * i2;
                partial += x3S[rr][f] * wpos[f * 15 + e];
            }
#pragma unroll
            for (int mask = 1; mask < 32; mask <<= 1) partial += __shfl_xor(partial, mask);
            if (sub == 0) nlS[rr][e] = lpw[(size_t)(blockIdx.x * 8 + rr) * 15 + e] + partial;
        }
    }
    __syncthreads();
    if (tid < 120) {
        int rr = tid / 15, e = tid % 15;
        int rj = blockIdx.x * 8 + rr;
        int a2 = e / 3, ii = e % 3;
        float R0 = Rw[(size_t)rj * 9 + ii * 3 + 0];
        float R1 = Rw[(size_t)rj * 9 + ii * 3 + 1];
        float R2 = Rw[(size_t)rj * 9 + ii * 3 + 2];
        float tt = pos[(size_t)rj * 15 + 3 + ii];
        float np = R0 * nlS[rr][a2 * 3 + 0] + R1 * nlS[rr][a2 * 3 + 1] + R2 * nlS[rr][a2 * 3 + 2] + tt;
        float old = pos[(size_t)rj * 15 + e];
        outp[(size_t)rj * 15 + e] = (umask[rj] != 0) ? np : old;
    }
}

extern "C" void kernel_launch(void* const* d_in, const int* in_sizes, int n_in,
                              void* d_out, int out_size, void* d_ws, size_t ws_size,
                              hipStream_t stream) {
    static const int map_dict[31] = {0, 1, 2, 3, 4, 5, 6, 7, 8, 9, 10, 11, 12, 13, 14, 15,
                                     16, 17, 18, 19, 20, 21, 22, 23, 24, 25, 26, 27, 28, 29, 30};
    static const int map_sig[31] = {0, 1, 25, 26, 27, 28, 29, 30, 2, 3, 4, 5, 6, 7, 8, 9,
                                    10, 11, 12, 13, 14, 15, 16, 17, 18, 19, 20, 21, 22, 23, 24};
    const int* M = (in_sizes[2] == FIN * DMODEL) ? map_sig : map_dict;

    const float* local = (const float*)d_in[M[0]];
    const float* pos = (const float*)d_in[M[1]];
    const int* nbr = (const int*)d_in[M[2]];
    const int* resi = (const int*)d_in[M[3]];
    const int* chain = (const int*)d_in[M[4]];
    const int* batch = (const int*)d_in[M[5]];
    const int* umask = (const int*)d_in[M[6]];
    const int* mask = (const int*)d_in[M[7]];
    const float* w_in = (const float*)d_in[M[8]];
    const float* w_pair = (const float*)d_in[M[9]];
    const float* b_pair = (const float*)d_in[M[10]];
    const float* ln1_s = (const float*)d_in[M[11]];
    const float* ln1_o = (const float*)d_in[M[12]];
    const float* wq = (const float*)d_in[M[13]];
    const float* wk = (const float*)d_in[M[14]];
    const float* wv = (const float*)d_in[M[15]];
    const float* wqp = (const float*)d_in[M[16]];
    const float* wkp = (const float*)d_in[M[17]];
    const float* wvp = (const float*)d_in[M[18]];
    const float* wbm = (const float*)d_in[M[19]];
    const float* gamma = (const float*)d_in[M[20]];
    const float* wo = (const float*)d_in[M[21]];
    const float* bo = (const float*)d_in[M[22]];
    const float* ln2_s = (const float*)d_in[M[23]];
    const float* ln2_o = (const float*)d_in[M[24]];
    const float* wg = (const float*)d_in[M[25]];
    const float* wvm = (const float*)d_in[M[26]];
    const float* wom = (const float*)d_in[M[27]];
    const float* ln3_s = (const float*)d_in[M[28]];
    const float* ln3_o = (const float*)d_in[M[29]];
    const float* wpos = (const float*)d_in[M[30]];

    int N = in_sizes[0] / DMODEL;

    float* out_local = (float*)d_out;
    float* out_pos = out_local + (size_t)N * DMODEL;

    char* wsb = (char*)d_ws;
    float* Rw = (float*)wsb;   wsb += (size_t)N * 9 * 4;
    float* lpw = (float*)wsb;  wsb += (size_t)N * 15 * 4;
    bf16* qbh = (bf16*)wsb;    wsb += (size_t)N * 256 * 2;
    bf16* kvb = (bf16*)wsb;    wsb += (size_t)N * 512 * 2;
    bf16* qpl = (bf16*)wsb;    wsb += (size_t)N * 192 * 2;
    bf16* kpl = (bf16*)wsb;    wsb += (size_t)N * 192 * 2;
    bf16* vpl = (bf16*)wsb;    wsb += (size_t)N * 192 * 2;
    bf16* ipab = (bf16*)wsb;   wsb += (size_t)N * 1024 * 2;
    float* qpg = (float*)wsb;  wsb += (size_t)N * 192 * 4;
    float* kvpg = (float*)wsb; wsb += (size_t)N * 384 * 4;
    unsigned short* featb = (unsigned short*)wsb; wsb += (size_t)N * KPAD * 2;
    unsigned short* wtrans = (unsigned short*)wsb; wsb += (size_t)WT_TOTAL * 2;
    unsigned short* wAllT = wtrans + OFF_WALL;
    unsigned short* woT   = wtrans + OFF_WO;
    unsigned short* wgT   = wtrans + OFF_WG;
    unsigned short* wvmT  = wtrans + OFF_WVM;
    unsigned short* womT  = wtrans + OFF_WOM;
    unsigned short* wpT   = wtrans + OFF_WP;
    unsigned short* winT  = wtrans + OFF_WIN;

    dim3 blk(256);
    hipLaunchKernelGGL(kT, dim3(512), blk, 0, stream, wq, wk, wv, wqp, wkp, wvp,
                       wo, wg, wvm, wom, w_pair, w_in, wtrans);
    hipLaunchKernelGGL(kA1, dim3(N / 8), blk, 0, stream, pos, Rw, lpw, featb);
    hipLaunchKernelGGL(kB, dim3(N / 32), blk, 0, stream, local, featb, ln1_s, ln1_o, wAllT, winT,
                       out_local, qbh, kvb, qpl, kpl, vpl);
    hipLaunchKernelGGL(kP, dim3(N / 4), blk, 0, stream, qpl, kpl, vpl, Rw, pos, qpg, kvpg);
    hipLaunchKernelGGL(kC, dim3(N), blk, 0, stream, pos, nbr, resi, chain, batch, mask, Rw,
                       w_pair, wpT, b_pair, wbm, gamma, qbh, kvb, qpg, kvpg, ipab, N);
    hipLaunchKernelGGL(kDE, dim3(N / 32), blk, 0, stream, ipab, woT, bo, ln2_s, ln2_o,
                       wgT, wvmT, womT, out_local);
    hipLaunchKernelGGL(kF, dim3(N / 8), blk, 0, stream, out_local, ln3_s, ln3_o, wpos, lpw, Rw, pos,
                       umask, out_pos);
}